// Round 2
// baseline (2259.235 us; speedup 1.0000x reference)
//
#include <hip/hip_runtime.h>
#include <hip/hip_bf16.h>
#include <math.h>
#include <type_traits>

#define LSEQ 8192
#define BATCH 4
#define M_TOK (BATCH * LSEQ)

// ---------------------------------------------------------------- helpers
__device__ __forceinline__ float siluf(float x) {
  return x / (1.f + __expf(-x));
}

__device__ __forceinline__ float waveReduceSum(float v) {
#pragma unroll
  for (int off = 32; off; off >>= 1) v += __shfl_xor(v, off, 64);
  return v;
}

// block = 256 threads (4 waves). lds8 must have >= 8 floats.
__device__ __forceinline__ void blockLNStats(float s, float ss, float* lds8,
                                             float& mean, float& rstd) {
  s = waveReduceSum(s);
  ss = waveReduceSum(ss);
  int wave = threadIdx.x >> 6;
  int lane = threadIdx.x & 63;
  if (lane == 0) { lds8[wave] = s; lds8[4 + wave] = ss; }
  __syncthreads();
  s  = lds8[0] + lds8[1] + lds8[2] + lds8[3];
  ss = lds8[4] + lds8[5] + lds8[6] + lds8[7];
  mean = s * (1.f / 512.f);
  float var = ss * (1.f / 512.f) - mean * mean;
  rstd = rsqrtf(var + 1e-5f);
}

// ---------------------------------------------------------------- kernel 1
// x[M][161] -> cat[M][576] = silu([emb[tid], reg*W_r^T+b, br*W_b^T+b, mem*W_m^T+b])
__global__ __launch_bounds__(256) void embed_kernel(
    const int* __restrict__ x, const float* __restrict__ emb,
    const float* __restrict__ reg_w, const float* __restrict__ reg_b,
    const float* __restrict__ br_w, const float* __restrict__ br_b,
    const float* __restrict__ mem_w, const float* __restrict__ mem_b,
    float* __restrict__ cat) {
  __shared__ float xs[160];
  __shared__ int tok_s;
  const int t = blockIdx.x;
  const int tid = threadIdx.x;
  const int* xr = x + (size_t)t * 161;
  if (tid == 0) tok_s = xr[0];
  if (tid < 160) xs[tid] = (float)xr[1 + tid];
  __syncthreads();
  const int tok = tok_s;
  // xs[0..63]=reg, xs[64..127]=mem, xs[128..159]=br
  for (int c = tid; c < 576; c += 256) {
    float v;
    if (c < 192) {
      v = emb[tok * 192 + c];
    } else if (c < 320) {
      int o = c - 192;
      float s = reg_b[o];
      const float* w = reg_w + o * 64;
#pragma unroll
      for (int j = 0; j < 64; ++j) s = fmaf(w[j], xs[j], s);
      v = s;
    } else if (c < 448) {
      int o = c - 320;
      float s = br_b[o];
      const float* w = br_w + o * 32;
#pragma unroll
      for (int j = 0; j < 32; ++j) s = fmaf(w[j], xs[128 + j], s);
      v = s;
    } else {
      int o = c - 448;
      float s = mem_b[o];
      const float* w = mem_w + o * 64;
#pragma unroll
      for (int j = 0; j < 64; ++j) s = fmaf(w[j], xs[64 + j], s);
      v = s;
    }
    cat[(size_t)t * 576 + c] = siluf(v);
  }
}

// ---------------------------------------------------------------- kernel 2
// C[M][N] = A[M][K] @ W[N][K]^T + bias ; fp32 tiled, BM=BN=128, BK=16
// OT = float or __hip_bfloat16 (output conversion in epilogue)
template <typename OT>
__global__ __launch_bounds__(256) void gemm_kernel(
    const float* __restrict__ A, const float* __restrict__ W,
    const float* __restrict__ bias, OT* __restrict__ C, int M, int N,
    int K) {
  __shared__ float As[16][132];
  __shared__ float Ws[16][132];
  const int tid = threadIdx.x;
  const int row0 = blockIdx.x * 128;
  const int col0 = blockIdx.y * 128;
  const int lr = tid >> 2;          // 0..63
  const int lc = (tid & 3) << 2;    // 0,4,8,12
  const int tx = tid & 15;
  const int ty = tid >> 4;
  float acc[8][8];
#pragma unroll
  for (int i = 0; i < 8; ++i)
#pragma unroll
    for (int j = 0; j < 8; ++j) acc[i][j] = 0.f;

  for (int k0 = 0; k0 < K; k0 += 16) {
    const float4 a0 = *(const float4*)&A[(size_t)(row0 + lr) * K + k0 + lc];
    const float4 a1 = *(const float4*)&A[(size_t)(row0 + lr + 64) * K + k0 + lc];
    const float4 w0 = *(const float4*)&W[(size_t)(col0 + lr) * K + k0 + lc];
    const float4 w1 = *(const float4*)&W[(size_t)(col0 + lr + 64) * K + k0 + lc];
    __syncthreads();
    As[lc + 0][lr] = a0.x; As[lc + 1][lr] = a0.y;
    As[lc + 2][lr] = a0.z; As[lc + 3][lr] = a0.w;
    As[lc + 0][lr + 64] = a1.x; As[lc + 1][lr + 64] = a1.y;
    As[lc + 2][lr + 64] = a1.z; As[lc + 3][lr + 64] = a1.w;
    Ws[lc + 0][lr] = w0.x; Ws[lc + 1][lr] = w0.y;
    Ws[lc + 2][lr] = w0.z; Ws[lc + 3][lr] = w0.w;
    Ws[lc + 0][lr + 64] = w1.x; Ws[lc + 1][lr + 64] = w1.y;
    Ws[lc + 2][lr + 64] = w1.z; Ws[lc + 3][lr + 64] = w1.w;
    __syncthreads();
#pragma unroll
    for (int kk = 0; kk < 16; ++kk) {
      const float4 af0 = *(const float4*)&As[kk][ty * 8];
      const float4 af1 = *(const float4*)&As[kk][ty * 8 + 4];
      const float4 bf0 = *(const float4*)&Ws[kk][tx * 8];
      const float4 bf1 = *(const float4*)&Ws[kk][tx * 8 + 4];
      const float a[8] = {af0.x, af0.y, af0.z, af0.w, af1.x, af1.y, af1.z, af1.w};
      const float bb[8] = {bf0.x, bf0.y, bf0.z, bf0.w, bf1.x, bf1.y, bf1.z, bf1.w};
#pragma unroll
      for (int i = 0; i < 8; ++i)
#pragma unroll
        for (int j = 0; j < 8; ++j) acc[i][j] = fmaf(a[i], bb[j], acc[i][j]);
    }
  }
  float bv[8];
#pragma unroll
  for (int j = 0; j < 8; ++j) bv[j] = bias ? bias[col0 + tx * 8 + j] : 0.f;
#pragma unroll
  for (int i = 0; i < 8; ++i) {
    size_t r = (size_t)(row0 + ty * 8 + i) * N + col0 + tx * 8;
    float vv[8];
#pragma unroll
    for (int j = 0; j < 8; ++j) vv[j] = acc[i][j] + bv[j];
    if constexpr (std::is_same<OT, float>::value) {
      float4 o0 = {vv[0], vv[1], vv[2], vv[3]};
      float4 o1 = {vv[4], vv[5], vv[6], vv[7]};
      *(float4*)&C[r] = o0;
      *(float4*)&C[r + 4] = o1;
    } else {
      union { __hip_bfloat16 h[8]; uint4 u; } pk;
#pragma unroll
      for (int j = 0; j < 8; ++j) pk.h[j] = __float2bfloat16(vv[j]);
      *(uint4*)&C[r] = pk.u;  // 16B store, r is a multiple of 8 elements
    }
  }
}

// ---------------------------------------------------------------- kernel 3
// in-place LN(512) + silu, one token per block (256 thr, 2 feat/thr)
__global__ __launch_bounds__(256) void ln_silu_kernel(
    float* __restrict__ buf, const float* __restrict__ g,
    const float* __restrict__ b) {
  __shared__ float lds8[8];
  const int t = blockIdx.x;
  const int tid = threadIdx.x;
  float2 v = *(const float2*)&buf[(size_t)t * 512 + tid * 2];
  float mean, rstd;
  blockLNStats(v.x + v.y, v.x * v.x + v.y * v.y, lds8, mean, rstd);
  float y0 = (v.x - mean) * rstd * g[2 * tid] + b[2 * tid];
  float y1 = (v.y - mean) * rstd * g[2 * tid + 1] + b[2 * tid + 1];
  float2 o = {siluf(y0), siluf(y1)};
  *(float2*)&buf[(size_t)t * 512 + tid * 2] = o;
}

// ---------------------------------------------------------------- kernel 4
// sliding-window attention. one block per (b, h, window-block), 128 threads
// = 128 queries. K/V staged in LDS in 64-row chunks; RoPE applied on the fly.
// qkv (bf16) layout per token: [h*192 + d*3 + {0:q,1:k,2:v}]
__global__ __launch_bounds__(128) void attn_kernel(
    const __hip_bfloat16* __restrict__ qkv, float* __restrict__ o_out) {
  __shared__ float Ks[64][64];
  __shared__ float Vs[64][64];
  const int blk = blockIdx.x;
  const int nbIdx = blk & 63;
  const int h = (blk >> 6) & 7;
  const int b = blk >> 9;
  const int qi = threadIdx.x;  // 0..127
  const size_t seqBase = (size_t)b * LSEQ;
  const int qtok = nbIdx * 128 + qi;
  const size_t qrow = (seqBase + qtok) * 1536 + h * 192;

  // load q with rope
  float q[64];
  const float posq = (float)qtok;
#pragma unroll
  for (int p = 0; p < 32; ++p) {
    float x1 = __bfloat162float(qkv[qrow + 6 * p + 0]);
    float x2 = __bfloat162float(qkv[qrow + 6 * p + 3]);
    float inv = expf(-(float)p * 0.28782313662f);  // ln(10000)/32
    float sn, cs;
    sincosf(posq * inv, &sn, &cs);
    q[2 * p] = x1 * cs - x2 * sn;
    q[2 * p + 1] = x1 * sn + x2 * cs;
  }

  const int kminblk = (nbIdx == 0) ? 128 : 0;
  float m = -3.0e38f, l = 0.f;
  float o[64];
#pragma unroll
  for (int d = 0; d < 64; ++d) o[d] = 0.f;

  for (int c0 = 0; c0 < 256; c0 += 64) {
    if (c0 + 63 < kminblk) continue;  // uniform skip (block 0 prev-window)
    __syncthreads();
    // stage K chunk with rope: 64 rows x 32 pairs
    for (int idx = threadIdx.x; idx < 64 * 32; idx += 128) {
      int row = idx >> 5;
      int p = idx & 31;
      int ktok = (nbIdx - 1) * 128 + c0 + row;  // >=0 in non-skipped chunks
      size_t krow = (seqBase + ktok) * 1536 + h * 192;
      float x1 = __bfloat162float(qkv[krow + 6 * p + 1]);
      float x2 = __bfloat162float(qkv[krow + 6 * p + 4]);
      float inv = expf(-(float)p * 0.28782313662f);
      float sn, cs;
      sincosf((float)ktok * inv, &sn, &cs);
      float2 kv = {x1 * cs - x2 * sn, x1 * sn + x2 * cs};
      *(float2*)&Ks[row][2 * p] = kv;
    }
    // stage V chunk
    for (int idx = threadIdx.x; idx < 64 * 64; idx += 128) {
      int row = idx >> 6;
      int d = idx & 63;
      int ktok = (nbIdx - 1) * 128 + c0 + row;
      Vs[row][d] =
          __bfloat162float(qkv[(seqBase + ktok) * 1536 + h * 192 + 3 * d + 2]);
    }
    __syncthreads();
    for (int kj = c0; kj < c0 + 64; ++kj) {
      const float* kr = &Ks[kj - c0][0];
      float d0 = 0.f, d1 = 0.f, d2 = 0.f, d3 = 0.f;
#pragma unroll
      for (int d = 0; d < 64; d += 4) {
        d0 = fmaf(q[d + 0], kr[d + 0], d0);
        d1 = fmaf(q[d + 1], kr[d + 1], d1);
        d2 = fmaf(q[d + 2], kr[d + 2], d2);
        d3 = fmaf(q[d + 3], kr[d + 3], d3);
      }
      float s = 0.125f * ((d0 + d1) + (d2 + d3));
      // mask: key kj valid for query qi iff qi <= kj <= qi+128
      bool active = (kj >= qi) && (kj <= qi + 128);
      float nm = active ? fmaxf(m, s) : m;
      float r = __expf(m - nm);          // ==1 when m unchanged; 0 on first hit
      float p = active ? __expf(s - nm) : 0.f;
      l = l * r + p;
      const float* vr = &Vs[kj - c0][0];
#pragma unroll
      for (int d = 0; d < 64; ++d) o[d] = fmaf(o[d], r, p * vr[d]);
      m = nm;
    }
  }
  const float rl = 1.f / l;
  const size_t orow = (seqBase + qtok) * 512 + h * 64;
#pragma unroll
  for (int d = 0; d < 64; d += 4) {
    float4 v = {o[d] * rl, o[d + 1] * rl, o[d + 2] * rl, o[d + 3] * rl};
    *(float4*)&o_out[orow + d] = v;
  }
}

// ---------------------------------------------------------------- kernel 5
// LN2 + silu + head(9) + activations -> out[M][9]
__global__ __launch_bounds__(256) void head_kernel(
    const float* __restrict__ pre, const float* __restrict__ g,
    const float* __restrict__ b, const float* __restrict__ hw,
    const float* __restrict__ hb, float* __restrict__ out) {
  __shared__ float lds8[8];
  __shared__ float ys[512];
  __shared__ float raw[9];
  const int t = blockIdx.x;
  const int tid = threadIdx.x;
  float2 v = *(const float2*)&pre[(size_t)t * 512 + tid * 2];
  float mean, rstd;
  blockLNStats(v.x + v.y, v.x * v.x + v.y * v.y, lds8, mean, rstd);
  float y0 = (v.x - mean) * rstd * g[2 * tid] + b[2 * tid];
  float y1 = (v.y - mean) * rstd * g[2 * tid + 1] + b[2 * tid + 1];
  ys[2 * tid] = siluf(y0);
  ys[2 * tid + 1] = siluf(y1);
  __syncthreads();
  const int wave = tid >> 6;
  const int lane = tid & 63;
  for (int r = wave; r < 9; r += 4) {
    float p = 0.f;
#pragma unroll
    for (int i = 0; i < 8; ++i)
      p = fmaf(ys[lane + i * 64], hw[r * 512 + lane + i * 64], p);
    p = waveReduceSum(p);
    if (lane == 0) raw[r] = p + hb[r];
  }
  __syncthreads();
  if (tid == 0) {
    float* op = out + (size_t)t * 9;
    // softplus (stable, matches jax.nn.softplus)
    op[0] = fmaxf(raw[0], 0.f) + log1pf(expf(-fabsf(raw[0])));
    op[1] = fmaxf(raw[1], 0.f) + log1pf(expf(-fabsf(raw[1])));
    op[2] = 1.f / (1.f + expf(-raw[2]));
    op[3] = 1.f / (1.f + expf(-raw[3]));
    op[4] = 1.f / (1.f + expf(-raw[4]));
    float mx = fmaxf(fmaxf(raw[5], raw[6]), fmaxf(raw[7], raw[8]));
    float e0 = expf(raw[5] - mx), e1 = expf(raw[6] - mx);
    float e2 = expf(raw[7] - mx), e3 = expf(raw[8] - mx);
    float inv = 1.f / (e0 + e1 + e2 + e3);
    op[5] = e0 * inv; op[6] = e1 * inv; op[7] = e2 * inv; op[8] = e3 * inv;
  }
}

// ---------------------------------------------------------------- launch
// Workspace layout (peak 160 MB; regions time-shared per dataflow):
//   [0, 96 MB)      qkvb (bf16, M*1536)  — written step 4, read step 5
//     [0, 75.5 MB)  cat  (fp32, M*576)   — written step 1, read step 2 (dead before qkvb)
//     [0, 64 MB)    pre  (fp32, M*512)   — written step 6, read step 7 (after qkvb dead)
//   [96, 160 MB)    hbuf (fp32, M*512)   — steps 2-4; reused as attn output (att) steps 5-6
extern "C" void kernel_launch(void* const* d_in, const int* in_sizes, int n_in,
                              void* d_out, int out_size, void* d_ws,
                              size_t ws_size, hipStream_t stream) {
  const float* emb = (const float*)d_in[0];
  const float* reg_w = (const float*)d_in[1];
  const float* reg_b = (const float*)d_in[2];
  const float* br_w = (const float*)d_in[3];
  const float* br_b = (const float*)d_in[4];
  const float* mem_w = (const float*)d_in[5];
  const float* mem_b = (const float*)d_in[6];
  const float* inst_w = (const float*)d_in[7];
  const float* inst_b = (const float*)d_in[8];
  const float* ln1_g = (const float*)d_in[9];
  const float* ln1_b = (const float*)d_in[10];
  const float* qkv_w = (const float*)d_in[11];
  const float* outp_w = (const float*)d_in[12];
  const float* outp_b = (const float*)d_in[13];
  const float* ln2_g = (const float*)d_in[14];
  const float* ln2_b = (const float*)d_in[15];
  const float* head_w = (const float*)d_in[16];
  const float* head_b = (const float*)d_in[17];
  const int* x = (const int*)d_in[18];
  float* out = (float*)d_out;

  const int M = M_TOK;
  char* wsb = (char*)d_ws;
  __hip_bfloat16* qkvb = (__hip_bfloat16*)wsb;          // M*1536 bf16
  float* cat = (float*)wsb;                             // M*576 fp32 (aliases qkvb)
  float* pre = (float*)wsb;                             // M*512 fp32 (aliases qkvb)
  float* hbuf = (float*)(wsb + (size_t)M * 1536 * 2);   // M*512 fp32
  float* att = hbuf;                                    // attn out reuses hbuf

  // 1. features -> cat (silu'd)
  embed_kernel<<<M, 256, 0, stream>>>(x, emb, reg_w, reg_b, br_w, br_b, mem_w,
                                      mem_b, cat);
  // 2. inst proj: cat[M,576] @ inst_w[512,576]^T + b -> hbuf
  gemm_kernel<float><<<dim3(M / 128, 512 / 128), 256, 0, stream>>>(
      cat, inst_w, inst_b, hbuf, M, 512, 576);
  // 3. LN1 + silu in place
  ln_silu_kernel<<<M, 256, 0, stream>>>(hbuf, ln1_g, ln1_b);
  // 4. qkv proj: hbuf @ qkv_w[1536,512]^T -> qkvb (bf16)
  gemm_kernel<__hip_bfloat16><<<dim3(M / 128, 1536 / 128), 256, 0, stream>>>(
      hbuf, qkv_w, nullptr, qkvb, M, 1536, 512);
  // 5. attention -> att ([M][512], heads concatenated)
  attn_kernel<<<BATCH * 8 * 64, 128, 0, stream>>>(qkvb, att);
  // 6. out proj: att @ outp_w[512,512]^T + b -> pre
  gemm_kernel<float><<<dim3(M / 128, 512 / 128), 256, 0, stream>>>(
      att, outp_w, outp_b, pre, M, 512, 512);
  // 7. LN2 + silu + head + activations -> out
  head_kernel<<<M, 256, 0, stream>>>(pre, ln2_g, ln2_b, head_w, head_b, out);
}

// Round 3
// 1399.536 us; speedup vs baseline: 1.6143x; 1.6143x over previous
//
#include <hip/hip_runtime.h>
#include <hip/hip_bf16.h>
#include <math.h>
#include <type_traits>

#define LSEQ 8192
#define BATCH 4
#define M_TOK (BATCH * LSEQ)

typedef __attribute__((ext_vector_type(8))) short bf16x8;   // 8 bf16 = 4 VGPR
typedef __attribute__((ext_vector_type(4))) float f32x4;

// ---------------------------------------------------------------- helpers
__device__ __forceinline__ float siluf(float x) {
  return x / (1.f + __expf(-x));
}

__device__ __forceinline__ float bf2f(uint u16) {
  union { float f; uint u; } c;
  c.u = u16 << 16;
  return c.f;
}

__device__ __forceinline__ float waveReduceSum(float v) {
#pragma unroll
  for (int off = 32; off; off >>= 1) v += __shfl_xor(v, off, 64);
  return v;
}

// block = 256 threads (4 waves). lds8 must have >= 8 floats.
__device__ __forceinline__ void blockLNStats(float s, float ss, float* lds8,
                                             float& mean, float& rstd) {
  s = waveReduceSum(s);
  ss = waveReduceSum(ss);
  int wave = threadIdx.x >> 6;
  int lane = threadIdx.x & 63;
  if (lane == 0) { lds8[wave] = s; lds8[4 + wave] = ss; }
  __syncthreads();
  s  = lds8[0] + lds8[1] + lds8[2] + lds8[3];
  ss = lds8[4] + lds8[5] + lds8[6] + lds8[7];
  mean = s * (1.f / 512.f);
  float var = ss * (1.f / 512.f) - mean * mean;
  rstd = rsqrtf(var + 1e-5f);
}

// ---------------------------------------------------------------- weights->bf16
__global__ __launch_bounds__(256) void wcvt_kernel(
    const float* __restrict__ a, const float* __restrict__ b,
    const float* __restrict__ c, __hip_bfloat16* __restrict__ o, int na,
    int nb, int nc) {
  int i = blockIdx.x * 256 + threadIdx.x;
  int tot = na + nb + nc;
  if (i >= tot) return;
  float v = (i < na) ? a[i] : ((i < na + nb) ? b[i - na] : c[i - na - nb]);
  o[i] = __float2bfloat16(v);
}

// ---------------------------------------------------------------- kernel 1
// x[M][161] -> cat[M][576] bf16 = silu([emb[tid], reg@Wr^T+b, br@Wb^T+b, mem@Wm^T+b])
__global__ __launch_bounds__(256) void embed_kernel(
    const int* __restrict__ x, const float* __restrict__ emb,
    const float* __restrict__ reg_w, const float* __restrict__ reg_b,
    const float* __restrict__ br_w, const float* __restrict__ br_b,
    const float* __restrict__ mem_w, const float* __restrict__ mem_b,
    __hip_bfloat16* __restrict__ cat) {
  __shared__ float xs[160];
  __shared__ int tok_s;
  const int t = blockIdx.x;
  const int tid = threadIdx.x;
  const int* xr = x + (size_t)t * 161;
  if (tid == 0) tok_s = xr[0];
  if (tid < 160) xs[tid] = (float)xr[1 + tid];
  __syncthreads();
  const int tok = tok_s;
  // xs[0..63]=reg, xs[64..127]=mem, xs[128..159]=br
  for (int c = tid; c < 576; c += 256) {
    float v;
    if (c < 192) {
      v = emb[tok * 192 + c];
    } else if (c < 320) {
      int o = c - 192;
      float s = reg_b[o];
      const float* w = reg_w + o * 64;
#pragma unroll
      for (int j = 0; j < 64; ++j) s = fmaf(w[j], xs[j], s);
      v = s;
    } else if (c < 448) {
      int o = c - 320;
      float s = br_b[o];
      const float* w = br_w + o * 32;
#pragma unroll
      for (int j = 0; j < 32; ++j) s = fmaf(w[j], xs[128 + j], s);
      v = s;
    } else {
      int o = c - 448;
      float s = mem_b[o];
      const float* w = mem_w + o * 64;
#pragma unroll
      for (int j = 0; j < 64; ++j) s = fmaf(w[j], xs[64 + j], s);
      v = s;
    }
    cat[(size_t)t * 576 + c] = __float2bfloat16(siluf(v));
  }
}

// ---------------------------------------------------------------- MFMA GEMM
// C[M][N] = A[M][K](bf16) @ W[N][K](bf16)^T + bias
// 128x128 tile, BK=32, 4 waves each 64x64 (4x4 frags of 16x16x32).
// LDS padded stride 40 elems (80B): 16B-aligned ds_read_b128, ~2-way conflicts.
template <typename OT>
__global__ __launch_bounds__(256) void gemm_mfma(
    const ushort* __restrict__ A, const ushort* __restrict__ W,
    const float* __restrict__ bias, OT* __restrict__ C, int M, int N, int K) {
  constexpr int LDSS = 40;
  __shared__ short As[128 * LDSS];
  __shared__ short Bs[128 * LDSS];
  const int tid = threadIdx.x;
  const int lane = tid & 63;
  const int wid = tid >> 6;
  const int wr = wid >> 1, wc = wid & 1;
  const int row0 = blockIdx.x * 128, col0 = blockIdx.y * 128;
  // staging mapping: 2 threads per row, 32B (16 elems) each
  const int srow = tid >> 1;
  const int scol = (tid & 1) * 16;
  const ushort* Ap = A + (size_t)(row0 + srow) * K + scol;
  const ushort* Wp = W + (size_t)(col0 + srow) * K + scol;
  short* aw = &As[srow * LDSS + scol];
  short* bw = &Bs[srow * LDSS + scol];
  // fragment read mapping
  const int frow = lane & 15;
  const int fk = (lane >> 4) * 8;

  f32x4 acc[4][4];
  const f32x4 z = {0.f, 0.f, 0.f, 0.f};
#pragma unroll
  for (int i = 0; i < 4; ++i)
#pragma unroll
    for (int j = 0; j < 4; ++j) acc[i][j] = z;

  bf16x8 a0 = *(const bf16x8*)(Ap);
  bf16x8 a1 = *(const bf16x8*)(Ap + 8);
  bf16x8 b0 = *(const bf16x8*)(Wp);
  bf16x8 b1 = *(const bf16x8*)(Wp + 8);

  const int T = K >> 5;
  for (int t = 0; t < T; ++t) {
    __syncthreads();
    *(bf16x8*)aw = a0;
    *(bf16x8*)(aw + 8) = a1;
    *(bf16x8*)bw = b0;
    *(bf16x8*)(bw + 8) = b1;
    __syncthreads();
    if (t + 1 < T) {
      const ushort* Ap2 = Ap + (t + 1) * 32;
      const ushort* Wp2 = Wp + (t + 1) * 32;
      a0 = *(const bf16x8*)(Ap2);
      a1 = *(const bf16x8*)(Ap2 + 8);
      b0 = *(const bf16x8*)(Wp2);
      b1 = *(const bf16x8*)(Wp2 + 8);
    }
    bf16x8 af[4], bfr[4];
#pragma unroll
    for (int i = 0; i < 4; ++i)
      af[i] = *(const bf16x8*)&As[(wr * 64 + i * 16 + frow) * LDSS + fk];
#pragma unroll
    for (int j = 0; j < 4; ++j)
      bfr[j] = *(const bf16x8*)&Bs[(wc * 64 + j * 16 + frow) * LDSS + fk];
#pragma unroll
    for (int i = 0; i < 4; ++i)
#pragma unroll
      for (int j = 0; j < 4; ++j)
        acc[i][j] = __builtin_amdgcn_mfma_f32_16x16x32_bf16(af[i], bfr[j],
                                                            acc[i][j], 0, 0, 0);
  }

  // epilogue: C/D layout col=lane&15, row=(lane>>4)*4+reg
  const int crow0 = row0 + wr * 64 + (lane >> 4) * 4;
  const int ccol0 = col0 + wc * 64 + (lane & 15);
#pragma unroll
  for (int j = 0; j < 4; ++j) {
    const int col = ccol0 + j * 16;
    const float bv = bias ? bias[col] : 0.f;
#pragma unroll
    for (int i = 0; i < 4; ++i) {
#pragma unroll
      for (int r = 0; r < 4; ++r) {
        float v = acc[i][j][r] + bv;
        size_t off = (size_t)(crow0 + i * 16 + r) * N + col;
        if constexpr (std::is_same<OT, float>::value) {
          C[off] = v;
        } else {
          C[off] = __float2bfloat16(v);
        }
      }
    }
  }
}

// ---------------------------------------------------------------- kernel 3
// in-place bf16 LN(512) + silu, one token per block (256 thr, 2 feat/thr)
__global__ __launch_bounds__(256) void ln_silu_kernel(
    __hip_bfloat16* __restrict__ buf, const float* __restrict__ g,
    const float* __restrict__ b) {
  __shared__ float lds8[8];
  const int t = blockIdx.x;
  const int tid = threadIdx.x;
  uint u = *(const uint*)&buf[(size_t)t * 512 + tid * 2];
  float x0 = bf2f(u & 0xffffu);
  float x1 = bf2f(u >> 16);
  float mean, rstd;
  blockLNStats(x0 + x1, x0 * x0 + x1 * x1, lds8, mean, rstd);
  float y0 = siluf((x0 - mean) * rstd * g[2 * tid] + b[2 * tid]);
  float y1 = siluf((x1 - mean) * rstd * g[2 * tid + 1] + b[2 * tid + 1]);
  union { __hip_bfloat16 h[2]; uint u; } pk;
  pk.h[0] = __float2bfloat16(y0);
  pk.h[1] = __float2bfloat16(y1);
  *(uint*)&buf[(size_t)t * 512 + tid * 2] = pk.u;
}

// ---------------------------------------------------------------- kernel 4
// sliding-window attention. one block per (b, h, window-block), 128 threads
// = 128 queries. K/V staged in LDS in 64-row chunks; RoPE applied on the fly.
// qkv (bf16) layout per token: [h*192 + d*3 + {0:q,1:k,2:v}]; output bf16.
__global__ __launch_bounds__(128) void attn_kernel(
    const __hip_bfloat16* __restrict__ qkv,
    __hip_bfloat16* __restrict__ o_out) {
  __shared__ float Ks[64][64];
  __shared__ float Vs[64][64];
  const int blk = blockIdx.x;
  const int nbIdx = blk & 63;
  const int h = (blk >> 6) & 7;
  const int b = blk >> 9;
  const int qi = threadIdx.x;  // 0..127
  const size_t seqBase = (size_t)b * LSEQ;
  const int qtok = nbIdx * 128 + qi;
  const size_t qrow = (seqBase + qtok) * 1536 + h * 192;

  // load q with rope
  float q[64];
  const float posq = (float)qtok;
#pragma unroll
  for (int p = 0; p < 32; ++p) {
    float x1 = __bfloat162float(qkv[qrow + 6 * p + 0]);
    float x2 = __bfloat162float(qkv[qrow + 6 * p + 3]);
    float inv = expf(-(float)p * 0.28782313662f);  // ln(10000)/32
    float sn, cs;
    sincosf(posq * inv, &sn, &cs);
    q[2 * p] = x1 * cs - x2 * sn;
    q[2 * p + 1] = x1 * sn + x2 * cs;
  }

  const int kminblk = (nbIdx == 0) ? 128 : 0;
  float m = -3.0e38f, l = 0.f;
  float o[64];
#pragma unroll
  for (int d = 0; d < 64; ++d) o[d] = 0.f;

  for (int c0 = 0; c0 < 256; c0 += 64) {
    if (c0 + 63 < kminblk) continue;  // uniform skip (block 0 prev-window)
    __syncthreads();
    // stage K chunk with rope: 64 rows x 32 pairs
    for (int idx = threadIdx.x; idx < 64 * 32; idx += 128) {
      int row = idx >> 5;
      int p = idx & 31;
      int ktok = (nbIdx - 1) * 128 + c0 + row;  // >=0 in non-skipped chunks
      size_t krow = (seqBase + ktok) * 1536 + h * 192;
      float x1 = __bfloat162float(qkv[krow + 6 * p + 1]);
      float x2 = __bfloat162float(qkv[krow + 6 * p + 4]);
      float inv = expf(-(float)p * 0.28782313662f);
      float sn, cs;
      sincosf((float)ktok * inv, &sn, &cs);
      float2 kv = {x1 * cs - x2 * sn, x1 * sn + x2 * cs};
      *(float2*)&Ks[row][2 * p] = kv;
    }
    // stage V chunk
    for (int idx = threadIdx.x; idx < 64 * 64; idx += 128) {
      int row = idx >> 6;
      int d = idx & 63;
      int ktok = (nbIdx - 1) * 128 + c0 + row;
      Vs[row][d] =
          __bfloat162float(qkv[(seqBase + ktok) * 1536 + h * 192 + 3 * d + 2]);
    }
    __syncthreads();
    for (int kj = c0; kj < c0 + 64; ++kj) {
      const float* kr = &Ks[kj - c0][0];
      float d0 = 0.f, d1 = 0.f, d2 = 0.f, d3 = 0.f;
#pragma unroll
      for (int d = 0; d < 64; d += 4) {
        d0 = fmaf(q[d + 0], kr[d + 0], d0);
        d1 = fmaf(q[d + 1], kr[d + 1], d1);
        d2 = fmaf(q[d + 2], kr[d + 2], d2);
        d3 = fmaf(q[d + 3], kr[d + 3], d3);
      }
      float s = 0.125f * ((d0 + d1) + (d2 + d3));
      // mask: key kj valid for query qi iff qi <= kj <= qi+128
      bool active = (kj >= qi) && (kj <= qi + 128);
      float nm = active ? fmaxf(m, s) : m;
      float r = __expf(m - nm);          // ==1 when m unchanged; 0 on first hit
      float p = active ? __expf(s - nm) : 0.f;
      l = l * r + p;
      const float* vr = &Vs[kj - c0][0];
#pragma unroll
      for (int d = 0; d < 64; ++d) o[d] = fmaf(o[d], r, p * vr[d]);
      m = nm;
    }
  }
  const float rl = 1.f / l;
  const size_t orow = (seqBase + qtok) * 512 + h * 64;
#pragma unroll
  for (int d = 0; d < 64; d += 8) {
    union { __hip_bfloat16 h[8]; uint4 u; } pk;
#pragma unroll
    for (int e = 0; e < 8; ++e) pk.h[e] = __float2bfloat16(o[d + e] * rl);
    *(uint4*)&o_out[orow + d] = pk.u;
  }
}

// ---------------------------------------------------------------- kernel 5
// LN2 + silu + head(9) + activations -> out[M][9]
__global__ __launch_bounds__(256) void head_kernel(
    const float* __restrict__ pre, const float* __restrict__ g,
    const float* __restrict__ b, const float* __restrict__ hw,
    const float* __restrict__ hb, float* __restrict__ out) {
  __shared__ float lds8[8];
  __shared__ float ys[512];
  __shared__ float raw[9];
  const int t = blockIdx.x;
  const int tid = threadIdx.x;
  float2 v = *(const float2*)&pre[(size_t)t * 512 + tid * 2];
  float mean, rstd;
  blockLNStats(v.x + v.y, v.x * v.x + v.y * v.y, lds8, mean, rstd);
  float y0 = (v.x - mean) * rstd * g[2 * tid] + b[2 * tid];
  float y1 = (v.y - mean) * rstd * g[2 * tid + 1] + b[2 * tid + 1];
  ys[2 * tid] = siluf(y0);
  ys[2 * tid + 1] = siluf(y1);
  __syncthreads();
  const int wave = tid >> 6;
  const int lane = tid & 63;
  for (int r = wave; r < 9; r += 4) {
    float p = 0.f;
#pragma unroll
    for (int i = 0; i < 8; ++i)
      p = fmaf(ys[lane + i * 64], hw[r * 512 + lane + i * 64], p);
    p = waveReduceSum(p);
    if (lane == 0) raw[r] = p + hb[r];
  }
  __syncthreads();
  if (tid == 0) {
    float* op = out + (size_t)t * 9;
    op[0] = fmaxf(raw[0], 0.f) + log1pf(expf(-fabsf(raw[0])));
    op[1] = fmaxf(raw[1], 0.f) + log1pf(expf(-fabsf(raw[1])));
    op[2] = 1.f / (1.f + expf(-raw[2]));
    op[3] = 1.f / (1.f + expf(-raw[3]));
    op[4] = 1.f / (1.f + expf(-raw[4]));
    float mx = fmaxf(fmaxf(raw[5], raw[6]), fmaxf(raw[7], raw[8]));
    float e0 = expf(raw[5] - mx), e1 = expf(raw[6] - mx);
    float e2 = expf(raw[7] - mx), e3 = expf(raw[8] - mx);
    float inv = 1.f / (e0 + e1 + e2 + e3);
    op[5] = e0 * inv; op[6] = e1 * inv; op[7] = e2 * inv; op[8] = e3 * inv;
  }
}

// ---------------------------------------------------------------- launch
// Workspace layout (~136 MB peak, regions time-shared per dataflow):
//   [0, 2.7MB)  w16: bf16 weights [inst | qkv | outp]        (whole call)
//   R1 (96MB):  cat bf16 [1-2] -> qkvb bf16 [4-5] -> pre2 fp32 [6-7]
//   R2 (32MB):  hb bf16 [2-4, in-place LN] -> att bf16 [5-6]
extern "C" void kernel_launch(void* const* d_in, const int* in_sizes, int n_in,
                              void* d_out, int out_size, void* d_ws,
                              size_t ws_size, hipStream_t stream) {
  const float* emb = (const float*)d_in[0];
  const float* reg_w = (const float*)d_in[1];
  const float* reg_b = (const float*)d_in[2];
  const float* br_w = (const float*)d_in[3];
  const float* br_b = (const float*)d_in[4];
  const float* mem_w = (const float*)d_in[5];
  const float* mem_b = (const float*)d_in[6];
  const float* inst_w = (const float*)d_in[7];
  const float* inst_b = (const float*)d_in[8];
  const float* ln1_g = (const float*)d_in[9];
  const float* ln1_b = (const float*)d_in[10];
  const float* qkv_w = (const float*)d_in[11];
  const float* outp_w = (const float*)d_in[12];
  const float* outp_b = (const float*)d_in[13];
  const float* ln2_g = (const float*)d_in[14];
  const float* ln2_b = (const float*)d_in[15];
  const float* head_w = (const float*)d_in[16];
  const float* head_b = (const float*)d_in[17];
  const int* x = (const int*)d_in[18];
  float* out = (float*)d_out;

  const int M = M_TOK;
  const int NW1 = 512 * 576, NW2 = 1536 * 512, NW3 = 512 * 512;
  char* wsb = (char*)d_ws;
  __hip_bfloat16* w16 = (__hip_bfloat16*)wsb;
  __hip_bfloat16* w1 = w16;
  __hip_bfloat16* w2 = w16 + NW1;
  __hip_bfloat16* w3 = w16 + NW1 + NW2;
  size_t woff = ((size_t)(NW1 + NW2 + NW3) * 2 + 255) & ~(size_t)255;
  char* r1 = wsb + woff;                       // 96 MB region
  char* r2 = r1 + (size_t)M * 1536 * 2;        // 32 MB region
  __hip_bfloat16* cat = (__hip_bfloat16*)r1;   // M*576
  __hip_bfloat16* qkvb = (__hip_bfloat16*)r1;  // M*1536
  float* pre2 = (float*)r1;                    // M*512 fp32
  __hip_bfloat16* hb = (__hip_bfloat16*)r2;    // M*512
  __hip_bfloat16* att = (__hip_bfloat16*)r2;   // M*512

  // 0. weights -> bf16
  int wtot = NW1 + NW2 + NW3;
  wcvt_kernel<<<(wtot + 255) / 256, 256, 0, stream>>>(inst_w, qkv_w, outp_w,
                                                      w16, NW1, NW2, NW3);
  // 1. features -> cat (silu'd, bf16)
  embed_kernel<<<M, 256, 0, stream>>>(x, emb, reg_w, reg_b, br_w, br_b, mem_w,
                                      mem_b, cat);
  // 2. inst proj: cat @ w1^T + b -> hb (bf16)
  gemm_mfma<__hip_bfloat16><<<dim3(M / 128, 4), 256, 0, stream>>>(
      (const ushort*)cat, (const ushort*)w1, inst_b, hb, M, 512, 576);
  // 3. LN1 + silu in place (bf16)
  ln_silu_kernel<<<M, 256, 0, stream>>>(hb, ln1_g, ln1_b);
  // 4. qkv proj: hb @ w2^T -> qkvb (bf16)
  gemm_mfma<__hip_bfloat16><<<dim3(M / 128, 12), 256, 0, stream>>>(
      (const ushort*)hb, (const ushort*)w2, nullptr, qkvb, M, 1536, 512);
  // 5. attention -> att (bf16, [M][512] heads concatenated)
  attn_kernel<<<BATCH * 8 * 64, 128, 0, stream>>>(qkvb, att);
  // 6. out proj: att @ w3^T + b -> pre2 (fp32)
  gemm_mfma<float><<<dim3(M / 128, 4), 256, 0, stream>>>(
      (const ushort*)att, (const ushort*)w3, outp_b, pre2, M, 512, 512);
  // 7. LN2 + silu + head + activations -> out
  head_kernel<<<M, 256, 0, stream>>>(pre2, ln2_g, ln2_b, head_w, head_b, out);
}

// Round 5
// 868.645 us; speedup vs baseline: 2.6009x; 1.6112x over previous
//
#include <hip/hip_runtime.h>
#include <hip/hip_bf16.h>
#include <math.h>
#include <type_traits>

#define LSEQ 8192
#define BATCH 4
#define M_TOK (BATCH * LSEQ)

typedef __attribute__((ext_vector_type(8))) short bf16x8;   // 8 bf16 = 4 VGPR
typedef __attribute__((ext_vector_type(4))) float f32x4;

// ---------------------------------------------------------------- helpers
__device__ __forceinline__ float siluf(float x) {
  return x / (1.f + __expf(-x));
}

__device__ __forceinline__ float bf2f(uint u16) {
  union { float f; uint u; } c;
  c.u = u16 << 16;
  return c.f;
}

__device__ __forceinline__ float waveReduceSum(float v) {
#pragma unroll
  for (int off = 32; off; off >>= 1) v += __shfl_xor(v, off, 64);
  return v;
}

// block = 256 threads (4 waves). lds8 must have >= 8 floats.
__device__ __forceinline__ void blockLNStats(float s, float ss, float* lds8,
                                             float& mean, float& rstd) {
  s = waveReduceSum(s);
  ss = waveReduceSum(ss);
  int wave = threadIdx.x >> 6;
  int lane = threadIdx.x & 63;
  if (lane == 0) { lds8[wave] = s; lds8[4 + wave] = ss; }
  __syncthreads();
  s  = lds8[0] + lds8[1] + lds8[2] + lds8[3];
  ss = lds8[4] + lds8[5] + lds8[6] + lds8[7];
  mean = s * (1.f / 512.f);
  float var = ss * (1.f / 512.f) - mean * mean;
  rstd = rsqrtf(var + 1e-5f);
}

// ---------------------------------------------------------------- weights->bf16
__global__ __launch_bounds__(256) void wcvt_kernel(
    const float* __restrict__ a, const float* __restrict__ b,
    const float* __restrict__ c, __hip_bfloat16* __restrict__ o, int na,
    int nb, int nc) {
  int i = blockIdx.x * 256 + threadIdx.x;
  int tot = na + nb + nc;
  if (i >= tot) return;
  float v = (i < na) ? a[i] : ((i < na + nb) ? b[i - na] : c[i - na - nb]);
  o[i] = __float2bfloat16(v);
}

// ---------------------------------------------------------------- rope table
// tab[pos*32 + p] = (cos, sin)(pos * 10000^(-p/32)), pos in [0,8192)
__global__ __launch_bounds__(256) void rope_table_kernel(
    float2* __restrict__ tab) {
  int i = blockIdx.x * 256 + threadIdx.x;  // 0 .. 8192*32-1
  int pos = i >> 5, p = i & 31;
  float inv = expf(-(float)p * 0.28782313662f);  // ln(10000)/32
  float sn, cs;
  sincosf((float)pos * inv, &sn, &cs);
  tab[i] = make_float2(cs, sn);
}

// ---------------------------------------------------------------- kernel 1
// x[M][161] -> cat[M][576] bf16 = silu([emb[tid], reg@Wr^T+b, br@Wb^T+b, mem@Wm^T+b])
__global__ __launch_bounds__(256) void embed_kernel(
    const int* __restrict__ x, const float* __restrict__ emb,
    const float* __restrict__ reg_w, const float* __restrict__ reg_b,
    const float* __restrict__ br_w, const float* __restrict__ br_b,
    const float* __restrict__ mem_w, const float* __restrict__ mem_b,
    __hip_bfloat16* __restrict__ cat) {
  __shared__ float xs[160];
  __shared__ int tok_s;
  const int t = blockIdx.x;
  const int tid = threadIdx.x;
  const int* xr = x + (size_t)t * 161;
  if (tid == 0) tok_s = xr[0];
  if (tid < 160) xs[tid] = (float)xr[1 + tid];
  __syncthreads();
  const int tok = tok_s;
  // xs[0..63]=reg, xs[64..127]=mem, xs[128..159]=br
  for (int c = tid; c < 576; c += 256) {
    float v;
    if (c < 192) {
      v = emb[tok * 192 + c];
    } else if (c < 320) {
      int o = c - 192;
      float s = reg_b[o];
      const float* w = reg_w + o * 64;
#pragma unroll
      for (int j = 0; j < 64; ++j) s = fmaf(w[j], xs[j], s);
      v = s;
    } else if (c < 448) {
      int o = c - 320;
      float s = br_b[o];
      const float* w = br_w + o * 32;
#pragma unroll
      for (int j = 0; j < 32; ++j) s = fmaf(w[j], xs[128 + j], s);
      v = s;
    } else {
      int o = c - 448;
      float s = mem_b[o];
      const float* w = mem_w + o * 64;
#pragma unroll
      for (int j = 0; j < 64; ++j) s = fmaf(w[j], xs[64 + j], s);
      v = s;
    }
    cat[(size_t)t * 576 + c] = __float2bfloat16(siluf(v));
  }
}

// ---------------------------------------------------------------- MFMA GEMM
// C[M][N] = A[M][K](bf16) @ W[N][K](bf16)^T + bias
// 128x128 tile, BK=32, 4 waves each 64x64 (4x4 frags of 16x16x32).
template <typename OT>
__global__ __launch_bounds__(256) void gemm_mfma(
    const ushort* __restrict__ A, const ushort* __restrict__ W,
    const float* __restrict__ bias, OT* __restrict__ C, int M, int N, int K) {
  constexpr int LDSS = 40;
  __shared__ short As[128 * LDSS];
  __shared__ short Bs[128 * LDSS];
  const int tid = threadIdx.x;
  const int lane = tid & 63;
  const int wid = tid >> 6;
  const int wr = wid >> 1, wc = wid & 1;
  const int row0 = blockIdx.x * 128, col0 = blockIdx.y * 128;
  const int srow = tid >> 1;
  const int scol = (tid & 1) * 16;
  const ushort* Ap = A + (size_t)(row0 + srow) * K + scol;
  const ushort* Wp = W + (size_t)(col0 + srow) * K + scol;
  short* aw = &As[srow * LDSS + scol];
  short* bw = &Bs[srow * LDSS + scol];
  const int frow = lane & 15;
  const int fk = (lane >> 4) * 8;

  f32x4 acc[4][4];
  const f32x4 z = {0.f, 0.f, 0.f, 0.f};
#pragma unroll
  for (int i = 0; i < 4; ++i)
#pragma unroll
    for (int j = 0; j < 4; ++j) acc[i][j] = z;

  bf16x8 a0 = *(const bf16x8*)(Ap);
  bf16x8 a1 = *(const bf16x8*)(Ap + 8);
  bf16x8 b0 = *(const bf16x8*)(Wp);
  bf16x8 b1 = *(const bf16x8*)(Wp + 8);

  const int T = K >> 5;
  for (int t = 0; t < T; ++t) {
    __syncthreads();
    *(bf16x8*)aw = a0;
    *(bf16x8*)(aw + 8) = a1;
    *(bf16x8*)bw = b0;
    *(bf16x8*)(bw + 8) = b1;
    __syncthreads();
    if (t + 1 < T) {
      const ushort* Ap2 = Ap + (t + 1) * 32;
      const ushort* Wp2 = Wp + (t + 1) * 32;
      a0 = *(const bf16x8*)(Ap2);
      a1 = *(const bf16x8*)(Ap2 + 8);
      b0 = *(const bf16x8*)(Wp2);
      b1 = *(const bf16x8*)(Wp2 + 8);
    }
    bf16x8 af[4], bfr[4];
#pragma unroll
    for (int i = 0; i < 4; ++i)
      af[i] = *(const bf16x8*)&As[(wr * 64 + i * 16 + frow) * LDSS + fk];
#pragma unroll
    for (int j = 0; j < 4; ++j)
      bfr[j] = *(const bf16x8*)&Bs[(wc * 64 + j * 16 + frow) * LDSS + fk];
#pragma unroll
    for (int i = 0; i < 4; ++i)
#pragma unroll
      for (int j = 0; j < 4; ++j)
        acc[i][j] = __builtin_amdgcn_mfma_f32_16x16x32_bf16(af[i], bfr[j],
                                                            acc[i][j], 0, 0, 0);
  }

  const int crow0 = row0 + wr * 64 + (lane >> 4) * 4;
  const int ccol0 = col0 + wc * 64 + (lane & 15);
#pragma unroll
  for (int j = 0; j < 4; ++j) {
    const int col = ccol0 + j * 16;
    const float bv = bias ? bias[col] : 0.f;
#pragma unroll
    for (int i = 0; i < 4; ++i) {
#pragma unroll
      for (int r = 0; r < 4; ++r) {
        float v = acc[i][j][r] + bv;
        size_t off = (size_t)(crow0 + i * 16 + r) * N + col;
        if constexpr (std::is_same<OT, float>::value) {
          C[off] = v;
        } else {
          C[off] = __float2bfloat16(v);
        }
      }
    }
  }
}

// ---------------------------------------------------------------- kernel 3
// in-place bf16 LN(512) + silu, one token per block (256 thr, 2 feat/thr)
__global__ __launch_bounds__(256) void ln_silu_kernel(
    __hip_bfloat16* __restrict__ buf, const float* __restrict__ g,
    const float* __restrict__ b) {
  __shared__ float lds8[8];
  const int t = blockIdx.x;
  const int tid = threadIdx.x;
  uint u = *(const uint*)&buf[(size_t)t * 512 + tid * 2];
  float x0 = bf2f(u & 0xffffu);
  float x1 = bf2f(u >> 16);
  float mean, rstd;
  blockLNStats(x0 + x1, x0 * x0 + x1 * x1, lds8, mean, rstd);
  float y0 = siluf((x0 - mean) * rstd * g[2 * tid] + b[2 * tid]);
  float y1 = siluf((x1 - mean) * rstd * g[2 * tid + 1] + b[2 * tid + 1]);
  union { __hip_bfloat16 h[2]; uint u; } pk;
  pk.h[0] = __float2bfloat16(y0);
  pk.h[1] = __float2bfloat16(y1);
  *(uint*)&buf[(size_t)t * 512 + tid * 2] = pk.u;
}

// ---------------------------------------------------------------- kernel 4
// sliding-window attention v2 (fixed key range 0..255).
// block = 256 thr per (b,h,window-block): 128 queries x 2 d-halves.
// K/V staged in LDS in 32-row chunks (16KB); RoPE from precomputed table.
// Online softmax with deferred-max (threshold 8, wave-uniform trigger).
// qkv (bf16) layout per token: [h*192 + d*3 + {0:q,1:k,2:v}]; output bf16.
__global__ __launch_bounds__(256) void attn_kernel(
    const __hip_bfloat16* __restrict__ qkv, const float2* __restrict__ tab,
    __hip_bfloat16* __restrict__ o_out) {
  __shared__ float Ks[32][64];
  __shared__ float Vs[32][64];
  const int blk = blockIdx.x;
  const int nbIdx = blk & 63;
  const int h = (blk >> 6) & 7;
  const int b = blk >> 9;
  const int tid = threadIdx.x;
  const int qi = tid >> 1;    // 0..127 query within window block
  const int half = tid & 1;   // owns dims [half*32, half*32+32)
  const size_t seqBase = (size_t)b * LSEQ;
  const int qtok = nbIdx * 128 + qi;
  const size_t qrow = (seqBase + qtok) * 1536 + h * 192;
  const int qmin = (tid >> 6) * 32;  // wave's lowest query index

  // load q half with rope (pairs p = half*16+pp -> local dims 2pp,2pp+1)
  float q[32];
  const float2* qt = tab + qtok * 32;
#pragma unroll
  for (int pp = 0; pp < 16; ++pp) {
    int p = half * 16 + pp;
    float x1 = __bfloat162float(qkv[qrow + 6 * p + 0]);
    float x2 = __bfloat162float(qkv[qrow + 6 * p + 3]);
    float2 cs = qt[p];
    q[2 * pp] = x1 * cs.x - x2 * cs.y;
    q[2 * pp + 1] = x1 * cs.y + x2 * cs.x;
  }

  const int kminblk = (nbIdx == 0) ? 128 : 0;
  float m0 = -3.0e38f, l = 0.f;
  float o[32];
#pragma unroll
  for (int d = 0; d < 32; ++d) o[d] = 0.f;

  // key axis is 256 wide: prev window [0,128) + current window [128,256)
  for (int c0 = 0; c0 < 256; c0 += 32) {
    if (c0 + 31 < kminblk) continue;  // block-uniform skip (nbIdx==0 prev win)
    __syncthreads();
    // stage K chunk with rope: 32 rows x 32 pairs
    for (int idx = tid; idx < 32 * 32; idx += 256) {
      int row = idx >> 5;
      int p = idx & 31;
      int ktok = (nbIdx - 1) * 128 + c0 + row;  // >=0 in non-skipped chunks
      size_t krow = (seqBase + ktok) * 1536 + h * 192;
      float x1 = __bfloat162float(qkv[krow + 6 * p + 1]);
      float x2 = __bfloat162float(qkv[krow + 6 * p + 4]);
      float2 cs = tab[ktok * 32 + p];
      Ks[row][2 * p] = x1 * cs.x - x2 * cs.y;
      Ks[row][2 * p + 1] = x1 * cs.y + x2 * cs.x;
    }
    // stage V chunk: 32 rows x 64 dims
    for (int idx = tid; idx < 32 * 64; idx += 256) {
      int row = idx >> 6;
      int d = idx & 63;
      int ktok = (nbIdx - 1) * 128 + c0 + row;
      Vs[row][d] =
          __bfloat162float(qkv[(seqBase + ktok) * 1536 + h * 192 + 3 * d + 2]);
    }
    __syncthreads();
    // wave-uniform: does this wave (queries [qmin, qmin+31]) need this chunk?
    if (c0 + 31 >= qmin && c0 <= qmin + 159) {
      for (int r = 0; r < 32; ++r) {
        const int kjg = c0 + r;  // key index in [0,256)
        const float* kr = &Ks[r][half * 32];
        float sp = 0.f;
#pragma unroll
        for (int d = 0; d < 32; ++d) sp = fmaf(q[d], kr[d], sp);
        float s = (sp + __shfl_xor(sp, 1)) * 0.125f;
        // mask: key kjg valid for query qi iff qi <= kjg <= qi+128
        bool active = (kjg >= qi) && (kjg <= qi + 128);
        if (__any(active && (s > m0 + 8.f))) {  // deferred-max rescale
          float nm = active ? fmaxf(m0, s) : m0;
          float rr = __expf(m0 - nm);  // 1 if unchanged; 0 on first activation
          l *= rr;
#pragma unroll
          for (int d = 0; d < 32; ++d) o[d] *= rr;
          m0 = nm;
        }
        float p = active ? __expf(s - m0) : 0.f;  // bounded by e^8
        l += p;
        const float* vr = &Vs[r][half * 32];
#pragma unroll
        for (int d = 0; d < 32; ++d) o[d] = fmaf(p, vr[d], o[d]);
      }
    }
  }
  const float rl = 1.f / l;
  const size_t orow = (seqBase + qtok) * 512 + h * 64 + half * 32;
#pragma unroll
  for (int d = 0; d < 32; d += 8) {
    union { __hip_bfloat16 h[8]; uint4 u; } pk;
#pragma unroll
    for (int e = 0; e < 8; ++e) pk.h[e] = __float2bfloat16(o[d + e] * rl);
    *(uint4*)&o_out[orow + d] = pk.u;
  }
}

// ---------------------------------------------------------------- kernel 5
// LN2 + silu + head(9) + activations -> out[M][9]
__global__ __launch_bounds__(256) void head_kernel(
    const float* __restrict__ pre, const float* __restrict__ g,
    const float* __restrict__ b, const float* __restrict__ hw,
    const float* __restrict__ hb, float* __restrict__ out) {
  __shared__ float lds8[8];
  __shared__ float ys[512];
  __shared__ float raw[9];
  const int t = blockIdx.x;
  const int tid = threadIdx.x;
  float2 v = *(const float2*)&pre[(size_t)t * 512 + tid * 2];
  float mean, rstd;
  blockLNStats(v.x + v.y, v.x * v.x + v.y * v.y, lds8, mean, rstd);
  float y0 = (v.x - mean) * rstd * g[2 * tid] + b[2 * tid];
  float y1 = (v.y - mean) * rstd * g[2 * tid + 1] + b[2 * tid + 1];
  ys[2 * tid] = siluf(y0);
  ys[2 * tid + 1] = siluf(y1);
  __syncthreads();
  const int wave = tid >> 6;
  const int lane = tid & 63;
  for (int r = wave; r < 9; r += 4) {
    float p = 0.f;
#pragma unroll
    for (int i = 0; i < 8; ++i)
      p = fmaf(ys[lane + i * 64], hw[r * 512 + lane + i * 64], p);
    p = waveReduceSum(p);
    if (lane == 0) raw[r] = p + hb[r];
  }
  __syncthreads();
  if (tid == 0) {
    float* op = out + (size_t)t * 9;
    op[0] = fmaxf(raw[0], 0.f) + log1pf(expf(-fabsf(raw[0])));
    op[1] = fmaxf(raw[1], 0.f) + log1pf(expf(-fabsf(raw[1])));
    op[2] = 1.f / (1.f + expf(-raw[2]));
    op[3] = 1.f / (1.f + expf(-raw[3]));
    op[4] = 1.f / (1.f + expf(-raw[4]));
    float mx = fmaxf(fmaxf(raw[5], raw[6]), fmaxf(raw[7], raw[8]));
    float e0 = expf(raw[5] - mx), e1 = expf(raw[6] - mx);
    float e2 = expf(raw[7] - mx), e3 = expf(raw[8] - mx);
    float inv = 1.f / (e0 + e1 + e2 + e3);
    op[5] = e0 * inv; op[6] = e1 * inv; op[7] = e2 * inv; op[8] = e3 * inv;
  }
}

// ---------------------------------------------------------------- launch
// Workspace layout (~133 MB peak, regions time-shared per dataflow):
//   [0, 2.7MB)   w16: bf16 weights [inst | qkv | outp]   (whole call)
//   [2.7, 4.7MB) rope table float2[8192*32]              (whole call)
//   R1 (96MB):   cat bf16 [1-2] -> qkvb bf16 [4-5] -> pre2 fp32 [6-7]
//   R2 (32MB):   hb bf16 [2-4, in-place LN] -> att bf16 [5-6]
extern "C" void kernel_launch(void* const* d_in, const int* in_sizes, int n_in,
                              void* d_out, int out_size, void* d_ws,
                              size_t ws_size, hipStream_t stream) {
  const float* emb = (const float*)d_in[0];
  const float* reg_w = (const float*)d_in[1];
  const float* reg_b = (const float*)d_in[2];
  const float* br_w = (const float*)d_in[3];
  const float* br_b = (const float*)d_in[4];
  const float* mem_w = (const float*)d_in[5];
  const float* mem_b = (const float*)d_in[6];
  const float* inst_w = (const float*)d_in[7];
  const float* inst_b = (const float*)d_in[8];
  const float* ln1_g = (const float*)d_in[9];
  const float* ln1_b = (const float*)d_in[10];
  const float* qkv_w = (const float*)d_in[11];
  const float* outp_w = (const float*)d_in[12];
  const float* outp_b = (const float*)d_in[13];
  const float* ln2_g = (const float*)d_in[14];
  const float* ln2_b = (const float*)d_in[15];
  const float* head_w = (const float*)d_in[16];
  const float* head_b = (const float*)d_in[17];
  const int* x = (const int*)d_in[18];
  float* out = (float*)d_out;

  const int M = M_TOK;
  const int NW1 = 512 * 576, NW2 = 1536 * 512, NW3 = 512 * 512;
  char* wsb = (char*)d_ws;
  __hip_bfloat16* w16 = (__hip_bfloat16*)wsb;
  __hip_bfloat16* w1 = w16;
  __hip_bfloat16* w2 = w16 + NW1;
  __hip_bfloat16* w3 = w16 + NW1 + NW2;
  size_t woff = ((size_t)(NW1 + NW2 + NW3) * 2 + 255) & ~(size_t)255;
  float2* tab = (float2*)(wsb + woff);         // 8192*32 float2 = 2MB
  size_t toff = woff + (size_t)8192 * 32 * 8;
  char* r1 = wsb + toff;                       // 96 MB region
  char* r2 = r1 + (size_t)M * 1536 * 2;        // 32 MB region
  __hip_bfloat16* cat = (__hip_bfloat16*)r1;   // M*576
  __hip_bfloat16* qkvb = (__hip_bfloat16*)r1;  // M*1536
  float* pre2 = (float*)r1;                    // M*512 fp32
  __hip_bfloat16* hb = (__hip_bfloat16*)r2;    // M*512
  __hip_bfloat16* att = (__hip_bfloat16*)r2;   // M*512

  // 0. weights -> bf16 ; rope table
  int wtot = NW1 + NW2 + NW3;
  wcvt_kernel<<<(wtot + 255) / 256, 256, 0, stream>>>(inst_w, qkv_w, outp_w,
                                                      w16, NW1, NW2, NW3);
  rope_table_kernel<<<(8192 * 32) / 256, 256, 0, stream>>>(tab);
  // 1. features -> cat (silu'd, bf16)
  embed_kernel<<<M, 256, 0, stream>>>(x, emb, reg_w, reg_b, br_w, br_b, mem_w,
                                      mem_b, cat);
  // 2. inst proj: cat @ w1^T + b -> hb (bf16)
  gemm_mfma<__hip_bfloat16><<<dim3(M / 128, 4), 256, 0, stream>>>(
      (const ushort*)cat, (const ushort*)w1, inst_b, hb, M, 512, 576);
  // 3. LN1 + silu in place (bf16)
  ln_silu_kernel<<<M, 256, 0, stream>>>(hb, ln1_g, ln1_b);
  // 4. qkv proj: hb @ w2^T -> qkvb (bf16)
  gemm_mfma<__hip_bfloat16><<<dim3(M / 128, 12), 256, 0, stream>>>(
      (const ushort*)hb, (const ushort*)w2, nullptr, qkvb, M, 1536, 512);
  // 5. attention -> att (bf16, [M][512] heads concatenated)
  attn_kernel<<<BATCH * 8 * 64, 256, 0, stream>>>(qkvb, tab, att);
  // 6. out proj: att @ w3^T + b -> pre2 (fp32)
  gemm_mfma<float><<<dim3(M / 128, 4), 256, 0, stream>>>(
      (const ushort*)att, (const ushort*)w3, outp_b, pre2, M, 512, 512);
  // 7. LN2 + silu + head + activations -> out
  head_kernel<<<M, 256, 0, stream>>>(pre2, ln2_g, ln2_b, head_w, head_b, out);
}

// Round 6
// 590.060 us; speedup vs baseline: 3.8288x; 1.4721x over previous
//
#include <hip/hip_runtime.h>
#include <hip/hip_bf16.h>
#include <math.h>
#include <type_traits>

#define LSEQ 8192
#define BATCH 4
#define M_TOK (BATCH * LSEQ)

typedef __attribute__((ext_vector_type(8))) short bf16x8;   // 8 bf16 = 4 VGPR
typedef __attribute__((ext_vector_type(4))) float f32x4;

// ---------------------------------------------------------------- helpers
__device__ __forceinline__ float siluf(float x) {
  return x / (1.f + __expf(-x));
}

__device__ __forceinline__ float bf2f(uint u16) {
  union { float f; uint u; } c;
  c.u = u16 << 16;
  return c.f;
}

__device__ __forceinline__ float waveReduceSum(float v) {
#pragma unroll
  for (int off = 32; off; off >>= 1) v += __shfl_xor(v, off, 64);
  return v;
}

// block = 256 threads (4 waves). lds8 must have >= 8 floats.
__device__ __forceinline__ void blockLNStats(float s, float ss, float* lds8,
                                             float& mean, float& rstd) {
  s = waveReduceSum(s);
  ss = waveReduceSum(ss);
  int wave = threadIdx.x >> 6;
  int lane = threadIdx.x & 63;
  if (lane == 0) { lds8[wave] = s; lds8[4 + wave] = ss; }
  __syncthreads();
  s  = lds8[0] + lds8[1] + lds8[2] + lds8[3];
  ss = lds8[4] + lds8[5] + lds8[6] + lds8[7];
  mean = s * (1.f / 512.f);
  float var = ss * (1.f / 512.f) - mean * mean;
  rstd = rsqrtf(var + 1e-5f);
}

// ---------------------------------------------------------------- weights->bf16
__global__ __launch_bounds__(256) void wcvt_kernel(
    const float* __restrict__ a, const float* __restrict__ b,
    const float* __restrict__ c, __hip_bfloat16* __restrict__ o, int na,
    int nb, int nc) {
  int i = blockIdx.x * 256 + threadIdx.x;
  int tot = na + nb + nc;
  if (i >= tot) return;
  float v = (i < na) ? a[i] : ((i < na + nb) ? b[i - na] : c[i - na - nb]);
  o[i] = __float2bfloat16(v);
}

// ---------------------------------------------------------------- Wcat build
// Wcat[384][192] bf16. F cols: [0]=1(bias), [1..64]=reg, [65..128]=mem,
// [129..160]=br, [161..191]=0. Rows: [0,128)=reg out, [128,256)=br out,
// [256,384)=mem out (matching cat col order 192+o).
__global__ __launch_bounds__(256) void wcat_kernel(
    const float* __restrict__ reg_w, const float* __restrict__ reg_b,
    const float* __restrict__ br_w, const float* __restrict__ br_b,
    const float* __restrict__ mem_w, const float* __restrict__ mem_b,
    __hip_bfloat16* __restrict__ Wc) {
  int i = blockIdx.x * 256 + threadIdx.x;
  if (i >= 384 * 192) return;
  int o = i / 192, c = i % 192;
  float v = 0.f;
  if (o < 128) {
    if (c == 0) v = reg_b[o];
    else if (c <= 64) v = reg_w[o * 64 + (c - 1)];
  } else if (o < 256) {
    int oo = o - 128;
    if (c == 0) v = br_b[oo];
    else if (c >= 129 && c <= 160) v = br_w[oo * 32 + (c - 129)];
  } else {
    int oo = o - 256;
    if (c == 0) v = mem_b[oo];
    else if (c >= 65 && c <= 128) v = mem_w[oo * 64 + (c - 65)];
  }
  Wc[i] = __float2bfloat16(v);
}

// ---------------------------------------------------------------- rope table
// tab[pos*32 + p] = (cos, sin)(pos * 10000^(-p/32)), pos in [0,8192)
__global__ __launch_bounds__(256) void rope_table_kernel(
    float2* __restrict__ tab) {
  int i = blockIdx.x * 256 + threadIdx.x;  // 0 .. 8192*32-1
  int pos = i >> 5, p = i & 31;
  float inv = expf(-(float)p * 0.28782313662f);  // ln(10000)/32
  float sn, cs;
  sincosf((float)pos * inv, &sn, &cs);
  tab[i] = make_float2(cs, sn);
}

// ---------------------------------------------------------------- prep
// Per token t: cat[t][0..191] = silu(emb[tok]) bf16; Fb[t][0..191] =
// [1, x[t][1..160], 0...] bf16 (exact: feats are 0/1 ints).
// gid = t*48 + g ; g<24 -> cat octet, g>=24 -> Fb octet.
__global__ __launch_bounds__(256) void prep_kernel(
    const int* __restrict__ x, const float* __restrict__ emb,
    __hip_bfloat16* __restrict__ cat, __hip_bfloat16* __restrict__ Fb) {
  int gid = blockIdx.x * 256 + threadIdx.x;
  int t = gid / 48;
  int g = gid % 48;
  if (t >= M_TOK) return;
  const int* xr = x + (size_t)t * 161;
  union { __hip_bfloat16 h[8]; uint4 u; } pk;
  if (g < 24) {
    int c0 = g * 8;
    const float* e = emb + xr[0] * 192 + c0;
#pragma unroll
    for (int j = 0; j < 8; ++j) pk.h[j] = __float2bfloat16(siluf(e[j]));
    *(uint4*)&cat[(size_t)t * 576 + c0] = pk.u;
  } else {
    int c0 = (g - 24) * 8;
#pragma unroll
    for (int j = 0; j < 8; ++j) {
      int c = c0 + j;
      float v = (c == 0) ? 1.f : ((c <= 160) ? (float)xr[c] : 0.f);
      pk.h[j] = __float2bfloat16(v);
    }
    *(uint4*)&Fb[(size_t)t * 192 + c0] = pk.u;
  }
}

// ---------------------------------------------------------------- MFMA GEMM
// C[r*ldc + col0..] = A[M][K](bf16) @ W[N][K](bf16)^T + bias, opt. silu.
// 128x128 tile, BK=32, 4 waves each 64x64 (4x4 frags of 16x16x32).
template <typename OT, bool SILU = false>
__global__ __launch_bounds__(256) void gemm_mfma(
    const ushort* __restrict__ A, const ushort* __restrict__ W,
    const float* __restrict__ bias, OT* __restrict__ C, int M, int N, int K,
    int ldc) {
  constexpr int LDSS = 40;
  __shared__ short As[128 * LDSS];
  __shared__ short Bs[128 * LDSS];
  const int tid = threadIdx.x;
  const int lane = tid & 63;
  const int wid = tid >> 6;
  const int wr = wid >> 1, wc = wid & 1;
  const int row0 = blockIdx.x * 128, col0 = blockIdx.y * 128;
  const int srow = tid >> 1;
  const int scol = (tid & 1) * 16;
  const ushort* Ap = A + (size_t)(row0 + srow) * K + scol;
  const ushort* Wp = W + (size_t)(col0 + srow) * K + scol;
  short* aw = &As[srow * LDSS + scol];
  short* bw = &Bs[srow * LDSS + scol];
  const int frow = lane & 15;
  const int fk = (lane >> 4) * 8;

  f32x4 acc[4][4];
  const f32x4 z = {0.f, 0.f, 0.f, 0.f};
#pragma unroll
  for (int i = 0; i < 4; ++i)
#pragma unroll
    for (int j = 0; j < 4; ++j) acc[i][j] = z;

  bf16x8 a0 = *(const bf16x8*)(Ap);
  bf16x8 a1 = *(const bf16x8*)(Ap + 8);
  bf16x8 b0 = *(const bf16x8*)(Wp);
  bf16x8 b1 = *(const bf16x8*)(Wp + 8);

  const int T = K >> 5;
  for (int t = 0; t < T; ++t) {
    __syncthreads();
    *(bf16x8*)aw = a0;
    *(bf16x8*)(aw + 8) = a1;
    *(bf16x8*)bw = b0;
    *(bf16x8*)(bw + 8) = b1;
    __syncthreads();
    if (t + 1 < T) {
      const ushort* Ap2 = Ap + (t + 1) * 32;
      const ushort* Wp2 = Wp + (t + 1) * 32;
      a0 = *(const bf16x8*)(Ap2);
      a1 = *(const bf16x8*)(Ap2 + 8);
      b0 = *(const bf16x8*)(Wp2);
      b1 = *(const bf16x8*)(Wp2 + 8);
    }
    bf16x8 af[4], bfr[4];
#pragma unroll
    for (int i = 0; i < 4; ++i)
      af[i] = *(const bf16x8*)&As[(wr * 64 + i * 16 + frow) * LDSS + fk];
#pragma unroll
    for (int j = 0; j < 4; ++j)
      bfr[j] = *(const bf16x8*)&Bs[(wc * 64 + j * 16 + frow) * LDSS + fk];
#pragma unroll
    for (int i = 0; i < 4; ++i)
#pragma unroll
      for (int j = 0; j < 4; ++j)
        acc[i][j] = __builtin_amdgcn_mfma_f32_16x16x32_bf16(af[i], bfr[j],
                                                            acc[i][j], 0, 0, 0);
  }

  const int crow0 = row0 + wr * 64 + (lane >> 4) * 4;
  const int ccol0 = col0 + wc * 64 + (lane & 15);
#pragma unroll
  for (int j = 0; j < 4; ++j) {
    const int col = ccol0 + j * 16;
    const float bv = bias ? bias[col] : 0.f;
#pragma unroll
    for (int i = 0; i < 4; ++i) {
#pragma unroll
      for (int r = 0; r < 4; ++r) {
        float v = acc[i][j][r] + bv;
        if constexpr (SILU) v = siluf(v);
        size_t off = (size_t)(crow0 + i * 16 + r) * ldc + col;
        if constexpr (std::is_same<OT, float>::value) {
          C[off] = v;
        } else {
          C[off] = __float2bfloat16(v);
        }
      }
    }
  }
}

// ---------------------------------------------------------------- kernel 3
// in-place bf16 LN(512) + silu, one token per block (256 thr, 2 feat/thr)
__global__ __launch_bounds__(256) void ln_silu_kernel(
    __hip_bfloat16* __restrict__ buf, const float* __restrict__ g,
    const float* __restrict__ b) {
  __shared__ float lds8[8];
  const int t = blockIdx.x;
  const int tid = threadIdx.x;
  uint u = *(const uint*)&buf[(size_t)t * 512 + tid * 2];
  float x0 = bf2f(u & 0xffffu);
  float x1 = bf2f(u >> 16);
  float mean, rstd;
  blockLNStats(x0 + x1, x0 * x0 + x1 * x1, lds8, mean, rstd);
  float y0 = siluf((x0 - mean) * rstd * g[2 * tid] + b[2 * tid]);
  float y1 = siluf((x1 - mean) * rstd * g[2 * tid + 1] + b[2 * tid + 1]);
  union { __hip_bfloat16 h[2]; uint u; } pk;
  pk.h[0] = __float2bfloat16(y0);
  pk.h[1] = __float2bfloat16(y1);
  *(uint*)&buf[(size_t)t * 512 + tid * 2] = pk.u;
}

// ---------------------------------------------------------------- kernel 4
// sliding-window attention v3: float4 LDS reads (ds_read_b128).
// block = 256 thr per (b,h,window-block): 128 queries x 2 d-halves.
// K/V staged in LDS in 32-row chunks; RoPE from precomputed table.
// Online softmax with deferred-max (threshold 8, wave-uniform trigger).
__global__ __launch_bounds__(256) void attn_kernel(
    const __hip_bfloat16* __restrict__ qkv, const float2* __restrict__ tab,
    __hip_bfloat16* __restrict__ o_out) {
  __shared__ float Ks[32][64];
  __shared__ float Vs[32][64];
  const int blk = blockIdx.x;
  const int nbIdx = blk & 63;
  const int h = (blk >> 6) & 7;
  const int b = blk >> 9;
  const int tid = threadIdx.x;
  const int qi = tid >> 1;    // 0..127 query within window block
  const int half = tid & 1;   // owns dims [half*32, half*32+32)
  const size_t seqBase = (size_t)b * LSEQ;
  const int qtok = nbIdx * 128 + qi;
  const size_t qrow = (seqBase + qtok) * 1536 + h * 192;
  const int qmin = (tid >> 6) * 32;  // wave's lowest query index

  // load q half with rope (pairs p = half*16+pp -> local dims 2pp,2pp+1)
  float q[32];
  const float2* qt = tab + qtok * 32;
#pragma unroll
  for (int pp = 0; pp < 16; ++pp) {
    int p = half * 16 + pp;
    float x1 = __bfloat162float(qkv[qrow + 6 * p + 0]);
    float x2 = __bfloat162float(qkv[qrow + 6 * p + 3]);
    float2 cs = qt[p];
    q[2 * pp] = x1 * cs.x - x2 * cs.y;
    q[2 * pp + 1] = x1 * cs.y + x2 * cs.x;
  }

  const int kminblk = (nbIdx == 0) ? 128 : 0;
  float m0 = -3.0e38f, l = 0.f;
  float o[32];
#pragma unroll
  for (int d = 0; d < 32; ++d) o[d] = 0.f;

  // key axis is 256 wide: prev window [0,128) + current window [128,256)
  for (int c0 = 0; c0 < 256; c0 += 32) {
    if (c0 + 31 < kminblk) continue;  // block-uniform skip (nbIdx==0 prev win)
    __syncthreads();
    // stage K chunk with rope: 32 rows x 32 pairs
    for (int idx = tid; idx < 32 * 32; idx += 256) {
      int row = idx >> 5;
      int p = idx & 31;
      int ktok = (nbIdx - 1) * 128 + c0 + row;  // >=0 in non-skipped chunks
      size_t krow = (seqBase + ktok) * 1536 + h * 192;
      float x1 = __bfloat162float(qkv[krow + 6 * p + 1]);
      float x2 = __bfloat162float(qkv[krow + 6 * p + 4]);
      float2 cs = tab[ktok * 32 + p];
      Ks[row][2 * p] = x1 * cs.x - x2 * cs.y;
      Ks[row][2 * p + 1] = x1 * cs.y + x2 * cs.x;
    }
    // stage V chunk: 32 rows x 64 dims
    for (int idx = tid; idx < 32 * 64; idx += 256) {
      int row = idx >> 6;
      int d = idx & 63;
      int ktok = (nbIdx - 1) * 128 + c0 + row;
      Vs[row][d] =
          __bfloat162float(qkv[(seqBase + ktok) * 1536 + h * 192 + 3 * d + 2]);
    }
    __syncthreads();
    // wave-uniform: does this wave (queries [qmin, qmin+31]) need this chunk?
    if (c0 + 31 >= qmin && c0 <= qmin + 159) {
      for (int r = 0; r < 32; ++r) {
        const int kjg = c0 + r;  // key index in [0,256)
        const float4* kr4 = (const float4*)&Ks[r][half * 32];
        float sp = 0.f;
#pragma unroll
        for (int dd = 0; dd < 8; ++dd) {
          float4 kv = kr4[dd];
          sp = fmaf(q[4 * dd + 0], kv.x, sp);
          sp = fmaf(q[4 * dd + 1], kv.y, sp);
          sp = fmaf(q[4 * dd + 2], kv.z, sp);
          sp = fmaf(q[4 * dd + 3], kv.w, sp);
        }
        float s = (sp + __shfl_xor(sp, 1)) * 0.125f;
        // mask: key kjg valid for query qi iff qi <= kjg <= qi+128
        bool active = (kjg >= qi) && (kjg <= qi + 128);
        if (__any(active && (s > m0 + 8.f))) {  // deferred-max rescale
          float nm = active ? fmaxf(m0, s) : m0;
          float rr = __expf(m0 - nm);  // 1 if unchanged; 0 on first activation
          l *= rr;
#pragma unroll
          for (int d = 0; d < 32; ++d) o[d] *= rr;
          m0 = nm;
        }
        float p = active ? __expf(s - m0) : 0.f;  // bounded by e^8
        l += p;
        const float4* vr4 = (const float4*)&Vs[r][half * 32];
#pragma unroll
        for (int dd = 0; dd < 8; ++dd) {
          float4 vv = vr4[dd];
          o[4 * dd + 0] = fmaf(p, vv.x, o[4 * dd + 0]);
          o[4 * dd + 1] = fmaf(p, vv.y, o[4 * dd + 1]);
          o[4 * dd + 2] = fmaf(p, vv.z, o[4 * dd + 2]);
          o[4 * dd + 3] = fmaf(p, vv.w, o[4 * dd + 3]);
        }
      }
    }
  }
  const float rl = 1.f / l;
  const size_t orow = (seqBase + qtok) * 512 + h * 64 + half * 32;
#pragma unroll
  for (int d = 0; d < 32; d += 8) {
    union { __hip_bfloat16 h[8]; uint4 u; } pk;
#pragma unroll
    for (int e = 0; e < 8; ++e) pk.h[e] = __float2bfloat16(o[d + e] * rl);
    *(uint4*)&o_out[orow + d] = pk.u;
  }
}

// ---------------------------------------------------------------- kernel 5
// LN2 + silu + head(9) + activations -> out[M][9]
__global__ __launch_bounds__(256) void head_kernel(
    const float* __restrict__ pre, const float* __restrict__ g,
    const float* __restrict__ b, const float* __restrict__ hw,
    const float* __restrict__ hb, float* __restrict__ out) {
  __shared__ float lds8[8];
  __shared__ float ys[512];
  __shared__ float raw[9];
  const int t = blockIdx.x;
  const int tid = threadIdx.x;
  float2 v = *(const float2*)&pre[(size_t)t * 512 + tid * 2];
  float mean, rstd;
  blockLNStats(v.x + v.y, v.x * v.x + v.y * v.y, lds8, mean, rstd);
  float y0 = (v.x - mean) * rstd * g[2 * tid] + b[2 * tid];
  float y1 = (v.y - mean) * rstd * g[2 * tid + 1] + b[2 * tid + 1];
  ys[2 * tid] = siluf(y0);
  ys[2 * tid + 1] = siluf(y1);
  __syncthreads();
  const int wave = tid >> 6;
  const int lane = tid & 63;
  for (int r = wave; r < 9; r += 4) {
    float p = 0.f;
#pragma unroll
    for (int i = 0; i < 8; ++i)
      p = fmaf(ys[lane + i * 64], hw[r * 512 + lane + i * 64], p);
    p = waveReduceSum(p);
    if (lane == 0) raw[r] = p + hb[r];
  }
  __syncthreads();
  if (tid == 0) {
    float* op = out + (size_t)t * 9;
    op[0] = fmaxf(raw[0], 0.f) + log1pf(expf(-fabsf(raw[0])));
    op[1] = fmaxf(raw[1], 0.f) + log1pf(expf(-fabsf(raw[1])));
    op[2] = 1.f / (1.f + expf(-raw[2]));
    op[3] = 1.f / (1.f + expf(-raw[3]));
    op[4] = 1.f / (1.f + expf(-raw[4]));
    float mx = fmaxf(fmaxf(raw[5], raw[6]), fmaxf(raw[7], raw[8]));
    float e0 = expf(raw[5] - mx), e1 = expf(raw[6] - mx);
    float e2 = expf(raw[7] - mx), e3 = expf(raw[8] - mx);
    float inv = 1.f / (e0 + e1 + e2 + e3);
    op[5] = e0 * inv; op[6] = e1 * inv; op[7] = e2 * inv; op[8] = e3 * inv;
  }
}

// ---------------------------------------------------------------- launch
// Workspace layout (~133 MB peak, regions time-shared per dataflow):
//   [0, ~2.9MB)  w16: bf16 [inst | qkv | outp | wcat]    (whole call)
//   [+2MB)       rope table float2[8192*32]              (whole call)
//   R1 (96MB):   {cat bf16 M*576 | Fb bf16 M*192} [1-2]
//                -> qkvb bf16 M*1536 [4-5] -> pre2 fp32 M*512 [6-7]
//   R2 (32MB):   hb bf16 [2-4, in-place LN] -> att bf16 [5-6]
extern "C" void kernel_launch(void* const* d_in, const int* in_sizes, int n_in,
                              void* d_out, int out_size, void* d_ws,
                              size_t ws_size, hipStream_t stream) {
  const float* emb = (const float*)d_in[0];
  const float* reg_w = (const float*)d_in[1];
  const float* reg_b = (const float*)d_in[2];
  const float* br_w = (const float*)d_in[3];
  const float* br_b = (const float*)d_in[4];
  const float* mem_w = (const float*)d_in[5];
  const float* mem_b = (const float*)d_in[6];
  const float* inst_w = (const float*)d_in[7];
  const float* inst_b = (const float*)d_in[8];
  const float* ln1_g = (const float*)d_in[9];
  const float* ln1_b = (const float*)d_in[10];
  const float* qkv_w = (const float*)d_in[11];
  const float* outp_w = (const float*)d_in[12];
  const float* outp_b = (const float*)d_in[13];
  const float* ln2_g = (const float*)d_in[14];
  const float* ln2_b = (const float*)d_in[15];
  const float* head_w = (const float*)d_in[16];
  const float* head_b = (const float*)d_in[17];
  const int* x = (const int*)d_in[18];
  float* out = (float*)d_out;

  const int M = M_TOK;
  const int NW1 = 512 * 576, NW2 = 1536 * 512, NW3 = 512 * 512;
  const int NW4 = 384 * 192;
  char* wsb = (char*)d_ws;
  __hip_bfloat16* w16 = (__hip_bfloat16*)wsb;
  __hip_bfloat16* w1 = w16;
  __hip_bfloat16* w2 = w16 + NW1;
  __hip_bfloat16* w3 = w16 + NW1 + NW2;
  __hip_bfloat16* wcat = w16 + NW1 + NW2 + NW3;
  size_t woff = ((size_t)(NW1 + NW2 + NW3 + NW4) * 2 + 255) & ~(size_t)255;
  float2* tab = (float2*)(wsb + woff);         // 8192*32 float2 = 2MB
  size_t toff = woff + (size_t)8192 * 32 * 8;
  char* r1 = wsb + toff;                       // 96 MB region
  char* r2 = r1 + (size_t)M * 1536 * 2;        // 32 MB region
  __hip_bfloat16* cat = (__hip_bfloat16*)r1;   // M*576
  __hip_bfloat16* Fb = (__hip_bfloat16*)(r1 + (size_t)M * 576 * 2);  // M*192
  __hip_bfloat16* qkvb = (__hip_bfloat16*)r1;  // M*1536 (covers cat+Fb later)
  float* pre2 = (float*)r1;                    // M*512 fp32
  __hip_bfloat16* hb = (__hip_bfloat16*)r2;    // M*512
  __hip_bfloat16* att = (__hip_bfloat16*)r2;   // M*512

  // 0. weights -> bf16 ; Wcat ; rope table
  int wtot = NW1 + NW2 + NW3;
  wcvt_kernel<<<(wtot + 255) / 256, 256, 0, stream>>>(inst_w, qkv_w, outp_w,
                                                      w16, NW1, NW2, NW3);
  wcat_kernel<<<(NW4 + 255) / 256, 256, 0, stream>>>(reg_w, reg_b, br_w, br_b,
                                                     mem_w, mem_b, wcat);
  rope_table_kernel<<<(8192 * 32) / 256, 256, 0, stream>>>(tab);
  // 1. prep: cat[:,0:192] = silu(emb[tid]) ; Fb = [1, feats, 0]
  prep_kernel<<<(M * 48) / 256, 256, 0, stream>>>(x, emb, cat, Fb);
  // 1b. feature proj: cat[:,192:576] = silu(Fb @ wcat^T)
  gemm_mfma<__hip_bfloat16, true><<<dim3(M / 128, 3), 256, 0, stream>>>(
      (const ushort*)Fb, (const ushort*)wcat, nullptr, cat + 192, M, 384, 192,
      576);
  // 2. inst proj: cat @ w1^T + b -> hb (bf16)
  gemm_mfma<__hip_bfloat16><<<dim3(M / 128, 4), 256, 0, stream>>>(
      (const ushort*)cat, (const ushort*)w1, inst_b, hb, M, 512, 576, 512);
  // 3. LN1 + silu in place (bf16)
  ln_silu_kernel<<<M, 256, 0, stream>>>(hb, ln1_g, ln1_b);
  // 4. qkv proj: hb @ w2^T -> qkvb (bf16)
  gemm_mfma<__hip_bfloat16><<<dim3(M / 128, 12), 256, 0, stream>>>(
      (const ushort*)hb, (const ushort*)w2, nullptr, qkvb, M, 1536, 512, 1536);
  // 5. attention -> att (bf16, [M][512] heads concatenated)
  attn_kernel<<<BATCH * 8 * 64, 256, 0, stream>>>(qkvb, tab, att);
  // 6. out proj: att @ w3^T + b -> pre2 (fp32)
  gemm_mfma<float><<<dim3(M / 128, 4), 256, 0, stream>>>(
      (const ushort*)att, (const ushort*)w3, outp_b, pre2, M, 512, 512, 512);
  // 7. LN2 + silu + head + activations -> out
  head_kernel<<<M, 256, 0, stream>>>(pre2, ln2_g, ln2_b, head_w, head_b, out);
}

// Round 7
// 372.260 us; speedup vs baseline: 6.0690x; 1.5851x over previous
//
#include <hip/hip_runtime.h>
#include <hip/hip_bf16.h>
#include <math.h>
#include <type_traits>

#define LSEQ 8192
#define BATCH 4
#define M_TOK (BATCH * LSEQ)

typedef __attribute__((ext_vector_type(8))) short bf16x8;   // 8 bf16 = 4 VGPR
typedef __attribute__((ext_vector_type(4))) float f32x4;
typedef __attribute__((ext_vector_type(16))) float f32x16;

// ---------------------------------------------------------------- helpers
__device__ __forceinline__ float siluf(float x) {
  return x / (1.f + __expf(-x));
}

__device__ __forceinline__ float bf2f(uint u16) {
  union { float f; uint u; } c;
  c.u = u16 << 16;
  return c.f;
}

__device__ __forceinline__ uint cvtpk_bf16(float lo, float hi) {
  uint r;
  asm volatile("v_cvt_pk_bf16_f32 %0, %1, %2" : "=v"(r) : "v"(lo), "v"(hi));
  return r;
}

// swaps hi 32 lanes of a with lo 32 lanes of b
__device__ __forceinline__ void perm32swap(uint& a, uint& b) {
  asm volatile("v_permlane32_swap_b32 %0, %1" : "+v"(a), "+v"(b));
}

__device__ __forceinline__ float waveReduceSum(float v) {
#pragma unroll
  for (int off = 32; off; off >>= 1) v += __shfl_xor(v, off, 64);
  return v;
}

__device__ __forceinline__ void blockLNStats(float s, float ss, float* lds8,
                                             float& mean, float& rstd) {
  s = waveReduceSum(s);
  ss = waveReduceSum(ss);
  int wave = threadIdx.x >> 6;
  int lane = threadIdx.x & 63;
  if (lane == 0) { lds8[wave] = s; lds8[4 + wave] = ss; }
  __syncthreads();
  s  = lds8[0] + lds8[1] + lds8[2] + lds8[3];
  ss = lds8[4] + lds8[5] + lds8[6] + lds8[7];
  mean = s * (1.f / 512.f);
  float var = ss * (1.f / 512.f) - mean * mean;
  rstd = rsqrtf(var + 1e-5f);
}

// ---------------------------------------------------------------- weights->bf16
__global__ __launch_bounds__(256) void wcvt_kernel(
    const float* __restrict__ a, const float* __restrict__ b,
    __hip_bfloat16* __restrict__ o, int na, int nb) {
  int i = blockIdx.x * 256 + threadIdx.x;
  if (i >= na + nb) return;
  float v = (i < na) ? a[i] : b[i - na];
  o[i] = __float2bfloat16(v);
}

// qkv weight with ROW PERMUTATION: output row n' = which*512 + h*64 + d
// maps from src row n = h*192 + d*3 + which. Result: qkvb GEMM output has
// 3 contiguous planes per token: [Q(512) | K(512) | V(512)], col h*64+d.
__global__ __launch_bounds__(256) void wqkv_kernel(
    const float* __restrict__ qkv_w, __hip_bfloat16* __restrict__ w2) {
  int i = blockIdx.x * 256 + threadIdx.x;
  if (i >= 1536 * 512) return;
  int np = i / 512, k = i % 512;
  int which = np >> 9, rem = np & 511;
  int h = rem >> 6, d = rem & 63;
  int n = h * 192 + d * 3 + which;
  w2[i] = __float2bfloat16(qkv_w[n * 512 + k]);
}

// ---------------------------------------------------------------- Wcat build
// Wcat[384][192] bf16. F cols: [0]=1(bias), [1..64]=reg, [65..128]=mem,
// [129..160]=br, [161..191]=0.
__global__ __launch_bounds__(256) void wcat_kernel(
    const float* __restrict__ reg_w, const float* __restrict__ reg_b,
    const float* __restrict__ br_w, const float* __restrict__ br_b,
    const float* __restrict__ mem_w, const float* __restrict__ mem_b,
    __hip_bfloat16* __restrict__ Wc) {
  int i = blockIdx.x * 256 + threadIdx.x;
  if (i >= 384 * 192) return;
  int o = i / 192, c = i % 192;
  float v = 0.f;
  if (o < 128) {
    if (c == 0) v = reg_b[o];
    else if (c <= 64) v = reg_w[o * 64 + (c - 1)];
  } else if (o < 256) {
    int oo = o - 128;
    if (c == 0) v = br_b[oo];
    else if (c >= 129 && c <= 160) v = br_w[oo * 32 + (c - 129)];
  } else {
    int oo = o - 256;
    if (c == 0) v = mem_b[oo];
    else if (c >= 65 && c <= 128) v = mem_w[oo * 64 + (c - 65)];
  }
  Wc[i] = __float2bfloat16(v);
}

// ---------------------------------------------------------------- rope table
__global__ __launch_bounds__(256) void rope_table_kernel(
    float2* __restrict__ tab) {
  int i = blockIdx.x * 256 + threadIdx.x;  // 0 .. 8192*32-1
  int pos = i >> 5, p = i & 31;
  float inv = expf(-(float)p * 0.28782313662f);  // ln(10000)/32
  float sn, cs;
  sincosf((float)pos * inv, &sn, &cs);
  tab[i] = make_float2(cs, sn);
}

// ---------------------------------------------------------------- prep
__global__ __launch_bounds__(256) void prep_kernel(
    const int* __restrict__ x, const float* __restrict__ emb,
    __hip_bfloat16* __restrict__ cat, __hip_bfloat16* __restrict__ Fb) {
  int gid = blockIdx.x * 256 + threadIdx.x;
  int t = gid / 48;
  int g = gid % 48;
  if (t >= M_TOK) return;
  const int* xr = x + (size_t)t * 161;
  union { __hip_bfloat16 h[8]; uint4 u; } pk;
  if (g < 24) {
    int c0 = g * 8;
    const float* e = emb + xr[0] * 192 + c0;
#pragma unroll
    for (int j = 0; j < 8; ++j) pk.h[j] = __float2bfloat16(siluf(e[j]));
    *(uint4*)&cat[(size_t)t * 576 + c0] = pk.u;
  } else {
    int c0 = (g - 24) * 8;
#pragma unroll
    for (int j = 0; j < 8; ++j) {
      int c = c0 + j;
      float v = (c == 0) ? 1.f : ((c <= 160) ? (float)xr[c] : 0.f);
      pk.h[j] = __float2bfloat16(v);
    }
    *(uint4*)&Fb[(size_t)t * 192 + c0] = pk.u;
  }
}

// ---------------------------------------------------------------- MFMA GEMM
template <typename OT, bool SILU = false>
__global__ __launch_bounds__(256) void gemm_mfma(
    const ushort* __restrict__ A, const ushort* __restrict__ W,
    const float* __restrict__ bias, OT* __restrict__ C, int M, int N, int K,
    int ldc) {
  constexpr int LDSS = 40;
  __shared__ short As[128 * LDSS];
  __shared__ short Bs[128 * LDSS];
  const int tid = threadIdx.x;
  const int lane = tid & 63;
  const int wid = tid >> 6;
  const int wr = wid >> 1, wc = wid & 1;
  const int row0 = blockIdx.x * 128, col0 = blockIdx.y * 128;
  const int srow = tid >> 1;
  const int scol = (tid & 1) * 16;
  const ushort* Ap = A + (size_t)(row0 + srow) * K + scol;
  const ushort* Wp = W + (size_t)(col0 + srow) * K + scol;
  short* aw = &As[srow * LDSS + scol];
  short* bw = &Bs[srow * LDSS + scol];
  const int frow = lane & 15;
  const int fk = (lane >> 4) * 8;

  f32x4 acc[4][4];
  const f32x4 z = {0.f, 0.f, 0.f, 0.f};
#pragma unroll
  for (int i = 0; i < 4; ++i)
#pragma unroll
    for (int j = 0; j < 4; ++j) acc[i][j] = z;

  bf16x8 a0 = *(const bf16x8*)(Ap);
  bf16x8 a1 = *(const bf16x8*)(Ap + 8);
  bf16x8 b0 = *(const bf16x8*)(Wp);
  bf16x8 b1 = *(const bf16x8*)(Wp + 8);

  const int T = K >> 5;
  for (int t = 0; t < T; ++t) {
    __syncthreads();
    *(bf16x8*)aw = a0;
    *(bf16x8*)(aw + 8) = a1;
    *(bf16x8*)bw = b0;
    *(bf16x8*)(bw + 8) = b1;
    __syncthreads();
    if (t + 1 < T) {
      const ushort* Ap2 = Ap + (t + 1) * 32;
      const ushort* Wp2 = Wp + (t + 1) * 32;
      a0 = *(const bf16x8*)(Ap2);
      a1 = *(const bf16x8*)(Ap2 + 8);
      b0 = *(const bf16x8*)(Wp2);
      b1 = *(const bf16x8*)(Wp2 + 8);
    }
    bf16x8 af[4], bfr[4];
#pragma unroll
    for (int i = 0; i < 4; ++i)
      af[i] = *(const bf16x8*)&As[(wr * 64 + i * 16 + frow) * LDSS + fk];
#pragma unroll
    for (int j = 0; j < 4; ++j)
      bfr[j] = *(const bf16x8*)&Bs[(wc * 64 + j * 16 + frow) * LDSS + fk];
#pragma unroll
    for (int i = 0; i < 4; ++i)
#pragma unroll
      for (int j = 0; j < 4; ++j)
        acc[i][j] = __builtin_amdgcn_mfma_f32_16x16x32_bf16(af[i], bfr[j],
                                                            acc[i][j], 0, 0, 0);
  }

  const int crow0 = row0 + wr * 64 + (lane >> 4) * 4;
  const int ccol0 = col0 + wc * 64 + (lane & 15);
#pragma unroll
  for (int j = 0; j < 4; ++j) {
    const int col = ccol0 + j * 16;
    const float bv = bias ? bias[col] : 0.f;
#pragma unroll
    for (int i = 0; i < 4; ++i) {
#pragma unroll
      for (int r = 0; r < 4; ++r) {
        float v = acc[i][j][r] + bv;
        if constexpr (SILU) v = siluf(v);
        size_t off = (size_t)(crow0 + i * 16 + r) * ldc + col;
        if constexpr (std::is_same<OT, float>::value) {
          C[off] = v;
        } else {
          C[off] = __float2bfloat16(v);
        }
      }
    }
  }
}

// ---------------------------------------------------------------- kernel 3
__global__ __launch_bounds__(256) void ln_silu_kernel(
    __hip_bfloat16* __restrict__ buf, const float* __restrict__ g,
    const float* __restrict__ b) {
  __shared__ float lds8[8];
  const int t = blockIdx.x;
  const int tid = threadIdx.x;
  uint u = *(const uint*)&buf[(size_t)t * 512 + tid * 2];
  float x0 = bf2f(u & 0xffffu);
  float x1 = bf2f(u >> 16);
  float mean, rstd;
  blockLNStats(x0 + x1, x0 * x0 + x1 * x1, lds8, mean, rstd);
  float y0 = siluf((x0 - mean) * rstd * g[2 * tid] + b[2 * tid]);
  float y1 = siluf((x1 - mean) * rstd * g[2 * tid + 1] + b[2 * tid + 1]);
  union { __hip_bfloat16 h[2]; uint u; } pk;
  pk.h[0] = __float2bfloat16(y0);
  pk.h[1] = __float2bfloat16(y1);
  *(uint*)&buf[(size_t)t * 512 + tid * 2] = pk.u;
}

// ---------------------------------------------------------------- attn (MFMA)
// One block per (b,h,window-block): 4 waves x 32 queries. KV chunks of 64 keys.
// qkvb planes per token row (1536): [Q 0..511 | K 512..1023 | V 1024..1535],
// col within plane = h*64 + d.
// Swapped QK^T: S^T[key,q] = mfma(A=K rows, B=Q). C layout: col=lane&31 (=q),
// row = (r&3)+8*(r>>2)+4*hi (=key within 32-tile). P relayout to PV A-frag via
// cvt_pk_bf16 + permlane32_swap. V transposed in LDS for PV B-frag b128 reads.
__global__ __launch_bounds__(256) void attn_kernel(
    const __hip_bfloat16* __restrict__ qkv, const float2* __restrict__ tab,
    __hip_bfloat16* __restrict__ o_out) {
  __shared__ __align__(16) short Kc[64 * 72];   // [key 64][dim 64 pad 72]
  __shared__ __align__(16) short Vt[64 * 72];   // [dim 64][key 64 pad 72]
  __shared__ __align__(16) float rbuf[4][32];
  const int blk = blockIdx.x;
  const int nbIdx = blk & 63;
  const int h = (blk >> 6) & 7;
  const int b = blk >> 9;
  const int tid = threadIdx.x;
  const int w = tid >> 6;
  const int lane = tid & 63;
  const int lq = lane & 31;
  const int hi = lane >> 5;
  const size_t seqBase = (size_t)b * LSEQ;
  const int qi = w * 32 + lq;           // query index within window block
  const int qtok = nbIdx * 128 + qi;

  const ushort* qkvu = (const ushort*)qkv;

  // ---- load Q fragments (B-operand), rope + 1/8 scale folded in
  bf16x8 qf[4];
  {
    const ushort* Qrow = qkvu + (seqBase + qtok) * 1536 + h * 64;
#pragma unroll
    for (int s = 0; s < 4; ++s) {
      int dim0 = 16 * s + 8 * hi;
      bf16x8 qv = *(const bf16x8*)(Qrow + dim0);
      const float4* tp = (const float4*)(tab + qtok * 32 + dim0 / 2);
      float4 t01 = tp[0], t23 = tp[1];
      float cs[4] = {t01.x, t01.z, t23.x, t23.z};
      float sn[4] = {t01.y, t01.w, t23.y, t23.w};
      union { uint u[4]; bf16x8 v; } pk;
#pragma unroll
      for (int j = 0; j < 4; ++j) {
        float x1 = bf2f((ushort)qv[2 * j]);
        float x2 = bf2f((ushort)qv[2 * j + 1]);
        float r0 = (x1 * cs[j] - x2 * sn[j]) * 0.125f;
        float r1 = (x1 * sn[j] + x2 * cs[j]) * 0.125f;
        pk.u[j] = cvtpk_bf16(r0, r1);
      }
      qf[s] = pk.v;
    }
  }

  const f32x16 Z16 = {0.f};
  f32x16 oa0 = Z16, oa1 = Z16;       // O accum, d-tiles 0 (d=lq) and 1 (d=32+lq)
  float m0 = -3.0e38f, l = 0.f;

  const int cstart = (nbIdx == 0) ? 2 : 0;       // chunks of 64 keys, axis 256
  const int cw0 = (w >= 2) ? 1 : 0;              // wave needs chunks cw0..cw1
  const int cw1 = (w >= 2) ? 3 : 2;

  // staging thread mapping: 4 threads per key row, 16 dims each
  const int skk = tid >> 2;
  const int sd0 = (tid & 3) * 16;

  for (int c = cstart; c < 4; ++c) {
    __syncthreads();
    // ---- stage K chunk (rope'd) and V chunk (transposed)
    {
      int ktok = (nbIdx - 1) * 128 + c * 64 + skk;
      const ushort* Krow = qkvu + (seqBase + ktok) * 1536 + 512 + h * 64;
      const ushort* Vrow = qkvu + (seqBase + ktok) * 1536 + 1024 + h * 64;
      int swk = ((skk >> 3) & 3) << 5;
#pragma unroll
      for (int hh = 0; hh < 2; ++hh) {
        int dim0 = sd0 + 8 * hh;
        bf16x8 kv = *(const bf16x8*)(Krow + dim0);
        const float4* tp = (const float4*)(tab + ktok * 32 + dim0 / 2);
        float4 t01 = tp[0], t23 = tp[1];
        float cs[4] = {t01.x, t01.z, t23.x, t23.z};
        float sn[4] = {t01.y, t01.w, t23.y, t23.w};
        union { uint u[4]; bf16x8 v; } pk;
#pragma unroll
        for (int j = 0; j < 4; ++j) {
          float x1 = bf2f((ushort)kv[2 * j]);
          float x2 = bf2f((ushort)kv[2 * j + 1]);
          pk.u[j] = cvtpk_bf16(x1 * cs[j] - x2 * sn[j],
                               x1 * sn[j] + x2 * cs[j]);
        }
        *(bf16x8*)((char*)Kc + skk * 144 + ((dim0 * 2) ^ swk)) = pk.v;
        // V: transpose write (16 scalar b16 per thread over both hh)
        bf16x8 vv = *(const bf16x8*)(Vrow + dim0);
#pragma unroll
        for (int j = 0; j < 8; ++j) {
          int d = dim0 + j;
          int swv = ((d >> 3) & 3) << 5;
          *(short*)((char*)Vt + d * 144 + ((skk * 2) ^ swv)) = vv[j];
        }
      }
    }
    __syncthreads();
    if (c < cw0 || c > cw1) continue;

    // ---- QK^T (swapped): S^T tiles for key-subtiles t2=0,1
    bf16x8 ka[2][4];
#pragma unroll
    for (int t2 = 0; t2 < 2; ++t2)
#pragma unroll
      for (int s = 0; s < 4; ++s) {
        int kk = 32 * t2 + lq;
        int byteoff = kk * 144 + (((32 * s + 16 * hi)) ^ (((kk >> 3) & 3) << 5));
        ka[t2][s] = *(const bf16x8*)((const char*)Kc + byteoff);
      }
    f32x16 st0 = Z16, st1 = Z16;
#pragma unroll
    for (int s = 0; s < 4; ++s) {
      st0 = __builtin_amdgcn_mfma_f32_32x32x16_bf16(ka[0][s], qf[s], st0, 0, 0, 0);
      st1 = __builtin_amdgcn_mfma_f32_32x32x16_bf16(ka[1][s], qf[s], st1, 0, 0, 0);
    }

    // ---- masked online softmax (deferred max)
    float p2[2][16];
    float pmax = -3.0e38f;
#pragma unroll
    for (int t2 = 0; t2 < 2; ++t2)
#pragma unroll
      for (int r = 0; r < 16; ++r) {
        int key = c * 64 + 32 * t2 + (r & 3) + 8 * (r >> 2) + 4 * hi;
        float sv = (t2 ? st1[r] : st0[r]);
        bool act = (key >= qi) && (key <= qi + 128);
        sv = act ? sv : -1.0e30f;
        p2[t2][r] = sv;
        pmax = fmaxf(pmax, sv);
      }
    pmax = fmaxf(pmax, __shfl_xor(pmax, 32));
    if (__any(pmax > m0 + 8.f)) {
      float nm = fmaxf(m0, pmax);
      float rr = __expf(m0 - nm);
      l *= rr;
      m0 = nm;
      rbuf[w][lq] = rr;
      asm volatile("s_waitcnt lgkmcnt(0)" ::: "memory");
#pragma unroll
      for (int a = 0; a < 4; ++a) {
        f32x4 r4 = *(const f32x4*)&rbuf[w][8 * a + 4 * hi];
#pragma unroll
        for (int j = 0; j < 4; ++j) {
          oa0[4 * a + j] *= r4[j];
          oa1[4 * a + j] *= r4[j];
        }
      }
    }
    float lsum = 0.f;
#pragma unroll
    for (int t2 = 0; t2 < 2; ++t2)
#pragma unroll
      for (int r = 0; r < 16; ++r) {
        float p = __expf(p2[t2][r] - m0);
        p2[t2][r] = p;
        lsum += p;
      }
    l += lsum + __shfl_xor(lsum, 32);

    // ---- P relayout: cvt_pk + permlane32_swap -> PV A-frags (4 slots)
    union { uint u[4]; bf16x8 v; } pa[4];
#pragma unroll
    for (int t2 = 0; t2 < 2; ++t2)
#pragma unroll
      for (int sl = 0; sl < 2; ++sl) {
        const float* pp = &p2[t2][8 * sl];
        uint a0 = cvtpk_bf16(pp[0], pp[1]);
        uint a1 = cvtpk_bf16(pp[2], pp[3]);
        uint b0 = cvtpk_bf16(pp[4], pp[5]);
        uint b1 = cvtpk_bf16(pp[6], pp[7]);
        perm32swap(a0, b0);
        perm32swap(a1, b1);
        int slot = 2 * t2 + sl;
        pa[slot].u[0] = a0; pa[slot].u[1] = a1;
        pa[slot].u[2] = b0; pa[slot].u[3] = b1;
      }

    // ---- PV: O += P x V  (B-frag = Vt rows, contiguous b128)
#pragma unroll
    for (int slot = 0; slot < 4; ++slot) {
      {
        int d = lq;
        int byteoff = d * 144 + ((32 * slot + 16 * hi) ^ (((d >> 3) & 3) << 5));
        bf16x8 vb = *(const bf16x8*)((const char*)Vt + byteoff);
        oa0 = __builtin_amdgcn_mfma_f32_32x32x16_bf16(pa[slot].v, vb, oa0, 0, 0, 0);
      }
      {
        int d = 32 + lq;
        int byteoff = d * 144 + ((32 * slot + 16 * hi) ^ (((d >> 3) & 3) << 5));
        bf16x8 vb = *(const bf16x8*)((const char*)Vt + byteoff);
        oa1 = __builtin_amdgcn_mfma_f32_32x32x16_bf16(pa[slot].v, vb, oa1, 0, 0, 0);
      }
    }
  }

  // ---- normalize and store
  rbuf[w][lq] = 1.f / l;
  asm volatile("s_waitcnt lgkmcnt(0)" ::: "memory");
  const int q0 = nbIdx * 128 + 32 * w;
#pragma unroll
  for (int a = 0; a < 4; ++a) {
    f32x4 r4 = *(const f32x4*)&rbuf[w][8 * a + 4 * hi];
#pragma unroll
    for (int j = 0; j < 4; ++j) {
      int tok = q0 + 8 * a + 4 * hi + j;
      __hip_bfloat16* orow = o_out + (seqBase + tok) * 512 + h * 64;
      orow[lq] = __float2bfloat16(oa0[4 * a + j] * r4[j]);
      orow[32 + lq] = __float2bfloat16(oa1[4 * a + j] * r4[j]);
    }
  }
}

// ---------------------------------------------------------------- kernel 5
__global__ __launch_bounds__(256) void head_kernel(
    const float* __restrict__ pre, const float* __restrict__ g,
    const float* __restrict__ b, const float* __restrict__ hw,
    const float* __restrict__ hb, float* __restrict__ out) {
  __shared__ float lds8[8];
  __shared__ float ys[512];
  __shared__ float raw[9];
  const int t = blockIdx.x;
  const int tid = threadIdx.x;
  float2 v = *(const float2*)&pre[(size_t)t * 512 + tid * 2];
  float mean, rstd;
  blockLNStats(v.x + v.y, v.x * v.x + v.y * v.y, lds8, mean, rstd);
  float y0 = (v.x - mean) * rstd * g[2 * tid] + b[2 * tid];
  float y1 = (v.y - mean) * rstd * g[2 * tid + 1] + b[2 * tid + 1];
  ys[2 * tid] = siluf(y0);
  ys[2 * tid + 1] = siluf(y1);
  __syncthreads();
  const int wave = tid >> 6;
  const int lane = tid & 63;
  for (int r = wave; r < 9; r += 4) {
    float p = 0.f;
#pragma unroll
    for (int i = 0; i < 8; ++i)
      p = fmaf(ys[lane + i * 64], hw[r * 512 + lane + i * 64], p);
    p = waveReduceSum(p);
    if (lane == 0) raw[r] = p + hb[r];
  }
  __syncthreads();
  if (tid == 0) {
    float* op = out + (size_t)t * 9;
    op[0] = fmaxf(raw[0], 0.f) + log1pf(expf(-fabsf(raw[0])));
    op[1] = fmaxf(raw[1], 0.f) + log1pf(expf(-fabsf(raw[1])));
    op[2] = 1.f / (1.f + expf(-raw[2]));
    op[3] = 1.f / (1.f + expf(-raw[3]));
    op[4] = 1.f / (1.f + expf(-raw[4]));
    float mx = fmaxf(fmaxf(raw[5], raw[6]), fmaxf(raw[7], raw[8]));
    float e0 = expf(raw[5] - mx), e1 = expf(raw[6] - mx);
    float e2 = expf(raw[7] - mx), e3 = expf(raw[8] - mx);
    float inv = 1.f / (e0 + e1 + e2 + e3);
    op[5] = e0 * inv; op[6] = e1 * inv; op[7] = e2 * inv; op[8] = e3 * inv;
  }
}

// ---------------------------------------------------------------- launch
// Workspace layout (~133 MB peak):
//   w16: bf16 [inst | outp | qkv(permuted) | wcat] ; rope table (2MB)
//   R1 (96MB): {cat M*576 | Fb M*192} -> qkvb M*1536 -> pre2 fp32 M*512
//   R2 (32MB): hb bf16 [in-place LN] -> att bf16
extern "C" void kernel_launch(void* const* d_in, const int* in_sizes, int n_in,
                              void* d_out, int out_size, void* d_ws,
                              size_t ws_size, hipStream_t stream) {
  const float* emb = (const float*)d_in[0];
  const float* reg_w = (const float*)d_in[1];
  const float* reg_b = (const float*)d_in[2];
  const float* br_w = (const float*)d_in[3];
  const float* br_b = (const float*)d_in[4];
  const float* mem_w = (const float*)d_in[5];
  const float* mem_b = (const float*)d_in[6];
  const float* inst_w = (const float*)d_in[7];
  const float* inst_b = (const float*)d_in[8];
  const float* ln1_g = (const float*)d_in[9];
  const float* ln1_b = (const float*)d_in[10];
  const float* qkv_w = (const float*)d_in[11];
  const float* outp_w = (const float*)d_in[12];
  const float* outp_b = (const float*)d_in[13];
  const float* ln2_g = (const float*)d_in[14];
  const float* ln2_b = (const float*)d_in[15];
  const float* head_w = (const float*)d_in[16];
  const float* head_b = (const float*)d_in[17];
  const int* x = (const int*)d_in[18];
  float* out = (float*)d_out;

  const int M = M_TOK;
  const int NW1 = 512 * 576, NW2 = 1536 * 512, NW3 = 512 * 512;
  const int NW4 = 384 * 192;
  char* wsb = (char*)d_ws;
  __hip_bfloat16* w16 = (__hip_bfloat16*)wsb;
  __hip_bfloat16* w1 = w16;                        // inst
  __hip_bfloat16* w3 = w16 + NW1;                  // outp
  __hip_bfloat16* w2 = w16 + NW1 + NW3;            // qkv (permuted)
  __hip_bfloat16* wcat = w16 + NW1 + NW3 + NW2;    // feature proj
  size_t woff = ((size_t)(NW1 + NW2 + NW3 + NW4) * 2 + 255) & ~(size_t)255;
  float2* tab = (float2*)(wsb + woff);             // 8192*32 float2 = 2MB
  size_t toff = woff + (size_t)8192 * 32 * 8;
  char* r1 = wsb + toff;                           // 96 MB region
  char* r2 = r1 + (size_t)M * 1536 * 2;            // 32 MB region
  __hip_bfloat16* cat = (__hip_bfloat16*)r1;       // M*576
  __hip_bfloat16* Fb = (__hip_bfloat16*)(r1 + (size_t)M * 576 * 2);  // M*192
  __hip_bfloat16* qkvb = (__hip_bfloat16*)r1;      // M*1536
  float* pre2 = (float*)r1;                        // M*512 fp32
  __hip_bfloat16* hb = (__hip_bfloat16*)r2;        // M*512
  __hip_bfloat16* att = (__hip_bfloat16*)r2;       // M*512

  // 0. weights -> bf16 ; permuted qkv ; Wcat ; rope table
  wcvt_kernel<<<(NW1 + NW3 + 255) / 256, 256, 0, stream>>>(inst_w, outp_w, w16,
                                                           NW1, NW3);
  wqkv_kernel<<<(NW2 + 255) / 256, 256, 0, stream>>>(qkv_w, w2);
  wcat_kernel<<<(NW4 + 255) / 256, 256, 0, stream>>>(reg_w, reg_b, br_w, br_b,
                                                     mem_w, mem_b, wcat);
  rope_table_kernel<<<(8192 * 32) / 256, 256, 0, stream>>>(tab);
  // 1. prep: cat[:,0:192] = silu(emb[tid]) ; Fb = [1, feats, 0]
  prep_kernel<<<(M * 48) / 256, 256, 0, stream>>>(x, emb, cat, Fb);
  // 1b. feature proj: cat[:,192:576] = silu(Fb @ wcat^T)
  gemm_mfma<__hip_bfloat16, true><<<dim3(M / 128, 3), 256, 0, stream>>>(
      (const ushort*)Fb, (const ushort*)wcat, nullptr, cat + 192, M, 384, 192,
      576);
  // 2. inst proj: cat @ w1^T + b -> hb (bf16)
  gemm_mfma<__hip_bfloat16><<<dim3(M / 128, 4), 256, 0, stream>>>(
      (const ushort*)cat, (const ushort*)w1, inst_b, hb, M, 512, 576, 512);
  // 3. LN1 + silu in place (bf16)
  ln_silu_kernel<<<M, 256, 0, stream>>>(hb, ln1_g, ln1_b);
  // 4. qkv proj (permuted cols): hb @ w2^T -> qkvb planes [Q|K|V]
  gemm_mfma<__hip_bfloat16><<<dim3(M / 128, 12), 256, 0, stream>>>(
      (const ushort*)hb, (const ushort*)w2, nullptr, qkvb, M, 1536, 512, 1536);
  // 5. attention (MFMA) -> att (bf16, [M][512] heads concatenated)
  attn_kernel<<<BATCH * 8 * 64, 256, 0, stream>>>(qkvb, tab, att);
  // 6. out proj: att @ w3^T + b -> pre2 (fp32)
  gemm_mfma<float><<<dim3(M / 128, 4), 256, 0, stream>>>(
      (const ushort*)att, (const ushort*)w3, outp_b, pre2, M, 512, 512, 512);
  // 7. LN2 + silu + head + activations -> out
  head_kernel<<<M, 256, 0, stream>>>(pre2, ln2_g, ln2_b, head_w, head_b, out);
}

// Round 8
// 362.100 us; speedup vs baseline: 6.2393x; 1.0281x over previous
//
#include <hip/hip_runtime.h>
#include <hip/hip_bf16.h>
#include <math.h>
#include <type_traits>

#define LSEQ 8192
#define BATCH 4
#define M_TOK (BATCH * LSEQ)

typedef __attribute__((ext_vector_type(8))) short bf16x8;   // 8 bf16 = 4 VGPR
typedef __attribute__((ext_vector_type(4))) float f32x4;
typedef __attribute__((ext_vector_type(16))) float f32x16;

// ---------------------------------------------------------------- helpers
__device__ __forceinline__ float siluf(float x) {
  return x / (1.f + __expf(-x));
}

__device__ __forceinline__ float bf2f(uint u16) {
  union { float f; uint u; } c;
  c.u = u16 << 16;
  return c.f;
}

__device__ __forceinline__ uint cvtpk_bf16(float lo, float hi) {
  uint r;
  asm volatile("v_cvt_pk_bf16_f32 %0, %1, %2" : "=v"(r) : "v"(lo), "v"(hi));
  return r;
}

// swaps hi 32 lanes of a with lo 32 lanes of b
__device__ __forceinline__ void perm32swap(uint& a, uint& b) {
  asm volatile("v_permlane32_swap_b32 %0, %1" : "+v"(a), "+v"(b));
}

// async global->LDS, 16B per lane; LDS dest = wave-uniform base + lane*16
__device__ __forceinline__ void gload16(const ushort* g, short* l) {
  __builtin_amdgcn_global_load_lds(
      (const __attribute__((address_space(1))) void*)g,
      (__attribute__((address_space(3))) void*)l, 16, 0, 0);
}

__device__ __forceinline__ float waveReduceSum(float v) {
#pragma unroll
  for (int off = 32; off; off >>= 1) v += __shfl_xor(v, off, 64);
  return v;
}

__device__ __forceinline__ void blockLNStats(float s, float ss, float* lds8,
                                             float& mean, float& rstd) {
  s = waveReduceSum(s);
  ss = waveReduceSum(ss);
  int wave = threadIdx.x >> 6;
  int lane = threadIdx.x & 63;
  if (lane == 0) { lds8[wave] = s; lds8[4 + wave] = ss; }
  __syncthreads();
  s  = lds8[0] + lds8[1] + lds8[2] + lds8[3];
  ss = lds8[4] + lds8[5] + lds8[6] + lds8[7];
  mean = s * (1.f / 512.f);
  float var = ss * (1.f / 512.f) - mean * mean;
  rstd = rsqrtf(var + 1e-5f);
}

// ---------------------------------------------------------------- setup
// One kernel for all weight conversion + rope table.
// w16 layout: [w1 inst (512*576) | w3 outp (512*512) | w2 qkv-permuted
// (1536*512) | wcat (384*192)] ; tab float2[8192*32].
#define NW1 (512 * 576)
#define NW3 (512 * 512)
#define NW2 (1536 * 512)
#define NW4 (384 * 192)
#define NTAB (8192 * 32)

__global__ __launch_bounds__(256) void setup_kernel(
    const float* __restrict__ inst_w, const float* __restrict__ outp_w,
    const float* __restrict__ qkv_w, const float* __restrict__ reg_w,
    const float* __restrict__ reg_b, const float* __restrict__ br_w,
    const float* __restrict__ br_b, const float* __restrict__ mem_w,
    const float* __restrict__ mem_b, __hip_bfloat16* __restrict__ w16,
    float2* __restrict__ tab) {
  int i = blockIdx.x * 256 + threadIdx.x;
  if (i < NW1) {
    w16[i] = __float2bfloat16(inst_w[i]);
    return;
  }
  i -= NW1;
  if (i < NW3) {
    w16[NW1 + i] = __float2bfloat16(outp_w[i]);
    return;
  }
  i -= NW3;
  if (i < NW2) {
    // qkv row permutation: out row n' = which*512 + h*64 + d
    // from src row n = h*192 + d*3 + which -> qkvb planes [Q|K|V]
    int np = i / 512, k = i % 512;
    int which = np >> 9, rem = np & 511;
    int h = rem >> 6, d = rem & 63;
    int n = h * 192 + d * 3 + which;
    w16[NW1 + NW3 + i] = __float2bfloat16(qkv_w[n * 512 + k]);
    return;
  }
  i -= NW2;
  if (i < NW4) {
    // Wcat[384][192]: F cols [0]=1(bias),[1..64]=reg,[65..128]=mem,[129..160]=br
    int o = i / 192, c = i % 192;
    float v = 0.f;
    if (o < 128) {
      if (c == 0) v = reg_b[o];
      else if (c <= 64) v = reg_w[o * 64 + (c - 1)];
    } else if (o < 256) {
      int oo = o - 128;
      if (c == 0) v = br_b[oo];
      else if (c >= 129 && c <= 160) v = br_w[oo * 32 + (c - 129)];
    } else {
      int oo = o - 256;
      if (c == 0) v = mem_b[oo];
      else if (c >= 65 && c <= 128) v = mem_w[oo * 64 + (c - 65)];
    }
    w16[NW1 + NW3 + NW2 + i] = __float2bfloat16(v);
    return;
  }
  i -= NW4;
  if (i < NTAB) {
    int pos = i >> 5, p = i & 31;
    float inv = expf(-(float)p * 0.28782313662f);  // ln(10000)/32
    float sn, cs;
    sincosf((float)pos * inv, &sn, &cs);
    tab[i] = make_float2(cs, sn);
  }
}

// ---------------------------------------------------------------- prep
__global__ __launch_bounds__(256) void prep_kernel(
    const int* __restrict__ x, const float* __restrict__ emb,
    __hip_bfloat16* __restrict__ cat, __hip_bfloat16* __restrict__ Fb) {
  int gid = blockIdx.x * 256 + threadIdx.x;
  int t = gid / 48;
  int g = gid % 48;
  if (t >= M_TOK) return;
  const int* xr = x + (size_t)t * 161;
  union { __hip_bfloat16 h[8]; uint4 u; } pk;
  if (g < 24) {
    int c0 = g * 8;
    const float* e = emb + xr[0] * 192 + c0;
#pragma unroll
    for (int j = 0; j < 8; ++j) pk.h[j] = __float2bfloat16(siluf(e[j]));
    *(uint4*)&cat[(size_t)t * 576 + c0] = pk.u;
  } else {
    int c0 = (g - 24) * 8;
#pragma unroll
    for (int j = 0; j < 8; ++j) {
      int c = c0 + j;
      float v = (c == 0) ? 1.f : ((c <= 160) ? (float)xr[c] : 0.f);
      pk.h[j] = __float2bfloat16(v);
    }
    *(uint4*)&Fb[(size_t)t * 192 + c0] = pk.u;
  }
}

// ---------------------------------------------------------------- MFMA GEMM
// m97 structure: linear double-buffered LDS [2][128x32], staged via
// global_load_lds dwordx4 (4 insts/wave/tile), single barrier per K-step,
// next-tile prefetch in flight under the MFMA cluster.
// Staging map: wave w owns rows [32w,32w+32); lane l -> row 32w+l/4 (+16 for
// 2nd call), 16B chunk l%4. LDS dest = base + lane*16 (HW), matches linear
// row*64B + chunk*16B.
template <typename OT, bool SILU = false>
__global__ __launch_bounds__(256) void gemm_mfma(
    const ushort* __restrict__ A, const ushort* __restrict__ W,
    const float* __restrict__ bias, OT* __restrict__ C, int M, int N, int K,
    int ldc) {
  __shared__ __align__(16) short As[2][128 * 32];
  __shared__ __align__(16) short Bs[2][128 * 32];
  const int tid = threadIdx.x;
  const int lane = tid & 63;
  const int wid = tid >> 6;
  const int wr = wid >> 1, wc = wid & 1;
  const int row0 = blockIdx.x * 128, col0 = blockIdx.y * 128;
  const int lrow = lane >> 2;       // 0..15
  const int lch = (lane & 3) * 8;   // bf16 elems (16B chunks)
  const int frow = lane & 15;
  const int fk = (lane >> 4) * 8;

  const ushort* Abase = A + (size_t)(row0 + 32 * wid + lrow) * K + lch;
  const ushort* Wbase = W + (size_t)(col0 + 32 * wid + lrow) * K + lch;
  short* Al[2] = {&As[0][32 * wid * 32], &As[1][32 * wid * 32]};
  short* Bl[2] = {&Bs[0][32 * wid * 32], &Bs[1][32 * wid * 32]};

  f32x4 acc[4][4];
  const f32x4 z = {0.f, 0.f, 0.f, 0.f};
#pragma unroll
  for (int i = 0; i < 4; ++i)
#pragma unroll
    for (int j = 0; j < 4; ++j) acc[i][j] = z;

  const int T = K >> 5;
  // prologue: tile 0 -> buf 0
  gload16(Abase, Al[0]);
  gload16(Abase + (size_t)16 * K, Al[0] + 512);
  gload16(Wbase, Bl[0]);
  gload16(Wbase + (size_t)16 * K, Bl[0] + 512);

  for (int t = 0; t < T; ++t) {
    __syncthreads();  // drains vmcnt: buf[t&1] staged; prior reads done
    if (t + 1 < T) {
      const ushort* An = Abase + (t + 1) * 32;
      const ushort* Wn = Wbase + (t + 1) * 32;
      short* Ad = Al[(t + 1) & 1];
      short* Bd = Bl[(t + 1) & 1];
      gload16(An, Ad);
      gload16(An + (size_t)16 * K, Ad + 512);
      gload16(Wn, Bd);
      gload16(Wn + (size_t)16 * K, Bd + 512);
    }
    const short* Ab = As[t & 1];
    const short* Bb = Bs[t & 1];
    bf16x8 af[4], bfr[4];
#pragma unroll
    for (int i = 0; i < 4; ++i)
      af[i] = *(const bf16x8*)&Ab[(wr * 64 + i * 16 + frow) * 32 + fk];
#pragma unroll
    for (int j = 0; j < 4; ++j)
      bfr[j] = *(const bf16x8*)&Bb[(wc * 64 + j * 16 + frow) * 32 + fk];
#pragma unroll
    for (int i = 0; i < 4; ++i)
#pragma unroll
      for (int j = 0; j < 4; ++j)
        acc[i][j] = __builtin_amdgcn_mfma_f32_16x16x32_bf16(af[i], bfr[j],
                                                            acc[i][j], 0, 0, 0);
  }

  const int crow0 = row0 + wr * 64 + (lane >> 4) * 4;
  const int ccol0 = col0 + wc * 64 + (lane & 15);
#pragma unroll
  for (int j = 0; j < 4; ++j) {
    const int col = ccol0 + j * 16;
    const float bv = bias ? bias[col] : 0.f;
#pragma unroll
    for (int i = 0; i < 4; ++i) {
#pragma unroll
      for (int r = 0; r < 4; ++r) {
        float v = acc[i][j][r] + bv;
        if constexpr (SILU) v = siluf(v);
        size_t off = (size_t)(crow0 + i * 16 + r) * ldc + col;
        if constexpr (std::is_same<OT, float>::value) {
          C[off] = v;
        } else {
          C[off] = __float2bfloat16(v);
        }
      }
    }
  }
}

// ---------------------------------------------------------------- kernel 3
__global__ __launch_bounds__(256) void ln_silu_kernel(
    __hip_bfloat16* __restrict__ buf, const float* __restrict__ g,
    const float* __restrict__ b) {
  __shared__ float lds8[8];
  const int t = blockIdx.x;
  const int tid = threadIdx.x;
  uint u = *(const uint*)&buf[(size_t)t * 512 + tid * 2];
  float x0 = bf2f(u & 0xffffu);
  float x1 = bf2f(u >> 16);
  float mean, rstd;
  blockLNStats(x0 + x1, x0 * x0 + x1 * x1, lds8, mean, rstd);
  float y0 = siluf((x0 - mean) * rstd * g[2 * tid] + b[2 * tid]);
  float y1 = siluf((x1 - mean) * rstd * g[2 * tid + 1] + b[2 * tid + 1]);
  union { __hip_bfloat16 h[2]; uint u; } pk;
  pk.h[0] = __float2bfloat16(y0);
  pk.h[1] = __float2bfloat16(y1);
  *(uint*)&buf[(size_t)t * 512 + tid * 2] = pk.u;
}

// ---------------------------------------------------------------- attn (MFMA)
// One block per (b,h,window-block): 4 waves x 32 queries. KV chunks of 64 keys.
// qkvb planes per token row (1536): [Q 0..511 | K 512..1023 | V 1024..1535].
// Swapped QK^T; P relayout via cvt_pk_bf16 + permlane32_swap; V transposed in
// LDS for contiguous PV B-frag reads.
__global__ __launch_bounds__(256) void attn_kernel(
    const __hip_bfloat16* __restrict__ qkv, const float2* __restrict__ tab,
    __hip_bfloat16* __restrict__ o_out) {
  __shared__ __align__(16) short Kc[64 * 72];   // [key 64][dim 64 pad 72]
  __shared__ __align__(16) short Vt[64 * 72];   // [dim 64][key 64 pad 72]
  __shared__ __align__(16) float rbuf[4][32];
  const int blk = blockIdx.x;
  const int nbIdx = blk & 63;
  const int h = (blk >> 6) & 7;
  const int b = blk >> 9;
  const int tid = threadIdx.x;
  const int w = tid >> 6;
  const int lane = tid & 63;
  const int lq = lane & 31;
  const int hi = lane >> 5;
  const size_t seqBase = (size_t)b * LSEQ;
  const int qi = w * 32 + lq;
  const int qtok = nbIdx * 128 + qi;

  const ushort* qkvu = (const ushort*)qkv;

  // ---- load Q fragments (B-operand), rope + 1/8 scale folded in
  bf16x8 qf[4];
  {
    const ushort* Qrow = qkvu + (seqBase + qtok) * 1536 + h * 64;
#pragma unroll
    for (int s = 0; s < 4; ++s) {
      int dim0 = 16 * s + 8 * hi;
      bf16x8 qv = *(const bf16x8*)(Qrow + dim0);
      const float4* tp = (const float4*)(tab + qtok * 32 + dim0 / 2);
      float4 t01 = tp[0], t23 = tp[1];
      float cs[4] = {t01.x, t01.z, t23.x, t23.z};
      float sn[4] = {t01.y, t01.w, t23.y, t23.w};
      union { uint u[4]; bf16x8 v; } pk;
#pragma unroll
      for (int j = 0; j < 4; ++j) {
        float x1 = bf2f((ushort)qv[2 * j]);
        float x2 = bf2f((ushort)qv[2 * j + 1]);
        float r0 = (x1 * cs[j] - x2 * sn[j]) * 0.125f;
        float r1 = (x1 * sn[j] + x2 * cs[j]) * 0.125f;
        pk.u[j] = cvtpk_bf16(r0, r1);
      }
      qf[s] = pk.v;
    }
  }

  const f32x16 Z16 = {0.f};
  f32x16 oa0 = Z16, oa1 = Z16;
  float m0 = -3.0e38f, l = 0.f;

  const int cstart = (nbIdx == 0) ? 2 : 0;
  const int cw0 = (w >= 2) ? 1 : 0;
  const int cw1 = (w >= 2) ? 3 : 2;

  const int skk = tid >> 2;
  const int sd0 = (tid & 3) * 16;

  for (int c = cstart; c < 4; ++c) {
    __syncthreads();
    {
      int ktok = (nbIdx - 1) * 128 + c * 64 + skk;
      const ushort* Krow = qkvu + (seqBase + ktok) * 1536 + 512 + h * 64;
      const ushort* Vrow = qkvu + (seqBase + ktok) * 1536 + 1024 + h * 64;
      int swk = ((skk >> 3) & 3) << 5;
#pragma unroll
      for (int hh = 0; hh < 2; ++hh) {
        int dim0 = sd0 + 8 * hh;
        bf16x8 kv = *(const bf16x8*)(Krow + dim0);
        const float4* tp = (const float4*)(tab + ktok * 32 + dim0 / 2);
        float4 t01 = tp[0], t23 = tp[1];
        float cs[4] = {t01.x, t01.z, t23.x, t23.z};
        float sn[4] = {t01.y, t01.w, t23.y, t23.w};
        union { uint u[4]; bf16x8 v; } pk;
#pragma unroll
        for (int j = 0; j < 4; ++j) {
          float x1 = bf2f((ushort)kv[2 * j]);
          float x2 = bf2f((ushort)kv[2 * j + 1]);
          pk.u[j] = cvtpk_bf16(x1 * cs[j] - x2 * sn[j],
                               x1 * sn[j] + x2 * cs[j]);
        }
        *(bf16x8*)((char*)Kc + skk * 144 + ((dim0 * 2) ^ swk)) = pk.v;
        bf16x8 vv = *(const bf16x8*)(Vrow + dim0);
#pragma unroll
        for (int j = 0; j < 8; ++j) {
          int d = dim0 + j;
          int swv = ((d >> 3) & 3) << 5;
          *(short*)((char*)Vt + d * 144 + ((skk * 2) ^ swv)) = vv[j];
        }
      }
    }
    __syncthreads();
    if (c < cw0 || c > cw1) continue;

    bf16x8 ka[2][4];
#pragma unroll
    for (int t2 = 0; t2 < 2; ++t2)
#pragma unroll
      for (int s = 0; s < 4; ++s) {
        int kk = 32 * t2 + lq;
        int byteoff = kk * 144 + (((32 * s + 16 * hi)) ^ (((kk >> 3) & 3) << 5));
        ka[t2][s] = *(const bf16x8*)((const char*)Kc + byteoff);
      }
    f32x16 st0 = Z16, st1 = Z16;
#pragma unroll
    for (int s = 0; s < 4; ++s) {
      st0 = __builtin_amdgcn_mfma_f32_32x32x16_bf16(ka[0][s], qf[s], st0, 0, 0, 0);
      st1 = __builtin_amdgcn_mfma_f32_32x32x16_bf16(ka[1][s], qf[s], st1, 0, 0, 0);
    }

    float p2[2][16];
    float pmax = -3.0e38f;
#pragma unroll
    for (int t2 = 0; t2 < 2; ++t2)
#pragma unroll
      for (int r = 0; r < 16; ++r) {
        int key = c * 64 + 32 * t2 + (r & 3) + 8 * (r >> 2) + 4 * hi;
        float sv = (t2 ? st1[r] : st0[r]);
        bool act = (key >= qi) && (key <= qi + 128);
        sv = act ? sv : -1.0e30f;
        p2[t2][r] = sv;
        pmax = fmaxf(pmax, sv);
      }
    pmax = fmaxf(pmax, __shfl_xor(pmax, 32));
    if (__any(pmax > m0 + 8.f)) {
      float nm = fmaxf(m0, pmax);
      float rr = __expf(m0 - nm);
      l *= rr;
      m0 = nm;
      rbuf[w][lq] = rr;
      asm volatile("s_waitcnt lgkmcnt(0)" ::: "memory");
#pragma unroll
      for (int a = 0; a < 4; ++a) {
        f32x4 r4 = *(const f32x4*)&rbuf[w][8 * a + 4 * hi];
#pragma unroll
        for (int j = 0; j < 4; ++j) {
          oa0[4 * a + j] *= r4[j];
          oa1[4 * a + j] *= r4[j];
        }
      }
    }
    float lsum = 0.f;
#pragma unroll
    for (int t2 = 0; t2 < 2; ++t2)
#pragma unroll
      for (int r = 0; r < 16; ++r) {
        float p = __expf(p2[t2][r] - m0);
        p2[t2][r] = p;
        lsum += p;
      }
    l += lsum + __shfl_xor(lsum, 32);

    union { uint u[4]; bf16x8 v; } pa[4];
#pragma unroll
    for (int t2 = 0; t2 < 2; ++t2)
#pragma unroll
      for (int sl = 0; sl < 2; ++sl) {
        const float* pp = &p2[t2][8 * sl];
        uint a0 = cvtpk_bf16(pp[0], pp[1]);
        uint a1 = cvtpk_bf16(pp[2], pp[3]);
        uint b0 = cvtpk_bf16(pp[4], pp[5]);
        uint b1 = cvtpk_bf16(pp[6], pp[7]);
        perm32swap(a0, b0);
        perm32swap(a1, b1);
        int slot = 2 * t2 + sl;
        pa[slot].u[0] = a0; pa[slot].u[1] = a1;
        pa[slot].u[2] = b0; pa[slot].u[3] = b1;
      }

#pragma unroll
    for (int slot = 0; slot < 4; ++slot) {
      {
        int d = lq;
        int byteoff = d * 144 + ((32 * slot + 16 * hi) ^ (((d >> 3) & 3) << 5));
        bf16x8 vb = *(const bf16x8*)((const char*)Vt + byteoff);
        oa0 = __builtin_amdgcn_mfma_f32_32x32x16_bf16(pa[slot].v, vb, oa0, 0, 0, 0);
      }
      {
        int d = 32 + lq;
        int byteoff = d * 144 + ((32 * slot + 16 * hi) ^ (((d >> 3) & 3) << 5));
        bf16x8 vb = *(const bf16x8*)((const char*)Vt + byteoff);
        oa1 = __builtin_amdgcn_mfma_f32_32x32x16_bf16(pa[slot].v, vb, oa1, 0, 0, 0);
      }
    }
  }

  rbuf[w][lq] = 1.f / l;
  asm volatile("s_waitcnt lgkmcnt(0)" ::: "memory");
  const int q0 = nbIdx * 128 + 32 * w;
#pragma unroll
  for (int a = 0; a < 4; ++a) {
    f32x4 r4 = *(const f32x4*)&rbuf[w][8 * a + 4 * hi];
#pragma unroll
    for (int j = 0; j < 4; ++j) {
      int tok = q0 + 8 * a + 4 * hi + j;
      __hip_bfloat16* orow = o_out + (seqBase + tok) * 512 + h * 64;
      orow[lq] = __float2bfloat16(oa0[4 * a + j] * r4[j]);
      orow[32 + lq] = __float2bfloat16(oa1[4 * a + j] * r4[j]);
    }
  }
}

// ---------------------------------------------------------------- kernel 5
__global__ __launch_bounds__(256) void head_kernel(
    const float* __restrict__ pre, const float* __restrict__ g,
    const float* __restrict__ b, const float* __restrict__ hw,
    const float* __restrict__ hb, float* __restrict__ out) {
  __shared__ float lds8[8];
  __shared__ float ys[512];
  __shared__ float raw[9];
  const int t = blockIdx.x;
  const int tid = threadIdx.x;
  float2 v = *(const float2*)&pre[(size_t)t * 512 + tid * 2];
  float mean, rstd;
  blockLNStats(v.x + v.y, v.x * v.x + v.y * v.y, lds8, mean, rstd);
  float y0 = (v.x - mean) * rstd * g[2 * tid] + b[2 * tid];
  float y1 = (v.y - mean) * rstd * g[2 * tid + 1] + b[2 * tid + 1];
  ys[2 * tid] = siluf(y0);
  ys[2 * tid + 1] = siluf(y1);
  __syncthreads();
  const int wave = tid >> 6;
  const int lane = tid & 63;
  for (int r = wave; r < 9; r += 4) {
    float p = 0.f;
#pragma unroll
    for (int i = 0; i < 8; ++i)
      p = fmaf(ys[lane + i * 64], hw[r * 512 + lane + i * 64], p);
    p = waveReduceSum(p);
    if (lane == 0) raw[r] = p + hb[r];
  }
  __syncthreads();
  if (tid == 0) {
    float* op = out + (size_t)t * 9;
    op[0] = fmaxf(raw[0], 0.f) + log1pf(expf(-fabsf(raw[0])));
    op[1] = fmaxf(raw[1], 0.f) + log1pf(expf(-fabsf(raw[1])));
    op[2] = 1.f / (1.f + expf(-raw[2]));
    op[3] = 1.f / (1.f + expf(-raw[3]));
    op[4] = 1.f / (1.f + expf(-raw[4]));
    float mx = fmaxf(fmaxf(raw[5], raw[6]), fmaxf(raw[7], raw[8]));
    float e0 = expf(raw[5] - mx), e1 = expf(raw[6] - mx);
    float e2 = expf(raw[7] - mx), e3 = expf(raw[8] - mx);
    float inv = 1.f / (e0 + e1 + e2 + e3);
    op[5] = e0 * inv; op[6] = e1 * inv; op[7] = e2 * inv; op[8] = e3 * inv;
  }
}

// ---------------------------------------------------------------- launch
// Workspace layout (~133 MB peak):
//   w16: bf16 [inst | outp | qkv(permuted) | wcat] ; rope table (2MB)
//   R1 (96MB): {cat M*576 | Fb M*192} -> qkvb M*1536 -> pre2 fp32 M*512
//   R2 (32MB): hb bf16 [in-place LN] -> att bf16
extern "C" void kernel_launch(void* const* d_in, const int* in_sizes, int n_in,
                              void* d_out, int out_size, void* d_ws,
                              size_t ws_size, hipStream_t stream) {
  const float* emb = (const float*)d_in[0];
  const float* reg_w = (const float*)d_in[1];
  const float* reg_b = (const float*)d_in[2];
  const float* br_w = (const float*)d_in[3];
  const float* br_b = (const float*)d_in[4];
  const float* mem_w = (const float*)d_in[5];
  const float* mem_b = (const float*)d_in[6];
  const float* inst_w = (const float*)d_in[7];
  const float* inst_b = (const float*)d_in[8];
  const float* ln1_g = (const float*)d_in[9];
  const float* ln1_b = (const float*)d_in[10];
  const float* qkv_w = (const float*)d_in[11];
  const float* outp_w = (const float*)d_in[12];
  const float* outp_b = (const float*)d_in[13];
  const float* ln2_g = (const float*)d_in[14];
  const float* ln2_b = (const float*)d_in[15];
  const float* head_w = (const float*)d_in[16];
  const float* head_b = (const float*)d_in[17];
  const int* x = (const int*)d_in[18];
  float* out = (float*)d_out;

  const int M = M_TOK;
  char* wsb = (char*)d_ws;
  __hip_bfloat16* w16 = (__hip_bfloat16*)wsb;
  __hip_bfloat16* w1 = w16;                        // inst
  __hip_bfloat16* w3 = w16 + NW1;                  // outp
  __hip_bfloat16* w2 = w16 + NW1 + NW3;            // qkv (permuted)
  __hip_bfloat16* wcat = w16 + NW1 + NW3 + NW2;    // feature proj
  size_t woff = ((size_t)(NW1 + NW2 + NW3 + NW4) * 2 + 255) & ~(size_t)255;
  float2* tab = (float2*)(wsb + woff);             // 2MB
  size_t toff = woff + (size_t)NTAB * 8;
  char* r1 = wsb + toff;                           // 96 MB region
  char* r2 = r1 + (size_t)M * 1536 * 2;            // 32 MB region
  __hip_bfloat16* cat = (__hip_bfloat16*)r1;       // M*576
  __hip_bfloat16* Fb = (__hip_bfloat16*)(r1 + (size_t)M * 576 * 2);  // M*192
  __hip_bfloat16* qkvb = (__hip_bfloat16*)r1;      // M*1536
  float* pre2 = (float*)r1;                        // M*512 fp32
  __hip_bfloat16* hb = (__hip_bfloat16*)r2;        // M*512
  __hip_bfloat16* att = (__hip_bfloat16*)r2;       // M*512

  // 0. all weight conversion + rope table (one kernel)
  const int setup_tot = NW1 + NW3 + NW2 + NW4 + NTAB;
  setup_kernel<<<(setup_tot + 255) / 256, 256, 0, stream>>>(
      inst_w, outp_w, qkv_w, reg_w, reg_b, br_w, br_b, mem_w, mem_b, w16, tab);
  // 1. prep: cat[:,0:192] = silu(emb[tid]) ; Fb = [1, feats, 0]
  prep_kernel<<<(M * 48) / 256, 256, 0, stream>>>(x, emb, cat, Fb);
  // 1b. feature proj: cat[:,192:576] = silu(Fb @ wcat^T)
  gemm_mfma<__hip_bfloat16, true><<<dim3(M / 128, 3), 256, 0, stream>>>(
      (const ushort*)Fb, (const ushort*)wcat, nullptr, cat + 192, M, 384, 192,
      576);
  // 2. inst proj: cat @ w1^T + b -> hb (bf16)
  gemm_mfma<__hip_bfloat16><<<dim3(M / 128, 4), 256, 0, stream>>>(
      (const ushort*)cat, (const ushort*)w1, inst_b, hb, M, 512, 576, 512);
  // 3. LN1 + silu in place (bf16)
  ln_silu_kernel<<<M, 256, 0, stream>>>(hb, ln1_g, ln1_b);
  // 4. qkv proj (permuted cols): hb @ w2^T -> qkvb planes [Q|K|V]
  gemm_mfma<__hip_bfloat16><<<dim3(M / 128, 12), 256, 0, stream>>>(
      (const ushort*)hb, (const ushort*)w2, nullptr, qkvb, M, 1536, 512, 1536);
  // 5. attention (MFMA) -> att (bf16, [M][512] heads concatenated)
  attn_kernel<<<BATCH * 8 * 64, 256, 0, stream>>>(qkvb, tab, att);
  // 6. out proj: att @ w3^T + b -> pre2 (fp32)
  gemm_mfma<float><<<dim3(M / 128, 4), 256, 0, stream>>>(
      (const ushort*)att, (const ushort*)w3, outp_b, pre2, M, 512, 512, 512);
  // 7. LN2 + silu + head + activations -> out
  head_kernel<<<M, 256, 0, stream>>>(pre2, ln2_g, ln2_b, head_w, head_b, out);
}

// Round 9
// 335.123 us; speedup vs baseline: 6.7415x; 1.0805x over previous
//
#include <hip/hip_runtime.h>
#include <hip/hip_bf16.h>
#include <math.h>
#include <type_traits>

#define LSEQ 8192
#define BATCH 4
#define M_TOK (BATCH * LSEQ)

typedef __attribute__((ext_vector_type(8))) short bf16x8;   // 8 bf16 = 4 VGPR
typedef __attribute__((ext_vector_type(4))) float f32x4;
typedef __attribute__((ext_vector_type(16))) float f32x16;

// ---------------------------------------------------------------- helpers
__device__ __forceinline__ float siluf(float x) {
  return x / (1.f + __expf(-x));
}

__device__ __forceinline__ float bf2f(uint u16) {
  union { float f; uint u; } c;
  c.u = u16 << 16;
  return c.f;
}

__device__ __forceinline__ uint cvtpk_bf16(float lo, float hi) {
  uint r;
  asm volatile("v_cvt_pk_bf16_f32 %0, %1, %2" : "=v"(r) : "v"(lo), "v"(hi));
  return r;
}

// swaps hi 32 lanes of a with lo 32 lanes of b
__device__ __forceinline__ void perm32swap(uint& a, uint& b) {
  asm volatile("v_permlane32_swap_b32 %0, %1" : "+v"(a), "+v"(b));
}

// async global->LDS, 16B per lane; LDS dest = wave-uniform base + lane*16
__device__ __forceinline__ void gload16(const ushort* g, short* l) {
  __builtin_amdgcn_global_load_lds(
      (const __attribute__((address_space(1))) void*)g,
      (__attribute__((address_space(3))) void*)l, 16, 0, 0);
}

__device__ __forceinline__ float waveReduceSum(float v) {
#pragma unroll
  for (int off = 32; off; off >>= 1) v += __shfl_xor(v, off, 64);
  return v;
}

__device__ __forceinline__ void blockLNStats(float s, float ss, float* lds8,
                                             float& mean, float& rstd) {
  s = waveReduceSum(s);
  ss = waveReduceSum(ss);
  int wave = threadIdx.x >> 6;
  int lane = threadIdx.x & 63;
  if (lane == 0) { lds8[wave] = s; lds8[4 + wave] = ss; }
  __syncthreads();
  s  = lds8[0] + lds8[1] + lds8[2] + lds8[3];
  ss = lds8[4] + lds8[5] + lds8[6] + lds8[7];
  mean = s * (1.f / 512.f);
  float var = ss * (1.f / 512.f) - mean * mean;
  rstd = rsqrtf(var + 1e-5f);
}

// ---------------------------------------------------------------- setup
// One kernel for all weight conversion + rope table.
// w16 layout: [w1 inst (512*576) | w3 outp (512*512) | w2 qkv-permuted
// (1536*512) | wcat (384*192)] ; tab float2[8192*32].
#define NW1 (512 * 576)
#define NW3 (512 * 512)
#define NW2 (1536 * 512)
#define NW4 (384 * 192)
#define NTAB (8192 * 32)

__global__ __launch_bounds__(256) void setup_kernel(
    const float* __restrict__ inst_w, const float* __restrict__ outp_w,
    const float* __restrict__ qkv_w, const float* __restrict__ reg_w,
    const float* __restrict__ reg_b, const float* __restrict__ br_w,
    const float* __restrict__ br_b, const float* __restrict__ mem_w,
    const float* __restrict__ mem_b, __hip_bfloat16* __restrict__ w16,
    float2* __restrict__ tab) {
  int i = blockIdx.x * 256 + threadIdx.x;
  if (i < NW1) {
    w16[i] = __float2bfloat16(inst_w[i]);
    return;
  }
  i -= NW1;
  if (i < NW3) {
    w16[NW1 + i] = __float2bfloat16(outp_w[i]);
    return;
  }
  i -= NW3;
  if (i < NW2) {
    // qkv row permutation: out row n' = which*512 + h*64 + d
    // from src row n = h*192 + d*3 + which -> qkvb planes [Q|K|V]
    int np = i / 512, k = i % 512;
    int which = np >> 9, rem = np & 511;
    int h = rem >> 6, d = rem & 63;
    int n = h * 192 + d * 3 + which;
    w16[NW1 + NW3 + i] = __float2bfloat16(qkv_w[n * 512 + k]);
    return;
  }
  i -= NW2;
  if (i < NW4) {
    // Wcat[384][192]: F cols [0]=1(bias),[1..64]=reg,[65..128]=mem,[129..160]=br
    int o = i / 192, c = i % 192;
    float v = 0.f;
    if (o < 128) {
      if (c == 0) v = reg_b[o];
      else if (c <= 64) v = reg_w[o * 64 + (c - 1)];
    } else if (o < 256) {
      int oo = o - 128;
      if (c == 0) v = br_b[oo];
      else if (c >= 129 && c <= 160) v = br_w[oo * 32 + (c - 129)];
    } else {
      int oo = o - 256;
      if (c == 0) v = mem_b[oo];
      else if (c >= 65 && c <= 128) v = mem_w[oo * 64 + (c - 65)];
    }
    w16[NW1 + NW3 + NW2 + i] = __float2bfloat16(v);
    return;
  }
  i -= NW4;
  if (i < NTAB) {
    int pos = i >> 5, p = i & 31;
    float inv = expf(-(float)p * 0.28782313662f);  // ln(10000)/32
    float sn, cs;
    sincosf((float)pos * inv, &sn, &cs);
    tab[i] = make_float2(cs, sn);
  }
}

// ---------------------------------------------------------------- prep
__global__ __launch_bounds__(256) void prep_kernel(
    const int* __restrict__ x, const float* __restrict__ emb,
    __hip_bfloat16* __restrict__ cat, __hip_bfloat16* __restrict__ Fb) {
  int gid = blockIdx.x * 256 + threadIdx.x;
  int t = gid / 48;
  int g = gid % 48;
  if (t >= M_TOK) return;
  const int* xr = x + (size_t)t * 161;
  union { __hip_bfloat16 h[8]; uint4 u; } pk;
  if (g < 24) {
    int c0 = g * 8;
    const float* e = emb + xr[0] * 192 + c0;
#pragma unroll
    for (int j = 0; j < 8; ++j) pk.h[j] = __float2bfloat16(siluf(e[j]));
    *(uint4*)&cat[(size_t)t * 576 + c0] = pk.u;
  } else {
    int c0 = (g - 24) * 8;
#pragma unroll
    for (int j = 0; j < 8; ++j) {
      int c = c0 + j;
      float v = (c == 0) ? 1.f : ((c <= 160) ? (float)xr[c] : 0.f);
      pk.h[j] = __float2bfloat16(v);
    }
    *(uint4*)&Fb[(size_t)t * 192 + c0] = pk.u;
  }
}

// ---------------------------------------------------------------- MFMA GEMM
// m97 structure: linear double-buffered LDS [2][128x32], staged via
// global_load_lds dwordx4, single barrier per K-step, next-tile prefetch
// in flight under the MFMA cluster.
template <typename OT, bool SILU = false>
__global__ __launch_bounds__(256) void gemm_mfma(
    const ushort* __restrict__ A, const ushort* __restrict__ W,
    const float* __restrict__ bias, OT* __restrict__ C, int M, int N, int K,
    int ldc) {
  __shared__ __align__(16) short As[2][128 * 32];
  __shared__ __align__(16) short Bs[2][128 * 32];
  const int tid = threadIdx.x;
  const int lane = tid & 63;
  const int wid = tid >> 6;
  const int wr = wid >> 1, wc = wid & 1;
  const int row0 = blockIdx.x * 128, col0 = blockIdx.y * 128;
  const int lrow = lane >> 2;       // 0..15
  const int lch = (lane & 3) * 8;   // bf16 elems (16B chunks)
  const int frow = lane & 15;
  const int fk = (lane >> 4) * 8;

  const ushort* Abase = A + (size_t)(row0 + 32 * wid + lrow) * K + lch;
  const ushort* Wbase = W + (size_t)(col0 + 32 * wid + lrow) * K + lch;
  short* Al[2] = {&As[0][32 * wid * 32], &As[1][32 * wid * 32]};
  short* Bl[2] = {&Bs[0][32 * wid * 32], &Bs[1][32 * wid * 32]};

  f32x4 acc[4][4];
  const f32x4 z = {0.f, 0.f, 0.f, 0.f};
#pragma unroll
  for (int i = 0; i < 4; ++i)
#pragma unroll
    for (int j = 0; j < 4; ++j) acc[i][j] = z;

  const int T = K >> 5;
  gload16(Abase, Al[0]);
  gload16(Abase + (size_t)16 * K, Al[0] + 512);
  gload16(Wbase, Bl[0]);
  gload16(Wbase + (size_t)16 * K, Bl[0] + 512);

  for (int t = 0; t < T; ++t) {
    __syncthreads();
    if (t + 1 < T) {
      const ushort* An = Abase + (t + 1) * 32;
      const ushort* Wn = Wbase + (t + 1) * 32;
      short* Ad = Al[(t + 1) & 1];
      short* Bd = Bl[(t + 1) & 1];
      gload16(An, Ad);
      gload16(An + (size_t)16 * K, Ad + 512);
      gload16(Wn, Bd);
      gload16(Wn + (size_t)16 * K, Bd + 512);
    }
    const short* Ab = As[t & 1];
    const short* Bb = Bs[t & 1];
    bf16x8 af[4], bfr[4];
#pragma unroll
    for (int i = 0; i < 4; ++i)
      af[i] = *(const bf16x8*)&Ab[(wr * 64 + i * 16 + frow) * 32 + fk];
#pragma unroll
    for (int j = 0; j < 4; ++j)
      bfr[j] = *(const bf16x8*)&Bb[(wc * 64 + j * 16 + frow) * 32 + fk];
#pragma unroll
    for (int i = 0; i < 4; ++i)
#pragma unroll
      for (int j = 0; j < 4; ++j)
        acc[i][j] = __builtin_amdgcn_mfma_f32_16x16x32_bf16(af[i], bfr[j],
                                                            acc[i][j], 0, 0, 0);
  }

  const int crow0 = row0 + wr * 64 + (lane >> 4) * 4;
  const int ccol0 = col0 + wc * 64 + (lane & 15);
#pragma unroll
  for (int j = 0; j < 4; ++j) {
    const int col = ccol0 + j * 16;
    const float bv = bias ? bias[col] : 0.f;
#pragma unroll
    for (int i = 0; i < 4; ++i) {
#pragma unroll
      for (int r = 0; r < 4; ++r) {
        float v = acc[i][j][r] + bv;
        if constexpr (SILU) v = siluf(v);
        size_t off = (size_t)(crow0 + i * 16 + r) * ldc + col;
        if constexpr (std::is_same<OT, float>::value) {
          C[off] = v;
        } else {
          C[off] = __float2bfloat16(v);
        }
      }
    }
  }
}

// ---------------------------------------------------------------- kernel 3
__global__ __launch_bounds__(256) void ln_silu_kernel(
    __hip_bfloat16* __restrict__ buf, const float* __restrict__ g,
    const float* __restrict__ b) {
  __shared__ float lds8[8];
  const int t = blockIdx.x;
  const int tid = threadIdx.x;
  uint u = *(const uint*)&buf[(size_t)t * 512 + tid * 2];
  float x0 = bf2f(u & 0xffffu);
  float x1 = bf2f(u >> 16);
  float mean, rstd;
  blockLNStats(x0 + x1, x0 * x0 + x1 * x1, lds8, mean, rstd);
  float y0 = siluf((x0 - mean) * rstd * g[2 * tid] + b[2 * tid]);
  float y1 = siluf((x1 - mean) * rstd * g[2 * tid + 1] + b[2 * tid + 1]);
  union { __hip_bfloat16 h[2]; uint u; } pk;
  pk.h[0] = __float2bfloat16(y0);
  pk.h[1] = __float2bfloat16(y1);
  *(uint*)&buf[(size_t)t * 512 + tid * 2] = pk.u;
}

// ---------------------------------------------------------------- attn (MFMA)
// One block per (b,h,window-block): 4 waves x 32 queries. KV chunks of 64 keys,
// DOUBLE-BUFFERED with async-split staging: chunk c+1 global loads issued into
// regs before compute on chunk c; rope+LDS-write after compute. One barrier
// per chunk. V swizzle ((d>>4)&3)<<5 separates all 4 sd0 groups.
__global__ __launch_bounds__(256) void attn_kernel(
    const __hip_bfloat16* __restrict__ qkv, const float2* __restrict__ tab,
    __hip_bfloat16* __restrict__ o_out) {
  __shared__ __align__(16) short Kc[2][64 * 72];   // [key 64][dim 64 pad 72]
  __shared__ __align__(16) short Vt[2][64 * 72];   // [dim 64][key 64 pad 72]
  __shared__ __align__(16) float rbuf[4][32];
  const int blk = blockIdx.x;
  const int nbIdx = blk & 63;
  const int h = (blk >> 6) & 7;
  const int b = blk >> 9;
  const int tid = threadIdx.x;
  const int w = tid >> 6;
  const int lane = tid & 63;
  const int lq = lane & 31;
  const int hi = lane >> 5;
  const size_t seqBase = (size_t)b * LSEQ;
  const int qi = w * 32 + lq;
  const int qtok = nbIdx * 128 + qi;

  const ushort* qkvu = (const ushort*)qkv;

  // ---- load Q fragments (B-operand), rope + 1/8 scale folded in
  bf16x8 qf[4];
  {
    const ushort* Qrow = qkvu + (seqBase + qtok) * 1536 + h * 64;
#pragma unroll
    for (int s = 0; s < 4; ++s) {
      int dim0 = 16 * s + 8 * hi;
      bf16x8 qv = *(const bf16x8*)(Qrow + dim0);
      const float4* tp = (const float4*)(tab + qtok * 32 + dim0 / 2);
      float4 t01 = tp[0], t23 = tp[1];
      float cs[4] = {t01.x, t01.z, t23.x, t23.z};
      float sn[4] = {t01.y, t01.w, t23.y, t23.w};
      union { uint u[4]; bf16x8 v; } pk;
#pragma unroll
      for (int j = 0; j < 4; ++j) {
        float x1 = bf2f((ushort)qv[2 * j]);
        float x2 = bf2f((ushort)qv[2 * j + 1]);
        float r0 = (x1 * cs[j] - x2 * sn[j]) * 0.125f;
        float r1 = (x1 * sn[j] + x2 * cs[j]) * 0.125f;
        pk.u[j] = cvtpk_bf16(r0, r1);
      }
      qf[s] = pk.v;
    }
  }

  const f32x16 Z16 = {0.f};
  f32x16 oa0 = Z16, oa1 = Z16;
  float m0 = -3.0e38f, l = 0.f;

  const int cstart = (nbIdx == 0) ? 2 : 0;
  const int cw0 = (w >= 2) ? 1 : 0;
  const int cw1 = (w >= 2) ? 3 : 2;

  const int skk = tid >> 2;         // key row this thread stages
  const int sd0 = (tid & 3) * 16;   // dim group [sd0, sd0+16)

  bf16x8 kreg0, kreg1, vreg0, vreg1;  // in-flight staging registers

  auto issue = [&](int c) {
    int ktok = (nbIdx - 1) * 128 + c * 64 + skk;
    const ushort* base = qkvu + (seqBase + ktok) * 1536 + h * 64 + sd0;
    kreg0 = *(const bf16x8*)(base + 512);
    kreg1 = *(const bf16x8*)(base + 512 + 8);
    vreg0 = *(const bf16x8*)(base + 1024);
    vreg1 = *(const bf16x8*)(base + 1024 + 8);
  };

  auto write_chunk = [&](int c) {
    short* Kb = Kc[c & 1];
    short* Vb = Vt[c & 1];
    int ktok = (nbIdx - 1) * 128 + c * 64 + skk;
    const float4* tp = (const float4*)(tab + ktok * 32 + (sd0 >> 1));
    float4 t0 = tp[0], t1 = tp[1], t2 = tp[2], t3 = tp[3];
    const int swk = ((skk >> 3) & 3) << 5;
    {
      float cs[4] = {t0.x, t0.z, t1.x, t1.z};
      float sn[4] = {t0.y, t0.w, t1.y, t1.w};
      union { uint u[4]; bf16x8 v; } pk;
#pragma unroll
      for (int j = 0; j < 4; ++j) {
        float x1 = bf2f((ushort)kreg0[2 * j]);
        float x2 = bf2f((ushort)kreg0[2 * j + 1]);
        pk.u[j] = cvtpk_bf16(x1 * cs[j] - x2 * sn[j], x1 * sn[j] + x2 * cs[j]);
      }
      *(bf16x8*)((char*)Kb + skk * 144 + ((sd0 * 2) ^ swk)) = pk.v;
    }
    {
      float cs[4] = {t2.x, t2.z, t3.x, t3.z};
      float sn[4] = {t2.y, t2.w, t3.y, t3.w};
      union { uint u[4]; bf16x8 v; } pk;
#pragma unroll
      for (int j = 0; j < 4; ++j) {
        float x1 = bf2f((ushort)kreg1[2 * j]);
        float x2 = bf2f((ushort)kreg1[2 * j + 1]);
        pk.u[j] = cvtpk_bf16(x1 * cs[j] - x2 * sn[j], x1 * sn[j] + x2 * cs[j]);
      }
      *(bf16x8*)((char*)Kb + skk * 144 + (((sd0 + 8) * 2) ^ swk)) = pk.v;
    }
#pragma unroll
    for (int j = 0; j < 8; ++j) {
      int d0 = sd0 + j;
      *(short*)((char*)Vb + d0 * 144 +
                ((skk * 2) ^ (((d0 >> 4) & 3) << 5))) = vreg0[j];
      int d1 = sd0 + 8 + j;
      *(short*)((char*)Vb + d1 * 144 +
                ((skk * 2) ^ (((d1 >> 4) & 3) << 5))) = vreg1[j];
    }
  };

  // prologue: stage chunk cstart
  issue(cstart);
  write_chunk(cstart);

  for (int c = cstart; c < 4; ++c) {
    if (c < 3) issue(c + 1);     // loads in flight during compute
    __syncthreads();             // buf[c&1] visible to all waves
    if (c >= cw0 && c <= cw1) {
      const char* Kb = (const char*)Kc[c & 1];
      const char* Vb = (const char*)Vt[c & 1];

      bf16x8 ka[2][4];
#pragma unroll
      for (int t2 = 0; t2 < 2; ++t2)
#pragma unroll
        for (int s = 0; s < 4; ++s) {
          int kk = 32 * t2 + lq;
          int byteoff =
              kk * 144 + ((32 * s + 16 * hi) ^ (((kk >> 3) & 3) << 5));
          ka[t2][s] = *(const bf16x8*)(Kb + byteoff);
        }
      f32x16 st0 = Z16, st1 = Z16;
#pragma unroll
      for (int s = 0; s < 4; ++s) {
        st0 = __builtin_amdgcn_mfma_f32_32x32x16_bf16(ka[0][s], qf[s], st0, 0, 0, 0);
        st1 = __builtin_amdgcn_mfma_f32_32x32x16_bf16(ka[1][s], qf[s], st1, 0, 0, 0);
      }

      float p2[2][16];
      float pmax = -3.0e38f;
#pragma unroll
      for (int t2 = 0; t2 < 2; ++t2)
#pragma unroll
        for (int r = 0; r < 16; ++r) {
          int key = c * 64 + 32 * t2 + (r & 3) + 8 * (r >> 2) + 4 * hi;
          float sv = (t2 ? st1[r] : st0[r]);
          bool act = (key >= qi) && (key <= qi + 128);
          sv = act ? sv : -1.0e30f;
          p2[t2][r] = sv;
          pmax = fmaxf(pmax, sv);
        }
      pmax = fmaxf(pmax, __shfl_xor(pmax, 32));
      if (__any(pmax > m0 + 8.f)) {
        float nm = fmaxf(m0, pmax);
        float rr = __expf(m0 - nm);
        l *= rr;
        m0 = nm;
        rbuf[w][lq] = rr;
        asm volatile("s_waitcnt lgkmcnt(0)" ::: "memory");
#pragma unroll
        for (int a = 0; a < 4; ++a) {
          f32x4 r4 = *(const f32x4*)&rbuf[w][8 * a + 4 * hi];
#pragma unroll
          for (int j = 0; j < 4; ++j) {
            oa0[4 * a + j] *= r4[j];
            oa1[4 * a + j] *= r4[j];
          }
        }
      }
      float lsum = 0.f;
#pragma unroll
      for (int t2 = 0; t2 < 2; ++t2)
#pragma unroll
        for (int r = 0; r < 16; ++r) {
          float p = __expf(p2[t2][r] - m0);
          p2[t2][r] = p;
          lsum += p;
        }
      l += lsum + __shfl_xor(lsum, 32);

      union { uint u[4]; bf16x8 v; } pa[4];
#pragma unroll
      for (int t2 = 0; t2 < 2; ++t2)
#pragma unroll
        for (int sl = 0; sl < 2; ++sl) {
          const float* pp = &p2[t2][8 * sl];
          uint a0 = cvtpk_bf16(pp[0], pp[1]);
          uint a1 = cvtpk_bf16(pp[2], pp[3]);
          uint b0 = cvtpk_bf16(pp[4], pp[5]);
          uint b1 = cvtpk_bf16(pp[6], pp[7]);
          perm32swap(a0, b0);
          perm32swap(a1, b1);
          int slot = 2 * t2 + sl;
          pa[slot].u[0] = a0; pa[slot].u[1] = a1;
          pa[slot].u[2] = b0; pa[slot].u[3] = b1;
        }

#pragma unroll
      for (int slot = 0; slot < 4; ++slot) {
        {
          int d = lq;
          int byteoff =
              d * 144 + ((32 * slot + 16 * hi) ^ (((d >> 4) & 3) << 5));
          bf16x8 vb = *(const bf16x8*)(Vb + byteoff);
          oa0 = __builtin_amdgcn_mfma_f32_32x32x16_bf16(pa[slot].v, vb, oa0, 0, 0, 0);
        }
        {
          int d = 32 + lq;
          int byteoff =
              d * 144 + ((32 * slot + 16 * hi) ^ (((d >> 4) & 3) << 5));
          bf16x8 vb = *(const bf16x8*)(Vb + byteoff);
          oa1 = __builtin_amdgcn_mfma_f32_32x32x16_bf16(pa[slot].v, vb, oa1, 0, 0, 0);
        }
      }
    }
    if (c < 3) write_chunk(c + 1);  // regs -> other buffer (post-compute)
  }

  rbuf[w][lq] = 1.f / l;
  asm volatile("s_waitcnt lgkmcnt(0)" ::: "memory");
  const int q0 = nbIdx * 128 + 32 * w;
#pragma unroll
  for (int a = 0; a < 4; ++a) {
    f32x4 r4 = *(const f32x4*)&rbuf[w][8 * a + 4 * hi];
#pragma unroll
    for (int j = 0; j < 4; ++j) {
      int tok = q0 + 8 * a + 4 * hi + j;
      __hip_bfloat16* orow = o_out + (seqBase + tok) * 512 + h * 64;
      orow[lq] = __float2bfloat16(oa0[4 * a + j] * r4[j]);
      orow[32 + lq] = __float2bfloat16(oa1[4 * a + j] * r4[j]);
    }
  }
}

// ---------------------------------------------------------------- kernel 5
__global__ __launch_bounds__(256) void head_kernel(
    const float* __restrict__ pre, const float* __restrict__ g,
    const float* __restrict__ b, const float* __restrict__ hw,
    const float* __restrict__ hb, float* __restrict__ out) {
  __shared__ float lds8[8];
  __shared__ float ys[512];
  __shared__ float raw[9];
  const int t = blockIdx.x;
  const int tid = threadIdx.x;
  float2 v = *(const float2*)&pre[(size_t)t * 512 + tid * 2];
  float mean, rstd;
  blockLNStats(v.x + v.y, v.x * v.x + v.y * v.y, lds8, mean, rstd);
  float y0 = (v.x - mean) * rstd * g[2 * tid] + b[2 * tid];
  float y1 = (v.y - mean) * rstd * g[2 * tid + 1] + b[2 * tid + 1];
  ys[2 * tid] = siluf(y0);
  ys[2 * tid + 1] = siluf(y1);
  __syncthreads();
  const int wave = tid >> 6;
  const int lane = tid & 63;
  for (int r = wave; r < 9; r += 4) {
    float p = 0.f;
#pragma unroll
    for (int i = 0; i < 8; ++i)
      p = fmaf(ys[lane + i * 64], hw[r * 512 + lane + i * 64], p);
    p = waveReduceSum(p);
    if (lane == 0) raw[r] = p + hb[r];
  }
  __syncthreads();
  if (tid == 0) {
    float* op = out + (size_t)t * 9;
    op[0] = fmaxf(raw[0], 0.f) + log1pf(expf(-fabsf(raw[0])));
    op[1] = fmaxf(raw[1], 0.f) + log1pf(expf(-fabsf(raw[1])));
    op[2] = 1.f / (1.f + expf(-raw[2]));
    op[3] = 1.f / (1.f + expf(-raw[3]));
    op[4] = 1.f / (1.f + expf(-raw[4]));
    float mx = fmaxf(fmaxf(raw[5], raw[6]), fmaxf(raw[7], raw[8]));
    float e0 = expf(raw[5] - mx), e1 = expf(raw[6] - mx);
    float e2 = expf(raw[7] - mx), e3 = expf(raw[8] - mx);
    float inv = 1.f / (e0 + e1 + e2 + e3);
    op[5] = e0 * inv; op[6] = e1 * inv; op[7] = e2 * inv; op[8] = e3 * inv;
  }
}

// ---------------------------------------------------------------- launch
// Workspace layout (~133 MB peak):
//   w16: bf16 [inst | outp | qkv(permuted) | wcat] ; rope table (2MB)
//   R1 (96MB): {cat M*576 | Fb M*192} -> qkvb M*1536 -> pre2 fp32 M*512
//   R2 (32MB): hb bf16 [in-place LN] -> att bf16
extern "C" void kernel_launch(void* const* d_in, const int* in_sizes, int n_in,
                              void* d_out, int out_size, void* d_ws,
                              size_t ws_size, hipStream_t stream) {
  const float* emb = (const float*)d_in[0];
  const float* reg_w = (const float*)d_in[1];
  const float* reg_b = (const float*)d_in[2];
  const float* br_w = (const float*)d_in[3];
  const float* br_b = (const float*)d_in[4];
  const float* mem_w = (const float*)d_in[5];
  const float* mem_b = (const float*)d_in[6];
  const float* inst_w = (const float*)d_in[7];
  const float* inst_b = (const float*)d_in[8];
  const float* ln1_g = (const float*)d_in[9];
  const float* ln1_b = (const float*)d_in[10];
  const float* qkv_w = (const float*)d_in[11];
  const float* outp_w = (const float*)d_in[12];
  const float* outp_b = (const float*)d_in[13];
  const float* ln2_g = (const float*)d_in[14];
  const float* ln2_b = (const float*)d_in[15];
  const float* head_w = (const float*)d_in[16];
  const float* head_b = (const float*)d_in[17];
  const int* x = (const int*)d_in[18];
  float* out = (float*)d_out;

  const int M = M_TOK;
  char* wsb = (char*)d_ws;
  __hip_bfloat16* w16 = (__hip_bfloat16*)wsb;
  __hip_bfloat16* w1 = w16;                        // inst
  __hip_bfloat16* w3 = w16 + NW1;                  // outp
  __hip_bfloat16* w2 = w16 + NW1 + NW3;            // qkv (permuted)
  __hip_bfloat16* wcat = w16 + NW1 + NW3 + NW2;    // feature proj
  size_t woff = ((size_t)(NW1 + NW2 + NW3 + NW4) * 2 + 255) & ~(size_t)255;
  float2* tab = (float2*)(wsb + woff);             // 2MB
  size_t toff = woff + (size_t)NTAB * 8;
  char* r1 = wsb + toff;                           // 96 MB region
  char* r2 = r1 + (size_t)M * 1536 * 2;            // 32 MB region
  __hip_bfloat16* cat = (__hip_bfloat16*)r1;       // M*576
  __hip_bfloat16* Fb = (__hip_bfloat16*)(r1 + (size_t)M * 576 * 2);  // M*192
  __hip_bfloat16* qkvb = (__hip_bfloat16*)r1;      // M*1536
  float* pre2 = (float*)r1;                        // M*512 fp32
  __hip_bfloat16* hb = (__hip_bfloat16*)r2;        // M*512
  __hip_bfloat16* att = (__hip_bfloat16*)r2;       // M*512

  // 0. all weight conversion + rope table (one kernel)
  const int setup_tot = NW1 + NW3 + NW2 + NW4 + NTAB;
  setup_kernel<<<(setup_tot + 255) / 256, 256, 0, stream>>>(
      inst_w, outp_w, qkv_w, reg_w, reg_b, br_w, br_b, mem_w, mem_b, w16, tab);
  // 1. prep: cat[:,0:192] = silu(emb[tid]) ; Fb = [1, feats, 0]
  prep_kernel<<<(M * 48) / 256, 256, 0, stream>>>(x, emb, cat, Fb);
  // 1b. feature proj: cat[:,192:576] = silu(Fb @ wcat^T)
  gemm_mfma<__hip_bfloat16, true><<<dim3(M / 128, 3), 256, 0, stream>>>(
      (const ushort*)Fb, (const ushort*)wcat, nullptr, cat + 192, M, 384, 192,
      576);
  // 2. inst proj: cat @ w1^T + b -> hb (bf16)
  gemm_mfma<__hip_bfloat16><<<dim3(M / 128, 4), 256, 0, stream>>>(
      (const ushort*)cat, (const ushort*)w1, inst_b, hb, M, 512, 576, 512);
  // 3. LN1 + silu in place (bf16)
  ln_silu_kernel<<<M, 256, 0, stream>>>(hb, ln1_g, ln1_b);
  // 4. qkv proj (permuted cols): hb @ w2^T -> qkvb planes [Q|K|V]
  gemm_mfma<__hip_bfloat16><<<dim3(M / 128, 12), 256, 0, stream>>>(
      (const ushort*)hb, (const ushort*)w2, nullptr, qkvb, M, 1536, 512, 1536);
  // 5. attention (MFMA) -> att (bf16, [M][512] heads concatenated)
  attn_kernel<<<BATCH * 8 * 64, 256, 0, stream>>>(qkvb, tab, att);
  // 6. out proj: att @ w3^T + b -> pre2 (fp32)
  gemm_mfma<float><<<dim3(M / 128, 4), 256, 0, stream>>>(
      (const ushort*)att, (const ushort*)w3, outp_b, pre2, M, 512, 512, 512);
  // 7. LN2 + silu + head + activations -> out
  head_kernel<<<M, 256, 0, stream>>>(pre2, ln2_g, ln2_b, head_w, head_b, out);
}

// Round 10
// 328.920 us; speedup vs baseline: 6.8686x; 1.0189x over previous
//
#include <hip/hip_runtime.h>
#include <hip/hip_bf16.h>
#include <math.h>
#include <type_traits>

#define LSEQ 8192
#define BATCH 4
#define M_TOK (BATCH * LSEQ)

typedef __attribute__((ext_vector_type(8))) short bf16x8;   // 8 bf16 = 4 VGPR
typedef __attribute__((ext_vector_type(4))) float f32x4;
typedef __attribute__((ext_vector_type(16))) float f32x16;

// ---------------------------------------------------------------- helpers
__device__ __forceinline__ float siluf(float x) {
  return x / (1.f + __expf(-x));
}

__device__ __forceinline__ float bf2f(uint u16) {
  union { float f; uint u; } c;
  c.u = u16 << 16;
  return c.f;
}

__device__ __forceinline__ uint cvtpk_bf16(float lo, float hi) {
  uint r;
  asm volatile("v_cvt_pk_bf16_f32 %0, %1, %2" : "=v"(r) : "v"(lo), "v"(hi));
  return r;
}

// swaps hi 32 lanes of a with lo 32 lanes of b
__device__ __forceinline__ void perm32swap(uint& a, uint& b) {
  asm volatile("v_permlane32_swap_b32 %0, %1" : "+v"(a), "+v"(b));
}

// async global->LDS, 16B per lane; LDS dest = wave-uniform base + lane*16
__device__ __forceinline__ void gload16(const ushort* g, short* l) {
  __builtin_amdgcn_global_load_lds(
      (const __attribute__((address_space(1))) void*)g,
      (__attribute__((address_space(3))) void*)l, 16, 0, 0);
}

__device__ __forceinline__ float waveReduceSum(float v) {
#pragma unroll
  for (int off = 32; off; off >>= 1) v += __shfl_xor(v, off, 64);
  return v;
}

__device__ __forceinline__ void blockLNStats(float s, float ss, float* lds8,
                                             float& mean, float& rstd) {
  s = waveReduceSum(s);
  ss = waveReduceSum(ss);
  int wave = threadIdx.x >> 6;
  int lane = threadIdx.x & 63;
  if (lane == 0) { lds8[wave] = s; lds8[4 + wave] = ss; }
  __syncthreads();
  s  = lds8[0] + lds8[1] + lds8[2] + lds8[3];
  ss = lds8[4] + lds8[5] + lds8[6] + lds8[7];
  mean = s * (1.f / 512.f);
  float var = ss * (1.f / 512.f) - mean * mean;
  rstd = rsqrtf(var + 1e-5f);
}

// ---------------------------------------------------------------- setup
// One kernel for all weight conversion + rope table.
#define NW1 (512 * 576)
#define NW3 (512 * 512)
#define NW2 (1536 * 512)
#define NW4 (384 * 192)
#define NTAB (8192 * 32)

__global__ __launch_bounds__(256) void setup_kernel(
    const float* __restrict__ inst_w, const float* __restrict__ outp_w,
    const float* __restrict__ qkv_w, const float* __restrict__ reg_w,
    const float* __restrict__ reg_b, const float* __restrict__ br_w,
    const float* __restrict__ br_b, const float* __restrict__ mem_w,
    const float* __restrict__ mem_b, __hip_bfloat16* __restrict__ w16,
    float2* __restrict__ tab) {
  int i = blockIdx.x * 256 + threadIdx.x;
  if (i < NW1) {
    w16[i] = __float2bfloat16(inst_w[i]);
    return;
  }
  i -= NW1;
  if (i < NW3) {
    w16[NW1 + i] = __float2bfloat16(outp_w[i]);
    return;
  }
  i -= NW3;
  if (i < NW2) {
    // qkv row permutation: out row n' = which*512 + h*64 + d
    // from src row n = h*192 + d*3 + which -> qkvb planes [Q|K|V]
    int np = i / 512, k = i % 512;
    int which = np >> 9, rem = np & 511;
    int h = rem >> 6, d = rem & 63;
    int n = h * 192 + d * 3 + which;
    w16[NW1 + NW3 + i] = __float2bfloat16(qkv_w[n * 512 + k]);
    return;
  }
  i -= NW2;
  if (i < NW4) {
    // Wcat[384][192]: F cols [0]=1(bias),[1..64]=reg,[65..128]=mem,[129..160]=br
    int o = i / 192, c = i % 192;
    float v = 0.f;
    if (o < 128) {
      if (c == 0) v = reg_b[o];
      else if (c <= 64) v = reg_w[o * 64 + (c - 1)];
    } else if (o < 256) {
      int oo = o - 128;
      if (c == 0) v = br_b[oo];
      else if (c >= 129 && c <= 160) v = br_w[oo * 32 + (c - 129)];
    } else {
      int oo = o - 256;
      if (c == 0) v = mem_b[oo];
      else if (c >= 65 && c <= 128) v = mem_w[oo * 64 + (c - 65)];
    }
    w16[NW1 + NW3 + NW2 + i] = __float2bfloat16(v);
    return;
  }
  i -= NW4;
  if (i < NTAB) {
    int pos = i >> 5, p = i & 31;
    float inv = expf(-(float)p * 0.28782313662f);  // ln(10000)/32
    float sn, cs;
    sincosf((float)pos * inv, &sn, &cs);
    tab[i] = make_float2(cs, sn);
  }
}

// ---------------------------------------------------------------- prep
__global__ __launch_bounds__(256) void prep_kernel(
    const int* __restrict__ x, const float* __restrict__ emb,
    __hip_bfloat16* __restrict__ cat, __hip_bfloat16* __restrict__ Fb) {
  int gid = blockIdx.x * 256 + threadIdx.x;
  int t = gid / 48;
  int g = gid % 48;
  if (t >= M_TOK) return;
  const int* xr = x + (size_t)t * 161;
  union { __hip_bfloat16 h[8]; uint4 u; } pk;
  if (g < 24) {
    int c0 = g * 8;
    const float* e = emb + xr[0] * 192 + c0;
#pragma unroll
    for (int j = 0; j < 8; ++j) pk.h[j] = __float2bfloat16(siluf(e[j]));
    *(uint4*)&cat[(size_t)t * 576 + c0] = pk.u;
  } else {
    int c0 = (g - 24) * 8;
#pragma unroll
    for (int j = 0; j < 8; ++j) {
      int c = c0 + j;
      float v = (c == 0) ? 1.f : ((c <= 160) ? (float)xr[c] : 0.f);
      pk.h[j] = __float2bfloat16(v);
    }
    *(uint4*)&Fb[(size_t)t * 192 + c0] = pk.u;
  }
}

// ---------------------------------------------------------------- MFMA GEMM
// m97 structure + LDS bank-swizzle via pre-swizzled global source (rule #21):
// LDS stays linear [32rows][4 chunks of 16B] per wave-quarter; lane l stages
// global chunk (l&3)^((l>>2)&3), so LDS slot (row,c) holds global chunk
// c^(row&3). Frag reads XOR the chunk index back: ((lane>>4)^(lane&3)).
// Turns the 8-way ds_read_b128 conflict into 4-way.
template <typename OT, bool SILU = false>
__global__ __launch_bounds__(256) void gemm_mfma(
    const ushort* __restrict__ A, const ushort* __restrict__ W,
    const float* __restrict__ bias, OT* __restrict__ C, int M, int N, int K,
    int ldc) {
  __shared__ __align__(16) short As[2][128 * 32];
  __shared__ __align__(16) short Bs[2][128 * 32];
  const int tid = threadIdx.x;
  const int lane = tid & 63;
  const int wid = tid >> 6;
  const int wr = wid >> 1, wc = wid & 1;
  const int row0 = blockIdx.x * 128, col0 = blockIdx.y * 128;
  const int lrow = lane >> 2;                              // 0..15
  const int lch = (((lane & 3) ^ (lrow & 3)) << 3);        // swizzled src chunk
  const int frow = lane & 15;
  const int rdsw = (((lane >> 4) ^ (lane & 3)) << 3);      // swizzled read chunk

  const ushort* Abase = A + (size_t)(row0 + 32 * wid + lrow) * K + lch;
  const ushort* Wbase = W + (size_t)(col0 + 32 * wid + lrow) * K + lch;
  short* Al[2] = {&As[0][32 * wid * 32], &As[1][32 * wid * 32]};
  short* Bl[2] = {&Bs[0][32 * wid * 32], &Bs[1][32 * wid * 32]};

  f32x4 acc[4][4];
  const f32x4 z = {0.f, 0.f, 0.f, 0.f};
#pragma unroll
  for (int i = 0; i < 4; ++i)
#pragma unroll
    for (int j = 0; j < 4; ++j) acc[i][j] = z;

  const int T = K >> 5;
  gload16(Abase, Al[0]);
  gload16(Abase + (size_t)16 * K, Al[0] + 512);
  gload16(Wbase, Bl[0]);
  gload16(Wbase + (size_t)16 * K, Bl[0] + 512);

  for (int t = 0; t < T; ++t) {
    __syncthreads();
    if (t + 1 < T) {
      const ushort* An = Abase + (t + 1) * 32;
      const ushort* Wn = Wbase + (t + 1) * 32;
      short* Ad = Al[(t + 1) & 1];
      short* Bd = Bl[(t + 1) & 1];
      gload16(An, Ad);
      gload16(An + (size_t)16 * K, Ad + 512);
      gload16(Wn, Bd);
      gload16(Wn + (size_t)16 * K, Bd + 512);
    }
    const short* Ab = As[t & 1];
    const short* Bb = Bs[t & 1];
    bf16x8 af[4], bfr[4];
#pragma unroll
    for (int i = 0; i < 4; ++i)
      af[i] = *(const bf16x8*)&Ab[(wr * 64 + i * 16 + frow) * 32 + rdsw];
#pragma unroll
    for (int j = 0; j < 4; ++j)
      bfr[j] = *(const bf16x8*)&Bb[(wc * 64 + j * 16 + frow) * 32 + rdsw];
#pragma unroll
    for (int i = 0; i < 4; ++i)
#pragma unroll
      for (int j = 0; j < 4; ++j)
        acc[i][j] = __builtin_amdgcn_mfma_f32_16x16x32_bf16(af[i], bfr[j],
                                                            acc[i][j], 0, 0, 0);
  }

  const int crow0 = row0 + wr * 64 + (lane >> 4) * 4;
  const int ccol0 = col0 + wc * 64 + (lane & 15);
#pragma unroll
  for (int j = 0; j < 4; ++j) {
    const int col = ccol0 + j * 16;
    const float bv = bias ? bias[col] : 0.f;
#pragma unroll
    for (int i = 0; i < 4; ++i) {
#pragma unroll
      for (int r = 0; r < 4; ++r) {
        float v = acc[i][j][r] + bv;
        if constexpr (SILU) v = siluf(v);
        size_t off = (size_t)(crow0 + i * 16 + r) * ldc + col;
        if constexpr (std::is_same<OT, float>::value) {
          C[off] = v;
        } else {
          C[off] = __float2bfloat16(v);
        }
      }
    }
  }
}

// ---------------------------------------------------------------- kernel 3
__global__ __launch_bounds__(256) void ln_silu_kernel(
    __hip_bfloat16* __restrict__ buf, const float* __restrict__ g,
    const float* __restrict__ b) {
  __shared__ float lds8[8];
  const int t = blockIdx.x;
  const int tid = threadIdx.x;
  uint u = *(const uint*)&buf[(size_t)t * 512 + tid * 2];
  float x0 = bf2f(u & 0xffffu);
  float x1 = bf2f(u >> 16);
  float mean, rstd;
  blockLNStats(x0 + x1, x0 * x0 + x1 * x1, lds8, mean, rstd);
  float y0 = siluf((x0 - mean) * rstd * g[2 * tid] + b[2 * tid]);
  float y1 = siluf((x1 - mean) * rstd * g[2 * tid + 1] + b[2 * tid + 1]);
  union { __hip_bfloat16 h[2]; uint u; } pk;
  pk.h[0] = __float2bfloat16(y0);
  pk.h[1] = __float2bfloat16(y1);
  *(uint*)&buf[(size_t)t * 512 + tid * 2] = pk.u;
}

// ---------------------------------------------------------------- attn (MFMA)
// One block per (b,h,window-block): 4 waves x 32 queries. KV chunks of 64 keys,
// double-buffered with async-split staging; one barrier per chunk.
__global__ __launch_bounds__(256) void attn_kernel(
    const __hip_bfloat16* __restrict__ qkv, const float2* __restrict__ tab,
    __hip_bfloat16* __restrict__ o_out) {
  __shared__ __align__(16) short Kc[2][64 * 72];   // [key 64][dim 64 pad 72]
  __shared__ __align__(16) short Vt[2][64 * 72];   // [dim 64][key 64 pad 72]
  __shared__ __align__(16) float rbuf[4][32];
  const int blk = blockIdx.x;
  const int nbIdx = blk & 63;
  const int h = (blk >> 6) & 7;
  const int b = blk >> 9;
  const int tid = threadIdx.x;
  const int w = tid >> 6;
  const int lane = tid & 63;
  const int lq = lane & 31;
  const int hi = lane >> 5;
  const size_t seqBase = (size_t)b * LSEQ;
  const int qi = w * 32 + lq;
  const int qtok = nbIdx * 128 + qi;

  const ushort* qkvu = (const ushort*)qkv;

  // ---- load Q fragments (B-operand), rope + 1/8 scale folded in
  bf16x8 qf[4];
  {
    const ushort* Qrow = qkvu + (seqBase + qtok) * 1536 + h * 64;
#pragma unroll
    for (int s = 0; s < 4; ++s) {
      int dim0 = 16 * s + 8 * hi;
      bf16x8 qv = *(const bf16x8*)(Qrow + dim0);
      const float4* tp = (const float4*)(tab + qtok * 32 + dim0 / 2);
      float4 t01 = tp[0], t23 = tp[1];
      float cs[4] = {t01.x, t01.z, t23.x, t23.z};
      float sn[4] = {t01.y, t01.w, t23.y, t23.w};
      union { uint u[4]; bf16x8 v; } pk;
#pragma unroll
      for (int j = 0; j < 4; ++j) {
        float x1 = bf2f((ushort)qv[2 * j]);
        float x2 = bf2f((ushort)qv[2 * j + 1]);
        float r0 = (x1 * cs[j] - x2 * sn[j]) * 0.125f;
        float r1 = (x1 * sn[j] + x2 * cs[j]) * 0.125f;
        pk.u[j] = cvtpk_bf16(r0, r1);
      }
      qf[s] = pk.v;
    }
  }

  const f32x16 Z16 = {0.f};
  f32x16 oa0 = Z16, oa1 = Z16;
  float m0 = -3.0e38f, l = 0.f;

  const int cstart = (nbIdx == 0) ? 2 : 0;
  const int cw0 = (w >= 2) ? 1 : 0;
  const int cw1 = (w >= 2) ? 3 : 2;

  const int skk = tid >> 2;         // key row this thread stages
  const int sd0 = (tid & 3) * 16;   // dim group [sd0, sd0+16)

  bf16x8 kreg0, kreg1, vreg0, vreg1;  // in-flight staging registers

  auto issue = [&](int c) {
    int ktok = (nbIdx - 1) * 128 + c * 64 + skk;
    const ushort* base = qkvu + (seqBase + ktok) * 1536 + h * 64 + sd0;
    kreg0 = *(const bf16x8*)(base + 512);
    kreg1 = *(const bf16x8*)(base + 512 + 8);
    vreg0 = *(const bf16x8*)(base + 1024);
    vreg1 = *(const bf16x8*)(base + 1024 + 8);
  };

  auto write_chunk = [&](int c) {
    short* Kb = Kc[c & 1];
    short* Vb = Vt[c & 1];
    int ktok = (nbIdx - 1) * 128 + c * 64 + skk;
    const float4* tp = (const float4*)(tab + ktok * 32 + (sd0 >> 1));
    float4 t0 = tp[0], t1 = tp[1], t2 = tp[2], t3 = tp[3];
    const int swk = ((skk >> 3) & 3) << 5;
    {
      float cs[4] = {t0.x, t0.z, t1.x, t1.z};
      float sn[4] = {t0.y, t0.w, t1.y, t1.w};
      union { uint u[4]; bf16x8 v; } pk;
#pragma unroll
      for (int j = 0; j < 4; ++j) {
        float x1 = bf2f((ushort)kreg0[2 * j]);
        float x2 = bf2f((ushort)kreg0[2 * j + 1]);
        pk.u[j] = cvtpk_bf16(x1 * cs[j] - x2 * sn[j], x1 * sn[j] + x2 * cs[j]);
      }
      *(bf16x8*)((char*)Kb + skk * 144 + ((sd0 * 2) ^ swk)) = pk.v;
    }
    {
      float cs[4] = {t2.x, t2.z, t3.x, t3.z};
      float sn[4] = {t2.y, t2.w, t3.y, t3.w};
      union { uint u[4]; bf16x8 v; } pk;
#pragma unroll
      for (int j = 0; j < 4; ++j) {
        float x1 = bf2f((ushort)kreg1[2 * j]);
        float x2 = bf2f((ushort)kreg1[2 * j + 1]);
        pk.u[j] = cvtpk_bf16(x1 * cs[j] - x2 * sn[j], x1 * sn[j] + x2 * cs[j]);
      }
      *(bf16x8*)((char*)Kb + skk * 144 + (((sd0 + 8) * 2) ^ swk)) = pk.v;
    }
#pragma unroll
    for (int j = 0; j < 8; ++j) {
      int d0 = sd0 + j;
      *(short*)((char*)Vb + d0 * 144 +
                ((skk * 2) ^ (((d0 >> 4) & 3) << 5))) = vreg0[j];
      int d1 = sd0 + 8 + j;
      *(short*)((char*)Vb + d1 * 144 +
                ((skk * 2) ^ (((d1 >> 4) & 3) << 5))) = vreg1[j];
    }
  };

  // prologue: stage chunk cstart
  issue(cstart);
  write_chunk(cstart);

  for (int c = cstart; c < 4; ++c) {
    if (c < 3) issue(c + 1);     // loads in flight during compute
    __syncthreads();             // buf[c&1] visible to all waves
    if (c >= cw0 && c <= cw1) {
      const char* Kb = (const char*)Kc[c & 1];
      const char* Vb = (const char*)Vt[c & 1];

      bf16x8 ka[2][4];
#pragma unroll
      for (int t2 = 0; t2 < 2; ++t2)
#pragma unroll
        for (int s = 0; s < 4; ++s) {
          int kk = 32 * t2 + lq;
          int byteoff =
              kk * 144 + ((32 * s + 16 * hi) ^ (((kk >> 3) & 3) << 5));
          ka[t2][s] = *(const bf16x8*)(Kb + byteoff);
        }
      f32x16 st0 = Z16, st1 = Z16;
#pragma unroll
      for (int s = 0; s < 4; ++s) {
        st0 = __builtin_amdgcn_mfma_f32_32x32x16_bf16(ka[0][s], qf[s], st0, 0, 0, 0);
        st1 = __builtin_amdgcn_mfma_f32_32x32x16_bf16(ka[1][s], qf[s], st1, 0, 0, 0);
      }

      float p2[2][16];
      float pmax = -3.0e38f;
#pragma unroll
      for (int t2 = 0; t2 < 2; ++t2)
#pragma unroll
        for (int r = 0; r < 16; ++r) {
          int key = c * 64 + 32 * t2 + (r & 3) + 8 * (r >> 2) + 4 * hi;
          float sv = (t2 ? st1[r] : st0[r]);
          bool act = (key >= qi) && (key <= qi + 128);
          sv = act ? sv : -1.0e30f;
          p2[t2][r] = sv;
          pmax = fmaxf(pmax, sv);
        }
      pmax = fmaxf(pmax, __shfl_xor(pmax, 32));
      if (__any(pmax > m0 + 8.f)) {
        float nm = fmaxf(m0, pmax);
        float rr = __expf(m0 - nm);
        l *= rr;
        m0 = nm;
        rbuf[w][lq] = rr;
        asm volatile("s_waitcnt lgkmcnt(0)" ::: "memory");
#pragma unroll
        for (int a = 0; a < 4; ++a) {
          f32x4 r4 = *(const f32x4*)&rbuf[w][8 * a + 4 * hi];
#pragma unroll
          for (int j = 0; j < 4; ++j) {
            oa0[4 * a + j] *= r4[j];
            oa1[4 * a + j] *= r4[j];
          }
        }
      }
      float lsum = 0.f;
#pragma unroll
      for (int t2 = 0; t2 < 2; ++t2)
#pragma unroll
        for (int r = 0; r < 16; ++r) {
          float p = __expf(p2[t2][r] - m0);
          p2[t2][r] = p;
          lsum += p;
        }
      l += lsum + __shfl_xor(lsum, 32);

      union { uint u[4]; bf16x8 v; } pa[4];
#pragma unroll
      for (int t2 = 0; t2 < 2; ++t2)
#pragma unroll
        for (int sl = 0; sl < 2; ++sl) {
          const float* pp = &p2[t2][8 * sl];
          uint a0 = cvtpk_bf16(pp[0], pp[1]);
          uint a1 = cvtpk_bf16(pp[2], pp[3]);
          uint b0 = cvtpk_bf16(pp[4], pp[5]);
          uint b1 = cvtpk_bf16(pp[6], pp[7]);
          perm32swap(a0, b0);
          perm32swap(a1, b1);
          int slot = 2 * t2 + sl;
          pa[slot].u[0] = a0; pa[slot].u[1] = a1;
          pa[slot].u[2] = b0; pa[slot].u[3] = b1;
        }

#pragma unroll
      for (int slot = 0; slot < 4; ++slot) {
        {
          int d = lq;
          int byteoff =
              d * 144 + ((32 * slot + 16 * hi) ^ (((d >> 4) & 3) << 5));
          bf16x8 vb = *(const bf16x8*)(Vb + byteoff);
          oa0 = __builtin_amdgcn_mfma_f32_32x32x16_bf16(pa[slot].v, vb, oa0, 0, 0, 0);
        }
        {
          int d = 32 + lq;
          int byteoff =
              d * 144 + ((32 * slot + 16 * hi) ^ (((d >> 4) & 3) << 5));
          bf16x8 vb = *(const bf16x8*)(Vb + byteoff);
          oa1 = __builtin_amdgcn_mfma_f32_32x32x16_bf16(pa[slot].v, vb, oa1, 0, 0, 0);
        }
      }
    }
    if (c < 3) write_chunk(c + 1);  // regs -> other buffer (post-compute)
  }

  rbuf[w][lq] = 1.f / l;
  asm volatile("s_waitcnt lgkmcnt(0)" ::: "memory");
  const int q0 = nbIdx * 128 + 32 * w;
#pragma unroll
  for (int a = 0; a < 4; ++a) {
    f32x4 r4 = *(const f32x4*)&rbuf[w][8 * a + 4 * hi];
#pragma unroll
    for (int j = 0; j < 4; ++j) {
      int tok = q0 + 8 * a + 4 * hi + j;
      __hip_bfloat16* orow = o_out + (seqBase + tok) * 512 + h * 64;
      orow[lq] = __float2bfloat16(oa0[4 * a + j] * r4[j]);
      orow[32 + lq] = __float2bfloat16(oa1[4 * a + j] * r4[j]);
    }
  }
}

// ---------------------------------------------------------------- kernel 5
// LN2 + silu + head(9) + activations, bf16 input
__global__ __launch_bounds__(256) void head_kernel(
    const __hip_bfloat16* __restrict__ pre, const float* __restrict__ g,
    const float* __restrict__ b, const float* __restrict__ hw,
    const float* __restrict__ hb, float* __restrict__ out) {
  __shared__ float lds8[8];
  __shared__ float ys[512];
  __shared__ float raw[9];
  const int t = blockIdx.x;
  const int tid = threadIdx.x;
  uint u = *(const uint*)&pre[(size_t)t * 512 + tid * 2];
  float x0 = bf2f(u & 0xffffu);
  float x1 = bf2f(u >> 16);
  float mean, rstd;
  blockLNStats(x0 + x1, x0 * x0 + x1 * x1, lds8, mean, rstd);
  float y0 = (x0 - mean) * rstd * g[2 * tid] + b[2 * tid];
  float y1 = (x1 - mean) * rstd * g[2 * tid + 1] + b[2 * tid + 1];
  ys[2 * tid] = siluf(y0);
  ys[2 * tid + 1] = siluf(y1);
  __syncthreads();
  const int wave = tid >> 6;
  const int lane = tid & 63;
  for (int r = wave; r < 9; r += 4) {
    float p = 0.f;
#pragma unroll
    for (int i = 0; i < 8; ++i)
      p = fmaf(ys[lane + i * 64], hw[r * 512 + lane + i * 64], p);
    p = waveReduceSum(p);
    if (lane == 0) raw[r] = p + hb[r];
  }
  __syncthreads();
  if (tid == 0) {
    float* op = out + (size_t)t * 9;
    op[0] = fmaxf(raw[0], 0.f) + log1pf(expf(-fabsf(raw[0])));
    op[1] = fmaxf(raw[1], 0.f) + log1pf(expf(-fabsf(raw[1])));
    op[2] = 1.f / (1.f + expf(-raw[2]));
    op[3] = 1.f / (1.f + expf(-raw[3]));
    op[4] = 1.f / (1.f + expf(-raw[4]));
    float mx = fmaxf(fmaxf(raw[5], raw[6]), fmaxf(raw[7], raw[8]));
    float e0 = expf(raw[5] - mx), e1 = expf(raw[6] - mx);
    float e2 = expf(raw[7] - mx), e3 = expf(raw[8] - mx);
    float inv = 1.f / (e0 + e1 + e2 + e3);
    op[5] = e0 * inv; op[6] = e1 * inv; op[7] = e2 * inv; op[8] = e3 * inv;
  }
}

// ---------------------------------------------------------------- launch
// Workspace layout (~133 MB peak):
//   w16: bf16 [inst | outp | qkv(permuted) | wcat] ; rope table (2MB)
//   R1 (96MB): {cat M*576 | Fb M*192} -> qkvb M*1536 -> preb bf16 M*512
//   R2 (32MB): hb bf16 [in-place LN] -> att bf16
extern "C" void kernel_launch(void* const* d_in, const int* in_sizes, int n_in,
                              void* d_out, int out_size, void* d_ws,
                              size_t ws_size, hipStream_t stream) {
  const float* emb = (const float*)d_in[0];
  const float* reg_w = (const float*)d_in[1];
  const float* reg_b = (const float*)d_in[2];
  const float* br_w = (const float*)d_in[3];
  const float* br_b = (const float*)d_in[4];
  const float* mem_w = (const float*)d_in[5];
  const float* mem_b = (const float*)d_in[6];
  const float* inst_w = (const float*)d_in[7];
  const float* inst_b = (const float*)d_in[8];
  const float* ln1_g = (const float*)d_in[9];
  const float* ln1_b = (const float*)d_in[10];
  const float* qkv_w = (const float*)d_in[11];
  const float* outp_w = (const float*)d_in[12];
  const float* outp_b = (const float*)d_in[13];
  const float* ln2_g = (const float*)d_in[14];
  const float* ln2_b = (const float*)d_in[15];
  const float* head_w = (const float*)d_in[16];
  const float* head_b = (const float*)d_in[17];
  const int* x = (const int*)d_in[18];
  float* out = (float*)d_out;

  const int M = M_TOK;
  char* wsb = (char*)d_ws;
  __hip_bfloat16* w16 = (__hip_bfloat16*)wsb;
  __hip_bfloat16* w1 = w16;                        // inst
  __hip_bfloat16* w3 = w16 + NW1;                  // outp
  __hip_bfloat16* w2 = w16 + NW1 + NW3;            // qkv (permuted)
  __hip_bfloat16* wcat = w16 + NW1 + NW3 + NW2;    // feature proj
  size_t woff = ((size_t)(NW1 + NW2 + NW3 + NW4) * 2 + 255) & ~(size_t)255;
  float2* tab = (float2*)(wsb + woff);             // 2MB
  size_t toff = woff + (size_t)NTAB * 8;
  char* r1 = wsb + toff;                           // 96 MB region
  char* r2 = r1 + (size_t)M * 1536 * 2;            // 32 MB region
  __hip_bfloat16* cat = (__hip_bfloat16*)r1;       // M*576
  __hip_bfloat16* Fb = (__hip_bfloat16*)(r1 + (size_t)M * 576 * 2);  // M*192
  __hip_bfloat16* qkvb = (__hip_bfloat16*)r1;      // M*1536
  __hip_bfloat16* preb = (__hip_bfloat16*)r1;      // M*512 bf16
  __hip_bfloat16* hb = (__hip_bfloat16*)r2;        // M*512
  __hip_bfloat16* att = (__hip_bfloat16*)r2;       // M*512

  // 0. all weight conversion + rope table (one kernel)
  const int setup_tot = NW1 + NW3 + NW2 + NW4 + NTAB;
  setup_kernel<<<(setup_tot + 255) / 256, 256, 0, stream>>>(
      inst_w, outp_w, qkv_w, reg_w, reg_b, br_w, br_b, mem_w, mem_b, w16, tab);
  // 1. prep: cat[:,0:192] = silu(emb[tid]) ; Fb = [1, feats, 0]
  prep_kernel<<<(M * 48) / 256, 256, 0, stream>>>(x, emb, cat, Fb);
  // 1b. feature proj: cat[:,192:576] = silu(Fb @ wcat^T)
  gemm_mfma<__hip_bfloat16, true><<<dim3(M / 128, 3), 256, 0, stream>>>(
      (const ushort*)Fb, (const ushort*)wcat, nullptr, cat + 192, M, 384, 192,
      576);
  // 2. inst proj: cat @ w1^T + b -> hb (bf16)
  gemm_mfma<__hip_bfloat16><<<dim3(M / 128, 4), 256, 0, stream>>>(
      (const ushort*)cat, (const ushort*)w1, inst_b, hb, M, 512, 576, 512);
  // 3. LN1 + silu in place (bf16)
  ln_silu_kernel<<<M, 256, 0, stream>>>(hb, ln1_g, ln1_b);
  // 4. qkv proj (permuted cols): hb @ w2^T -> qkvb planes [Q|K|V]
  gemm_mfma<__hip_bfloat16><<<dim3(M / 128, 12), 256, 0, stream>>>(
      (const ushort*)hb, (const ushort*)w2, nullptr, qkvb, M, 1536, 512, 1536);
  // 5. attention (MFMA) -> att (bf16, [M][512] heads concatenated)
  attn_kernel<<<BATCH * 8 * 64, 256, 0, stream>>>(qkvb, tab, att);
  // 6. out proj: att @ w3^T + b -> preb (bf16)
  gemm_mfma<__hip_bfloat16><<<dim3(M / 128, 4), 256, 0, stream>>>(
      (const ushort*)att, (const ushort*)w3, outp_b, preb, M, 512, 512, 512);
  // 7. LN2 + silu + head + activations -> out
  head_kernel<<<M, 256, 0, stream>>>(preb, ln2_g, ln2_b, head_w, head_b, out);
}

// Round 11
// 317.240 us; speedup vs baseline: 7.1215x; 1.0368x over previous
//
#include <hip/hip_runtime.h>
#include <hip/hip_bf16.h>
#include <math.h>
#include <type_traits>

#define LSEQ 8192
#define BATCH 4
#define M_TOK (BATCH * LSEQ)

typedef __attribute__((ext_vector_type(8))) short bf16x8;   // 8 bf16 = 4 VGPR
typedef __attribute__((ext_vector_type(4))) float f32x4;
typedef __attribute__((ext_vector_type(16))) float f32x16;

// ---------------------------------------------------------------- helpers
__device__ __forceinline__ float siluf(float x) {
  return x / (1.f + __expf(-x));
}

__device__ __forceinline__ float bf2f(uint u16) {
  union { float f; uint u; } c;
  c.u = u16 << 16;
  return c.f;
}

__device__ __forceinline__ uint cvtpk_bf16(float lo, float hi) {
  uint r;
  asm volatile("v_cvt_pk_bf16_f32 %0, %1, %2" : "=v"(r) : "v"(lo), "v"(hi));
  return r;
}

// swaps hi 32 lanes of a with lo 32 lanes of b
__device__ __forceinline__ void perm32swap(uint& a, uint& b) {
  asm volatile("v_permlane32_swap_b32 %0, %1" : "+v"(a), "+v"(b));
}

// async global->LDS, 16B per lane; LDS dest = wave-uniform base + lane*16
__device__ __forceinline__ void gload16(const ushort* g, short* l) {
  __builtin_amdgcn_global_load_lds(
      (const __attribute__((address_space(1))) void*)g,
      (__attribute__((address_space(3))) void*)l, 16, 0, 0);
}

__device__ __forceinline__ float waveReduceSum(float v) {
#pragma unroll
  for (int off = 32; off; off >>= 1) v += __shfl_xor(v, off, 64);
  return v;
}

__device__ __forceinline__ void blockLNStats(float s, float ss, float* lds8,
                                             float& mean, float& rstd) {
  s = waveReduceSum(s);
  ss = waveReduceSum(ss);
  int wave = threadIdx.x >> 6;
  int lane = threadIdx.x & 63;
  if (lane == 0) { lds8[wave] = s; lds8[4 + wave] = ss; }
  __syncthreads();
  s  = lds8[0] + lds8[1] + lds8[2] + lds8[3];
  ss = lds8[4] + lds8[5] + lds8[6] + lds8[7];
  mean = s * (1.f / 512.f);
  float var = ss * (1.f / 512.f) - mean * mean;
  rstd = rsqrtf(var + 1e-5f);
}

// ---------------------------------------------------------------- setup
#define NW1 (512 * 576)
#define NW3 (512 * 512)
#define NW2 (1536 * 512)
#define NW4 (384 * 192)
#define NTAB (8192 * 32)

__global__ __launch_bounds__(256) void setup_kernel(
    const float* __restrict__ inst_w, const float* __restrict__ outp_w,
    const float* __restrict__ qkv_w, const float* __restrict__ reg_w,
    const float* __restrict__ reg_b, const float* __restrict__ br_w,
    const float* __restrict__ br_b, const float* __restrict__ mem_w,
    const float* __restrict__ mem_b, __hip_bfloat16* __restrict__ w16,
    float2* __restrict__ tab) {
  int i = blockIdx.x * 256 + threadIdx.x;
  if (i < NW1) {
    w16[i] = __float2bfloat16(inst_w[i]);
    return;
  }
  i -= NW1;
  if (i < NW3) {
    w16[NW1 + i] = __float2bfloat16(outp_w[i]);
    return;
  }
  i -= NW3;
  if (i < NW2) {
    // qkv row permutation: out row n' = which*512 + h*64 + d
    // from src row n = h*192 + d*3 + which -> qkvb planes [Q|K|V]
    int np = i / 512, k = i % 512;
    int which = np >> 9, rem = np & 511;
    int h = rem >> 6, d = rem & 63;
    int n = h * 192 + d * 3 + which;
    w16[NW1 + NW3 + i] = __float2bfloat16(qkv_w[n * 512 + k]);
    return;
  }
  i -= NW2;
  if (i < NW4) {
    // Wcat[384][192]: F cols [0]=1(bias),[1..64]=reg,[65..128]=mem,[129..160]=br
    int o = i / 192, c = i % 192;
    float v = 0.f;
    if (o < 128) {
      if (c == 0) v = reg_b[o];
      else if (c <= 64) v = reg_w[o * 64 + (c - 1)];
    } else if (o < 256) {
      int oo = o - 128;
      if (c == 0) v = br_b[oo];
      else if (c >= 129 && c <= 160) v = br_w[oo * 32 + (c - 129)];
    } else {
      int oo = o - 256;
      if (c == 0) v = mem_b[oo];
      else if (c >= 65 && c <= 128) v = mem_w[oo * 64 + (c - 65)];
    }
    w16[NW1 + NW3 + NW2 + i] = __float2bfloat16(v);
    return;
  }
  i -= NW4;
  if (i < NTAB) {
    int pos = i >> 5, p = i & 31;
    float inv = expf(-(float)p * 0.28782313662f);  // ln(10000)/32
    float sn, cs;
    sincosf((float)pos * inv, &sn, &cs);
    tab[i] = make_float2(cs, sn);
  }
}

// ---------------------------------------------------------------- prep
__global__ __launch_bounds__(256) void prep_kernel(
    const int* __restrict__ x, const float* __restrict__ emb,
    __hip_bfloat16* __restrict__ cat, __hip_bfloat16* __restrict__ Fb) {
  int gid = blockIdx.x * 256 + threadIdx.x;
  int t = gid / 48;
  int g = gid % 48;
  if (t >= M_TOK) return;
  const int* xr = x + (size_t)t * 161;
  union { __hip_bfloat16 h[8]; uint4 u; } pk;
  if (g < 24) {
    int c0 = g * 8;
    const float* e = emb + xr[0] * 192 + c0;
#pragma unroll
    for (int j = 0; j < 8; ++j) pk.h[j] = __float2bfloat16(siluf(e[j]));
    *(uint4*)&cat[(size_t)t * 576 + c0] = pk.u;
  } else {
    int c0 = (g - 24) * 8;
#pragma unroll
    for (int j = 0; j < 8; ++j) {
      int c = c0 + j;
      float v = (c == 0) ? 1.f : ((c <= 160) ? (float)xr[c] : 0.f);
      pk.h[j] = __float2bfloat16(v);
    }
    *(uint4*)&Fb[(size_t)t * 192 + c0] = pk.u;
  }
}

// ---------------------------------------------------------------- MFMA GEMM
// m97 structure + T1 L2-locality: 1-D grid, column-tile-fastest logical order,
// m204 bijective XCD-chunk swizzle so the N/128 column-tiles of one A-stripe
// run back-to-back on ONE XCD -> A stripe fetched once into that L2 and
// re-read at ~200cy instead of ~600-900cy from L3/HBM.
template <typename OT, bool SILU = false>
__global__ __launch_bounds__(256) void gemm_mfma(
    const ushort* __restrict__ A, const ushort* __restrict__ W,
    const float* __restrict__ bias, OT* __restrict__ C, int M, int N, int K,
    int ldc, int ntn) {
  __shared__ __align__(16) short As[2][128 * 32];
  __shared__ __align__(16) short Bs[2][128 * 32];
  const int tid = threadIdx.x;
  const int lane = tid & 63;
  const int wid = tid >> 6;
  const int wr = wid >> 1, wc = wid & 1;
  // --- T1: bijective XCD-chunk swizzle (m204), col-tile fastest
  const int nwg = gridDim.x;
  const int orig = blockIdx.x;
  const int qq = nwg >> 3, rr = nwg & 7;
  const int xcd = orig & 7;
  const int wgid = (xcd < rr ? xcd * (qq + 1) : rr * (qq + 1) + (xcd - rr) * qq)
                   + (orig >> 3);
  const int row0 = (wgid / ntn) * 128, col0 = (wgid % ntn) * 128;

  const int lrow = lane >> 2;       // 0..15
  const int lch = (lane & 3) * 8;   // 16B chunk (linear; b128 reads already at
  const int frow = lane & 15;       //  HW throughput per m134 - no swizzle win)
  const int fk = (lane >> 4) * 8;

  const ushort* Abase = A + (size_t)(row0 + 32 * wid + lrow) * K + lch;
  const ushort* Wbase = W + (size_t)(col0 + 32 * wid + lrow) * K + lch;
  short* Al[2] = {&As[0][32 * wid * 32], &As[1][32 * wid * 32]};
  short* Bl[2] = {&Bs[0][32 * wid * 32], &Bs[1][32 * wid * 32]};

  f32x4 acc[4][4];
  const f32x4 z = {0.f, 0.f, 0.f, 0.f};
#pragma unroll
  for (int i = 0; i < 4; ++i)
#pragma unroll
    for (int j = 0; j < 4; ++j) acc[i][j] = z;

  const int T = K >> 5;
  gload16(Abase, Al[0]);
  gload16(Abase + (size_t)16 * K, Al[0] + 512);
  gload16(Wbase, Bl[0]);
  gload16(Wbase + (size_t)16 * K, Bl[0] + 512);

  for (int t = 0; t < T; ++t) {
    __syncthreads();
    if (t + 1 < T) {
      const ushort* An = Abase + (t + 1) * 32;
      const ushort* Wn = Wbase + (t + 1) * 32;
      short* Ad = Al[(t + 1) & 1];
      short* Bd = Bl[(t + 1) & 1];
      gload16(An, Ad);
      gload16(An + (size_t)16 * K, Ad + 512);
      gload16(Wn, Bd);
      gload16(Wn + (size_t)16 * K, Bd + 512);
    }
    const short* Ab = As[t & 1];
    const short* Bb = Bs[t & 1];
    bf16x8 af[4], bfr[4];
#pragma unroll
    for (int i = 0; i < 4; ++i)
      af[i] = *(const bf16x8*)&Ab[(wr * 64 + i * 16 + frow) * 32 + fk];
#pragma unroll
    for (int j = 0; j < 4; ++j)
      bfr[j] = *(const bf16x8*)&Bb[(wc * 64 + j * 16 + frow) * 32 + fk];
#pragma unroll
    for (int i = 0; i < 4; ++i)
#pragma unroll
      for (int j = 0; j < 4; ++j)
        acc[i][j] = __builtin_amdgcn_mfma_f32_16x16x32_bf16(af[i], bfr[j],
                                                            acc[i][j], 0, 0, 0);
  }

  const int crow0 = row0 + wr * 64 + (lane >> 4) * 4;
  const int ccol0 = col0 + wc * 64 + (lane & 15);
#pragma unroll
  for (int j = 0; j < 4; ++j) {
    const int col = ccol0 + j * 16;
    const float bv = bias ? bias[col] : 0.f;
#pragma unroll
    for (int i = 0; i < 4; ++i) {
#pragma unroll
      for (int r = 0; r < 4; ++r) {
        float v = acc[i][j][r] + bv;
        if constexpr (SILU) v = siluf(v);
        size_t off = (size_t)(crow0 + i * 16 + r) * ldc + col;
        if constexpr (std::is_same<OT, float>::value) {
          C[off] = v;
        } else {
          C[off] = __float2bfloat16(v);
        }
      }
    }
  }
}

// ---------------------------------------------------------------- kernel 3
__global__ __launch_bounds__(256) void ln_silu_kernel(
    __hip_bfloat16* __restrict__ buf, const float* __restrict__ g,
    const float* __restrict__ b) {
  __shared__ float lds8[8];
  const int t = blockIdx.x;
  const int tid = threadIdx.x;
  uint u = *(const uint*)&buf[(size_t)t * 512 + tid * 2];
  float x0 = bf2f(u & 0xffffu);
  float x1 = bf2f(u >> 16);
  float mean, rstd;
  blockLNStats(x0 + x1, x0 * x0 + x1 * x1, lds8, mean, rstd);
  float y0 = siluf((x0 - mean) * rstd * g[2 * tid] + b[2 * tid]);
  float y1 = siluf((x1 - mean) * rstd * g[2 * tid + 1] + b[2 * tid + 1]);
  union { __hip_bfloat16 h[2]; uint u; } pk;
  pk.h[0] = __float2bfloat16(y0);
  pk.h[1] = __float2bfloat16(y1);
  *(uint*)&buf[(size_t)t * 512 + tid * 2] = pk.u;
}

// ---------------------------------------------------------------- attn (MFMA)
// One block per (b,h,window-block): 4 waves x 32 queries. KV chunks of 64 keys,
// double-buffered with async-split staging; one barrier per chunk.
__global__ __launch_bounds__(256) void attn_kernel(
    const __hip_bfloat16* __restrict__ qkv, const float2* __restrict__ tab,
    __hip_bfloat16* __restrict__ o_out) {
  __shared__ __align__(16) short Kc[2][64 * 72];   // [key 64][dim 64 pad 72]
  __shared__ __align__(16) short Vt[2][64 * 72];   // [dim 64][key 64 pad 72]
  __shared__ __align__(16) float rbuf[4][32];
  const int blk = blockIdx.x;
  const int nbIdx = blk & 63;
  const int h = (blk >> 6) & 7;
  const int b = blk >> 9;
  const int tid = threadIdx.x;
  const int w = tid >> 6;
  const int lane = tid & 63;
  const int lq = lane & 31;
  const int hi = lane >> 5;
  const size_t seqBase = (size_t)b * LSEQ;
  const int qi = w * 32 + lq;
  const int qtok = nbIdx * 128 + qi;

  const ushort* qkvu = (const ushort*)qkv;

  // ---- load Q fragments (B-operand), rope + 1/8 scale folded in
  bf16x8 qf[4];
  {
    const ushort* Qrow = qkvu + (seqBase + qtok) * 1536 + h * 64;
#pragma unroll
    for (int s = 0; s < 4; ++s) {
      int dim0 = 16 * s + 8 * hi;
      bf16x8 qv = *(const bf16x8*)(Qrow + dim0);
      const float4* tp = (const float4*)(tab + qtok * 32 + dim0 / 2);
      float4 t01 = tp[0], t23 = tp[1];
      float cs[4] = {t01.x, t01.z, t23.x, t23.z};
      float sn[4] = {t01.y, t01.w, t23.y, t23.w};
      union { uint u[4]; bf16x8 v; } pk;
#pragma unroll
      for (int j = 0; j < 4; ++j) {
        float x1 = bf2f((ushort)qv[2 * j]);
        float x2 = bf2f((ushort)qv[2 * j + 1]);
        float r0 = (x1 * cs[j] - x2 * sn[j]) * 0.125f;
        float r1 = (x1 * sn[j] + x2 * cs[j]) * 0.125f;
        pk.u[j] = cvtpk_bf16(r0, r1);
      }
      qf[s] = pk.v;
    }
  }

  const f32x16 Z16 = {0.f};
  f32x16 oa0 = Z16, oa1 = Z16;
  float m0 = -3.0e38f, l = 0.f;

  const int cstart = (nbIdx == 0) ? 2 : 0;
  const int cw0 = (w >= 2) ? 1 : 0;
  const int cw1 = (w >= 2) ? 3 : 2;

  const int skk = tid >> 2;         // key row this thread stages
  const int sd0 = (tid & 3) * 16;   // dim group [sd0, sd0+16)

  bf16x8 kreg0, kreg1, vreg0, vreg1;  // in-flight staging registers

  auto issue = [&](int c) {
    int ktok = (nbIdx - 1) * 128 + c * 64 + skk;
    const ushort* base = qkvu + (seqBase + ktok) * 1536 + h * 64 + sd0;
    kreg0 = *(const bf16x8*)(base + 512);
    kreg1 = *(const bf16x8*)(base + 512 + 8);
    vreg0 = *(const bf16x8*)(base + 1024);
    vreg1 = *(const bf16x8*)(base + 1024 + 8);
  };

  auto write_chunk = [&](int c) {
    short* Kb = Kc[c & 1];
    short* Vb = Vt[c & 1];
    int ktok = (nbIdx - 1) * 128 + c * 64 + skk;
    const float4* tp = (const float4*)(tab + ktok * 32 + (sd0 >> 1));
    float4 t0 = tp[0], t1 = tp[1], t2 = tp[2], t3 = tp[3];
    const int swk = ((skk >> 3) & 3) << 5;
    {
      float cs[4] = {t0.x, t0.z, t1.x, t1.z};
      float sn[4] = {t0.y, t0.w, t1.y, t1.w};
      union { uint u[4]; bf16x8 v; } pk;
#pragma unroll
      for (int j = 0; j < 4; ++j) {
        float x1 = bf2f((ushort)kreg0[2 * j]);
        float x2 = bf2f((ushort)kreg0[2 * j + 1]);
        pk.u[j] = cvtpk_bf16(x1 * cs[j] - x2 * sn[j], x1 * sn[j] + x2 * cs[j]);
      }
      *(bf16x8*)((char*)Kb + skk * 144 + ((sd0 * 2) ^ swk)) = pk.v;
    }
    {
      float cs[4] = {t2.x, t2.z, t3.x, t3.z};
      float sn[4] = {t2.y, t2.w, t3.y, t3.w};
      union { uint u[4]; bf16x8 v; } pk;
#pragma unroll
      for (int j = 0; j < 4; ++j) {
        float x1 = bf2f((ushort)kreg1[2 * j]);
        float x2 = bf2f((ushort)kreg1[2 * j + 1]);
        pk.u[j] = cvtpk_bf16(x1 * cs[j] - x2 * sn[j], x1 * sn[j] + x2 * cs[j]);
      }
      *(bf16x8*)((char*)Kb + skk * 144 + (((sd0 + 8) * 2) ^ swk)) = pk.v;
    }
#pragma unroll
    for (int j = 0; j < 8; ++j) {
      int d0 = sd0 + j;
      *(short*)((char*)Vb + d0 * 144 +
                ((skk * 2) ^ (((d0 >> 4) & 3) << 5))) = vreg0[j];
      int d1 = sd0 + 8 + j;
      *(short*)((char*)Vb + d1 * 144 +
                ((skk * 2) ^ (((d1 >> 4) & 3) << 5))) = vreg1[j];
    }
  };

  // prologue: stage chunk cstart
  issue(cstart);
  write_chunk(cstart);

  for (int c = cstart; c < 4; ++c) {
    if (c < 3) issue(c + 1);     // loads in flight during compute
    __syncthreads();             // buf[c&1] visible to all waves
    if (c >= cw0 && c <= cw1) {
      const char* Kb = (const char*)Kc[c & 1];
      const char* Vb = (const char*)Vt[c & 1];

      bf16x8 ka[2][4];
#pragma unroll
      for (int t2 = 0; t2 < 2; ++t2)
#pragma unroll
        for (int s = 0; s < 4; ++s) {
          int kk = 32 * t2 + lq;
          int byteoff =
              kk * 144 + ((32 * s + 16 * hi) ^ (((kk >> 3) & 3) << 5));
          ka[t2][s] = *(const bf16x8*)(Kb + byteoff);
        }
      f32x16 st0 = Z16, st1 = Z16;
#pragma unroll
      for (int s = 0; s < 4; ++s) {
        st0 = __builtin_amdgcn_mfma_f32_32x32x16_bf16(ka[0][s], qf[s], st0, 0, 0, 0);
        st1 = __builtin_amdgcn_mfma_f32_32x32x16_bf16(ka[1][s], qf[s], st1, 0, 0, 0);
      }

      float p2[2][16];
      float pmax = -3.0e38f;
#pragma unroll
      for (int t2 = 0; t2 < 2; ++t2)
#pragma unroll
        for (int r = 0; r < 16; ++r) {
          int key = c * 64 + 32 * t2 + (r & 3) + 8 * (r >> 2) + 4 * hi;
          float sv = (t2 ? st1[r] : st0[r]);
          bool act = (key >= qi) && (key <= qi + 128);
          sv = act ? sv : -1.0e30f;
          p2[t2][r] = sv;
          pmax = fmaxf(pmax, sv);
        }
      pmax = fmaxf(pmax, __shfl_xor(pmax, 32));
      if (__any(pmax > m0 + 8.f)) {
        float nm = fmaxf(m0, pmax);
        float rr2 = __expf(m0 - nm);
        l *= rr2;
        m0 = nm;
        rbuf[w][lq] = rr2;
        asm volatile("s_waitcnt lgkmcnt(0)" ::: "memory");
#pragma unroll
        for (int a = 0; a < 4; ++a) {
          f32x4 r4 = *(const f32x4*)&rbuf[w][8 * a + 4 * hi];
#pragma unroll
          for (int j = 0; j < 4; ++j) {
            oa0[4 * a + j] *= r4[j];
            oa1[4 * a + j] *= r4[j];
          }
        }
      }
      float lsum = 0.f;
#pragma unroll
      for (int t2 = 0; t2 < 2; ++t2)
#pragma unroll
        for (int r = 0; r < 16; ++r) {
          float p = __expf(p2[t2][r] - m0);
          p2[t2][r] = p;
          lsum += p;
        }
      l += lsum + __shfl_xor(lsum, 32);

      union { uint u[4]; bf16x8 v; } pa[4];
#pragma unroll
      for (int t2 = 0; t2 < 2; ++t2)
#pragma unroll
        for (int sl = 0; sl < 2; ++sl) {
          const float* pp = &p2[t2][8 * sl];
          uint a0 = cvtpk_bf16(pp[0], pp[1]);
          uint a1 = cvtpk_bf16(pp[2], pp[3]);
          uint b0 = cvtpk_bf16(pp[4], pp[5]);
          uint b1 = cvtpk_bf16(pp[6], pp[7]);
          perm32swap(a0, b0);
          perm32swap(a1, b1);
          int slot = 2 * t2 + sl;
          pa[slot].u[0] = a0; pa[slot].u[1] = a1;
          pa[slot].u[2] = b0; pa[slot].u[3] = b1;
        }

#pragma unroll
      for (int slot = 0; slot < 4; ++slot) {
        {
          int d = lq;
          int byteoff =
              d * 144 + ((32 * slot + 16 * hi) ^ (((d >> 4) & 3) << 5));
          bf16x8 vb = *(const bf16x8*)(Vb + byteoff);
          oa0 = __builtin_amdgcn_mfma_f32_32x32x16_bf16(pa[slot].v, vb, oa0, 0, 0, 0);
        }
        {
          int d = 32 + lq;
          int byteoff =
              d * 144 + ((32 * slot + 16 * hi) ^ (((d >> 4) & 3) << 5));
          bf16x8 vb = *(const bf16x8*)(Vb + byteoff);
          oa1 = __builtin_amdgcn_mfma_f32_32x32x16_bf16(pa[slot].v, vb, oa1, 0, 0, 0);
        }
      }
    }
    if (c < 3) write_chunk(c + 1);  // regs -> other buffer (post-compute)
  }

  rbuf[w][lq] = 1.f / l;
  asm volatile("s_waitcnt lgkmcnt(0)" ::: "memory");
  const int q0 = nbIdx * 128 + 32 * w;
#pragma unroll
  for (int a = 0; a < 4; ++a) {
    f32x4 r4 = *(const f32x4*)&rbuf[w][8 * a + 4 * hi];
#pragma unroll
    for (int j = 0; j < 4; ++j) {
      int tok = q0 + 8 * a + 4 * hi + j;
      __hip_bfloat16* orow = o_out + (seqBase + tok) * 512 + h * 64;
      orow[lq] = __float2bfloat16(oa0[4 * a + j] * r4[j]);
      orow[32 + lq] = __float2bfloat16(oa1[4 * a + j] * r4[j]);
    }
  }
}

// ---------------------------------------------------------------- kernel 5
// LN2 + silu + head(9) + activations, bf16 input
__global__ __launch_bounds__(256) void head_kernel(
    const __hip_bfloat16* __restrict__ pre, const float* __restrict__ g,
    const float* __restrict__ b, const float* __restrict__ hw,
    const float* __restrict__ hb, float* __restrict__ out) {
  __shared__ float lds8[8];
  __shared__ float ys[512];
  __shared__ float raw[9];
  const int t = blockIdx.x;
  const int tid = threadIdx.x;
  uint u = *(const uint*)&pre[(size_t)t * 512 + tid * 2];
  float x0 = bf2f(u & 0xffffu);
  float x1 = bf2f(u >> 16);
  float mean, rstd;
  blockLNStats(x0 + x1, x0 * x0 + x1 * x1, lds8, mean, rstd);
  float y0 = (x0 - mean) * rstd * g[2 * tid] + b[2 * tid];
  float y1 = (x1 - mean) * rstd * g[2 * tid + 1] + b[2 * tid + 1];
  ys[2 * tid] = siluf(y0);
  ys[2 * tid + 1] = siluf(y1);
  __syncthreads();
  const int wave = tid >> 6;
  const int lane = tid & 63;
  for (int r = wave; r < 9; r += 4) {
    float p = 0.f;
#pragma unroll
    for (int i = 0; i < 8; ++i)
      p = fmaf(ys[lane + i * 64], hw[r * 512 + lane + i * 64], p);
    p = waveReduceSum(p);
    if (lane == 0) raw[r] = p + hb[r];
  }
  __syncthreads();
  if (tid == 0) {
    float* op = out + (size_t)t * 9;
    op[0] = fmaxf(raw[0], 0.f) + log1pf(expf(-fabsf(raw[0])));
    op[1] = fmaxf(raw[1], 0.f) + log1pf(expf(-fabsf(raw[1])));
    op[2] = 1.f / (1.f + expf(-raw[2]));
    op[3] = 1.f / (1.f + expf(-raw[3]));
    op[4] = 1.f / (1.f + expf(-raw[4]));
    float mx = fmaxf(fmaxf(raw[5], raw[6]), fmaxf(raw[7], raw[8]));
    float e0 = expf(raw[5] - mx), e1 = expf(raw[6] - mx);
    float e2 = expf(raw[7] - mx), e3 = expf(raw[8] - mx);
    float inv = 1.f / (e0 + e1 + e2 + e3);
    op[5] = e0 * inv; op[6] = e1 * inv; op[7] = e2 * inv; op[8] = e3 * inv;
  }
}

// ---------------------------------------------------------------- launch
// Workspace layout (~133 MB peak):
//   w16: bf16 [inst | outp | qkv(permuted) | wcat] ; rope table (2MB)
//   R1 (96MB): {cat M*576 | Fb M*192} -> qkvb M*1536 -> preb bf16 M*512
//   R2 (32MB): hb bf16 [in-place LN] -> att bf16
extern "C" void kernel_launch(void* const* d_in, const int* in_sizes, int n_in,
                              void* d_out, int out_size, void* d_ws,
                              size_t ws_size, hipStream_t stream) {
  const float* emb = (const float*)d_in[0];
  const float* reg_w = (const float*)d_in[1];
  const float* reg_b = (const float*)d_in[2];
  const float* br_w = (const float*)d_in[3];
  const float* br_b = (const float*)d_in[4];
  const float* mem_w = (const float*)d_in[5];
  const float* mem_b = (const float*)d_in[6];
  const float* inst_w = (const float*)d_in[7];
  const float* inst_b = (const float*)d_in[8];
  const float* ln1_g = (const float*)d_in[9];
  const float* ln1_b = (const float*)d_in[10];
  const float* qkv_w = (const float*)d_in[11];
  const float* outp_w = (const float*)d_in[12];
  const float* outp_b = (const float*)d_in[13];
  const float* ln2_g = (const float*)d_in[14];
  const float* ln2_b = (const float*)d_in[15];
  const float* head_w = (const float*)d_in[16];
  const float* head_b = (const float*)d_in[17];
  const int* x = (const int*)d_in[18];
  float* out = (float*)d_out;

  const int M = M_TOK;
  char* wsb = (char*)d_ws;
  __hip_bfloat16* w16 = (__hip_bfloat16*)wsb;
  __hip_bfloat16* w1 = w16;                        // inst
  __hip_bfloat16* w3 = w16 + NW1;                  // outp
  __hip_bfloat16* w2 = w16 + NW1 + NW3;            // qkv (permuted)
  __hip_bfloat16* wcat = w16 + NW1 + NW3 + NW2;    // feature proj
  size_t woff = ((size_t)(NW1 + NW2 + NW3 + NW4) * 2 + 255) & ~(size_t)255;
  float2* tab = (float2*)(wsb + woff);             // 2MB
  size_t toff = woff + (size_t)NTAB * 8;
  char* r1 = wsb + toff;                           // 96 MB region
  char* r2 = r1 + (size_t)M * 1536 * 2;            // 32 MB region
  __hip_bfloat16* cat = (__hip_bfloat16*)r1;       // M*576
  __hip_bfloat16* Fb = (__hip_bfloat16*)(r1 + (size_t)M * 576 * 2);  // M*192
  __hip_bfloat16* qkvb = (__hip_bfloat16*)r1;      // M*1536
  __hip_bfloat16* preb = (__hip_bfloat16*)r1;      // M*512 bf16
  __hip_bfloat16* hb = (__hip_bfloat16*)r2;        // M*512
  __hip_bfloat16* att = (__hip_bfloat16*)r2;       // M*512

  // 0. all weight conversion + rope table (one kernel)
  const int setup_tot = NW1 + NW3 + NW2 + NW4 + NTAB;
  setup_kernel<<<(setup_tot + 255) / 256, 256, 0, stream>>>(
      inst_w, outp_w, qkv_w, reg_w, reg_b, br_w, br_b, mem_w, mem_b, w16, tab);
  // 1. prep: cat[:,0:192] = silu(emb[tid]) ; Fb = [1, feats, 0]
  prep_kernel<<<(M * 48) / 256, 256, 0, stream>>>(x, emb, cat, Fb);
  // 1b. feature proj: cat[:,192:576] = silu(Fb @ wcat^T)
  gemm_mfma<__hip_bfloat16, true><<<(M / 128) * 3, 256, 0, stream>>>(
      (const ushort*)Fb, (const ushort*)wcat, nullptr, cat + 192, M, 384, 192,
      576, 3);
  // 2. inst proj: cat @ w1^T + b -> hb (bf16)
  gemm_mfma<__hip_bfloat16><<<(M / 128) * 4, 256, 0, stream>>>(
      (const ushort*)cat, (const ushort*)w1, inst_b, hb, M, 512, 576, 512, 4);
  // 3. LN1 + silu in place (bf16)
  ln_silu_kernel<<<M, 256, 0, stream>>>(hb, ln1_g, ln1_b);
  // 4. qkv proj (permuted cols): hb @ w2^T -> qkvb planes [Q|K|V]
  gemm_mfma<__hip_bfloat16><<<(M / 128) * 12, 256, 0, stream>>>(
      (const ushort*)hb, (const ushort*)w2, nullptr, qkvb, M, 1536, 512, 1536,
      12);
  // 5. attention (MFMA) -> att (bf16, [M][512] heads concatenated)
  attn_kernel<<<BATCH * 8 * 64, 256, 0, stream>>>(qkvb, tab, att);
  // 6. out proj: att @ w3^T + b -> preb (bf16)
  gemm_mfma<__hip_bfloat16><<<(M / 128) * 4, 256, 0, stream>>>(
      (const ushort*)att, (const ushort*)w3, outp_b, preb, M, 512, 512, 512,
      4);
  // 7. LN2 + silu + head + activations -> out
  head_kernel<<<M, 256, 0, stream>>>(preb, ln2_g, ln2_b, head_w, head_b, out);
}

// Round 12
// 255.927 us; speedup vs baseline: 8.8277x; 1.2396x over previous
//
#include <hip/hip_runtime.h>
#include <hip/hip_bf16.h>
#include <math.h>
#include <type_traits>

#define LSEQ 8192
#define BATCH 4
#define M_TOK (BATCH * LSEQ)

typedef __attribute__((ext_vector_type(8))) short bf16x8;   // 8 bf16 = 4 VGPR
typedef __attribute__((ext_vector_type(4))) float f32x4;
typedef __attribute__((ext_vector_type(16))) float f32x16;

// ---------------------------------------------------------------- helpers
__device__ __forceinline__ float siluf(float x) {
  return x / (1.f + __expf(-x));
}

__device__ __forceinline__ float bf2f(uint u16) {
  union { float f; uint u; } c;
  c.u = u16 << 16;
  return c.f;
}

__device__ __forceinline__ uint cvtpk_bf16(float lo, float hi) {
  uint r;
  asm volatile("v_cvt_pk_bf16_f32 %0, %1, %2" : "=v"(r) : "v"(lo), "v"(hi));
  return r;
}

// swaps hi 32 lanes of a with lo 32 lanes of b
__device__ __forceinline__ void perm32swap(uint& a, uint& b) {
  asm volatile("v_permlane32_swap_b32 %0, %1" : "+v"(a), "+v"(b));
}

// async global->LDS, 16B per lane; LDS dest = wave-uniform base + lane*16
__device__ __forceinline__ void gload16(const ushort* g, short* l) {
  __builtin_amdgcn_global_load_lds(
      (const __attribute__((address_space(1))) void*)g,
      (__attribute__((address_space(3))) void*)l, 16, 0, 0);
}

// ---------------------------------------------------------------- setup
#define NW1 (512 * 576)
#define NW3 (512 * 512)
#define NW2 (1536 * 512)
#define NW4 (384 * 192)
#define NTAB (8192 * 32)

__global__ __launch_bounds__(256) void setup_kernel(
    const float* __restrict__ inst_w, const float* __restrict__ outp_w,
    const float* __restrict__ qkv_w, const float* __restrict__ reg_w,
    const float* __restrict__ reg_b, const float* __restrict__ br_w,
    const float* __restrict__ br_b, const float* __restrict__ mem_w,
    const float* __restrict__ mem_b, __hip_bfloat16* __restrict__ w16,
    float2* __restrict__ tab) {
  int i = blockIdx.x * 256 + threadIdx.x;
  if (i < NW1) {
    w16[i] = __float2bfloat16(inst_w[i]);
    return;
  }
  i -= NW1;
  if (i < NW3) {
    w16[NW1 + i] = __float2bfloat16(outp_w[i]);
    return;
  }
  i -= NW3;
  if (i < NW2) {
    // qkv row permutation: out row n' = which*512 + h*64 + d
    // from src row n = h*192 + d*3 + which -> qkvb planes [Q|K|V]
    int np = i / 512, k = i % 512;
    int which = np >> 9, rem = np & 511;
    int h = rem >> 6, d = rem & 63;
    int n = h * 192 + d * 3 + which;
    w16[NW1 + NW3 + i] = __float2bfloat16(qkv_w[n * 512 + k]);
    return;
  }
  i -= NW2;
  if (i < NW4) {
    // Wcat[384][192]: F cols [0]=1(bias),[1..64]=reg,[65..128]=mem,[129..160]=br
    int o = i / 192, c = i % 192;
    float v = 0.f;
    if (o < 128) {
      if (c == 0) v = reg_b[o];
      else if (c <= 64) v = reg_w[o * 64 + (c - 1)];
    } else if (o < 256) {
      int oo = o - 128;
      if (c == 0) v = br_b[oo];
      else if (c >= 129 && c <= 160) v = br_w[oo * 32 + (c - 129)];
    } else {
      int oo = o - 256;
      if (c == 0) v = mem_b[oo];
      else if (c >= 65 && c <= 128) v = mem_w[oo * 64 + (c - 65)];
    }
    w16[NW1 + NW3 + NW2 + i] = __float2bfloat16(v);
    return;
  }
  i -= NW4;
  if (i < NTAB) {
    int pos = i >> 5, p = i & 31;
    float inv = expf(-(float)p * 0.28782313662f);  // ln(10000)/32
    float sn, cs;
    sincosf((float)pos * inv, &sn, &cs);
    tab[i] = make_float2(cs, sn);
  }
}

// ---------------------------------------------------------------- prep
__global__ __launch_bounds__(256) void prep_kernel(
    const int* __restrict__ x, const float* __restrict__ emb,
    __hip_bfloat16* __restrict__ cat, __hip_bfloat16* __restrict__ Fb) {
  int gid = blockIdx.x * 256 + threadIdx.x;
  int t = gid / 48;
  int g = gid % 48;
  if (t >= M_TOK) return;
  const int* xr = x + (size_t)t * 161;
  union { __hip_bfloat16 h[8]; uint4 u; } pk;
  if (g < 24) {
    int c0 = g * 8;
    const float* e = emb + xr[0] * 192 + c0;
#pragma unroll
    for (int j = 0; j < 8; ++j) pk.h[j] = __float2bfloat16(siluf(e[j]));
    *(uint4*)&cat[(size_t)t * 576 + c0] = pk.u;
  } else {
    int c0 = (g - 24) * 8;
#pragma unroll
    for (int j = 0; j < 8; ++j) {
      int c = c0 + j;
      float v = (c == 0) ? 1.f : ((c <= 160) ? (float)xr[c] : 0.f);
      pk.h[j] = __float2bfloat16(v);
    }
    *(uint4*)&Fb[(size_t)t * 192 + c0] = pk.u;
  }
}

// ---------------------------------------------------------------- MFMA GEMM
// m97 structure + T1 XCD swizzle (col-tile fastest). Used for feat + qkv.
template <typename OT, bool SILU = false>
__global__ __launch_bounds__(256) void gemm_mfma(
    const ushort* __restrict__ A, const ushort* __restrict__ W,
    const float* __restrict__ bias, OT* __restrict__ C, int M, int N, int K,
    int ldc, int ntn) {
  __shared__ __align__(16) short As[2][128 * 32];
  __shared__ __align__(16) short Bs[2][128 * 32];
  const int tid = threadIdx.x;
  const int lane = tid & 63;
  const int wid = tid >> 6;
  const int wr = wid >> 1, wc = wid & 1;
  const int nwg = gridDim.x;
  const int orig = blockIdx.x;
  const int qq = nwg >> 3, rr = nwg & 7;
  const int xcd = orig & 7;
  const int wgid = (xcd < rr ? xcd * (qq + 1) : rr * (qq + 1) + (xcd - rr) * qq)
                   + (orig >> 3);
  const int row0 = (wgid / ntn) * 128, col0 = (wgid % ntn) * 128;

  const int lrow = lane >> 2;       // 0..15
  const int lch = (lane & 3) * 8;
  const int frow = lane & 15;
  const int fk = (lane >> 4) * 8;

  const ushort* Abase = A + (size_t)(row0 + 32 * wid + lrow) * K + lch;
  const ushort* Wbase = W + (size_t)(col0 + 32 * wid + lrow) * K + lch;
  short* Al[2] = {&As[0][32 * wid * 32], &As[1][32 * wid * 32]};
  short* Bl[2] = {&Bs[0][32 * wid * 32], &Bs[1][32 * wid * 32]};

  f32x4 acc[4][4];
  const f32x4 z = {0.f, 0.f, 0.f, 0.f};
#pragma unroll
  for (int i = 0; i < 4; ++i)
#pragma unroll
    for (int j = 0; j < 4; ++j) acc[i][j] = z;

  const int T = K >> 5;
  gload16(Abase, Al[0]);
  gload16(Abase + (size_t)16 * K, Al[0] + 512);
  gload16(Wbase, Bl[0]);
  gload16(Wbase + (size_t)16 * K, Bl[0] + 512);

  for (int t = 0; t < T; ++t) {
    __syncthreads();
    if (t + 1 < T) {
      const ushort* An = Abase + (t + 1) * 32;
      const ushort* Wn = Wbase + (t + 1) * 32;
      short* Ad = Al[(t + 1) & 1];
      short* Bd = Bl[(t + 1) & 1];
      gload16(An, Ad);
      gload16(An + (size_t)16 * K, Ad + 512);
      gload16(Wn, Bd);
      gload16(Wn + (size_t)16 * K, Bd + 512);
    }
    const short* Ab = As[t & 1];
    const short* Bb = Bs[t & 1];
    bf16x8 af[4], bfr[4];
#pragma unroll
    for (int i = 0; i < 4; ++i)
      af[i] = *(const bf16x8*)&Ab[(wr * 64 + i * 16 + frow) * 32 + fk];
#pragma unroll
    for (int j = 0; j < 4; ++j)
      bfr[j] = *(const bf16x8*)&Bb[(wc * 64 + j * 16 + frow) * 32 + fk];
#pragma unroll
    for (int i = 0; i < 4; ++i)
#pragma unroll
      for (int j = 0; j < 4; ++j)
        acc[i][j] = __builtin_amdgcn_mfma_f32_16x16x32_bf16(af[i], bfr[j],
                                                            acc[i][j], 0, 0, 0);
  }

  const int crow0 = row0 + wr * 64 + (lane >> 4) * 4;
  const int ccol0 = col0 + wc * 64 + (lane & 15);
#pragma unroll
  for (int j = 0; j < 4; ++j) {
    const int col = ccol0 + j * 16;
    const float bv = bias ? bias[col] : 0.f;
#pragma unroll
    for (int i = 0; i < 4; ++i) {
#pragma unroll
      for (int r = 0; r < 4; ++r) {
        float v = acc[i][j][r] + bv;
        if constexpr (SILU) v = siluf(v);
        size_t off = (size_t)(crow0 + i * 16 + r) * ldc + col;
        if constexpr (std::is_same<OT, float>::value) {
          C[off] = v;
        } else {
          C[off] = __float2bfloat16(v);
        }
      }
    }
  }
}

// ---------------------------------------------------------------- fused GEMM
// BM=128 x full N=512 per block, 8 waves (512 thr) each 64x128 (acc 4x8).
// Epilogue: bias + LayerNorm(512) + silu computed from fp32 accs in-register
// (shfl over 16-lane col groups + LDS across the 4 col-waves).
// HEAD=false: write bf16 C. HEAD=true: + 9-dot head + activations -> out.
template <bool HEAD>
__global__ __launch_bounds__(512, 2) void gemm_ln_fused(
    const ushort* __restrict__ A, const ushort* __restrict__ W,
    const float* __restrict__ bias, const float* __restrict__ g,
    const float* __restrict__ b2, const float* __restrict__ hw,
    const float* __restrict__ hb, __hip_bfloat16* __restrict__ C,
    float* __restrict__ out, int K) {
  __shared__ __align__(16) short As[2][128 * 32];
  __shared__ __align__(16) short Bs[2][512 * 32];
  __shared__ float rs[4][128], rss[4][128];
  __shared__ float o9[4][128][9];
  const int tid = threadIdx.x;
  const int lane = tid & 63;
  const int wid = tid >> 6;            // 0..7
  const int wr = wid & 1, wc = wid >> 1;
  const int row0 = blockIdx.x * 128;
  const int frow = lane & 15;
  const int fk = (lane >> 4) * 8;

  // staging: wave stages 16 A-rows (1 gload) + 64 B-rows (4 gloads)
  const ushort* Abase =
      A + (size_t)(row0 + 16 * wid + (lane >> 2)) * K + (lane & 3) * 8;
  const ushort* Wbase = W + (size_t)(64 * wid + (lane >> 2)) * K + (lane & 3) * 8;
  short* Adst[2] = {&As[0][16 * wid * 32], &As[1][16 * wid * 32]};
  short* Bdst[2] = {&Bs[0][64 * wid * 32], &Bs[1][64 * wid * 32]};

  f32x4 acc[4][8];
  const f32x4 z = {0.f, 0.f, 0.f, 0.f};
#pragma unroll
  for (int i = 0; i < 4; ++i)
#pragma unroll
    for (int j = 0; j < 8; ++j) acc[i][j] = z;

  const int T = K >> 5;
  gload16(Abase, Adst[0]);
#pragma unroll
  for (int q = 0; q < 4; ++q)
    gload16(Wbase + (size_t)q * 16 * K, Bdst[0] + q * 16 * 32);

  for (int t = 0; t < T; ++t) {
    __syncthreads();
    if (t + 1 < T) {
      const ushort* An = Abase + (t + 1) * 32;
      const ushort* Wn = Wbase + (t + 1) * 32;
      short* Ad = Adst[(t + 1) & 1];
      short* Bd = Bdst[(t + 1) & 1];
      gload16(An, Ad);
#pragma unroll
      for (int q = 0; q < 4; ++q)
        gload16(Wn + (size_t)q * 16 * K, Bd + q * 16 * 32);
    }
    const short* Ab = As[t & 1];
    const short* Bb = Bs[t & 1];
    bf16x8 af[4], bfr[8];
#pragma unroll
    for (int i = 0; i < 4; ++i)
      af[i] = *(const bf16x8*)&Ab[(wr * 64 + i * 16 + frow) * 32 + fk];
#pragma unroll
    for (int j = 0; j < 8; ++j)
      bfr[j] = *(const bf16x8*)&Bb[(wc * 128 + j * 16 + frow) * 32 + fk];
#pragma unroll
    for (int i = 0; i < 4; ++i)
#pragma unroll
      for (int j = 0; j < 8; ++j)
        acc[i][j] = __builtin_amdgcn_mfma_f32_16x16x32_bf16(af[i], bfr[j],
                                                            acc[i][j], 0, 0, 0);
  }

  // ---- epilogue: bias + LN stats
  float bv[8], gv[8], b2v[8];
#pragma unroll
  for (int j = 0; j < 8; ++j) {
    int col = wc * 128 + (lane & 15) + j * 16;
    bv[j] = bias[col];
    gv[j] = g[col];
    b2v[j] = b2[col];
  }
  float sum_[4][4], sq_[4][4];
#pragma unroll
  for (int i = 0; i < 4; ++i)
#pragma unroll
    for (int r = 0; r < 4; ++r) { sum_[i][r] = 0.f; sq_[i][r] = 0.f; }
#pragma unroll
  for (int i = 0; i < 4; ++i)
#pragma unroll
    for (int j = 0; j < 8; ++j)
#pragma unroll
      for (int r = 0; r < 4; ++r) {
        float v = acc[i][j][r] + bv[j];
        acc[i][j][r] = v;
        sum_[i][r] += v;
        sq_[i][r] += v * v;
      }
#pragma unroll
  for (int i = 0; i < 4; ++i)
#pragma unroll
    for (int r = 0; r < 4; ++r)
#pragma unroll
      for (int off = 1; off < 16; off <<= 1) {
        sum_[i][r] += __shfl_xor(sum_[i][r], off, 64);
        sq_[i][r] += __shfl_xor(sq_[i][r], off, 64);
      }
  if ((lane & 15) == 0) {
#pragma unroll
    for (int i = 0; i < 4; ++i)
#pragma unroll
      for (int r = 0; r < 4; ++r) {
        int lr = wr * 64 + (lane >> 4) * 4 + i * 16 + r;
        rs[wc][lr] = sum_[i][r];
        rss[wc][lr] = sq_[i][r];
      }
  }
  __syncthreads();
  // ---- normalize + silu (overwrite acc with y)
#pragma unroll
  for (int i = 0; i < 4; ++i)
#pragma unroll
    for (int r = 0; r < 4; ++r) {
      int lr = wr * 64 + (lane >> 4) * 4 + i * 16 + r;
      float S = rs[0][lr] + rs[1][lr] + rs[2][lr] + rs[3][lr];
      float SS = rss[0][lr] + rss[1][lr] + rss[2][lr] + rss[3][lr];
      float mean = S * (1.f / 512.f);
      float var = SS * (1.f / 512.f) - mean * mean;
      float rstd = rsqrtf(var + 1e-5f);
#pragma unroll
      for (int j = 0; j < 8; ++j) {
        float y = (acc[i][j][r] - mean) * rstd * gv[j] + b2v[j];
        acc[i][j][r] = siluf(y);
      }
    }

  if constexpr (!HEAD) {
#pragma unroll
    for (int i = 0; i < 4; ++i)
#pragma unroll
      for (int r = 0; r < 4; ++r) {
        int grow = row0 + wr * 64 + (lane >> 4) * 4 + i * 16 + r;
#pragma unroll
        for (int j = 0; j < 8; ++j)
          C[(size_t)grow * 512 + wc * 128 + (lane & 15) + j * 16] =
              __float2bfloat16(acc[i][j][r]);
      }
  } else {
    // ---- head: out[row][0..8] = act(y @ hw^T + hb)
#pragma unroll
    for (int r9 = 0; r9 < 9; ++r9) {
      float hw8[8];
#pragma unroll
      for (int j = 0; j < 8; ++j)
        hw8[j] = hw[r9 * 512 + wc * 128 + (lane & 15) + j * 16];
      float pacc[4][4];
#pragma unroll
      for (int i = 0; i < 4; ++i)
#pragma unroll
        for (int r = 0; r < 4; ++r) {
          float p = 0.f;
#pragma unroll
          for (int j = 0; j < 8; ++j) p = fmaf(acc[i][j][r], hw8[j], p);
#pragma unroll
          for (int off = 1; off < 16; off <<= 1) p += __shfl_xor(p, off, 64);
          pacc[i][r] = p;
        }
      if ((lane & 15) == 0) {
#pragma unroll
        for (int i = 0; i < 4; ++i)
#pragma unroll
          for (int r = 0; r < 4; ++r) {
            int lr = wr * 64 + (lane >> 4) * 4 + i * 16 + r;
            o9[wc][lr][r9] = pacc[i][r];
          }
      }
    }
    __syncthreads();
    if (tid < 128) {
      float raw[9];
#pragma unroll
      for (int r9 = 0; r9 < 9; ++r9)
        raw[r9] = o9[0][tid][r9] + o9[1][tid][r9] + o9[2][tid][r9] +
                  o9[3][tid][r9] + hb[r9];
      float* op = out + (size_t)(row0 + tid) * 9;
      op[0] = fmaxf(raw[0], 0.f) + log1pf(expf(-fabsf(raw[0])));
      op[1] = fmaxf(raw[1], 0.f) + log1pf(expf(-fabsf(raw[1])));
      op[2] = 1.f / (1.f + expf(-raw[2]));
      op[3] = 1.f / (1.f + expf(-raw[3]));
      op[4] = 1.f / (1.f + expf(-raw[4]));
      float mx = fmaxf(fmaxf(raw[5], raw[6]), fmaxf(raw[7], raw[8]));
      float e0 = expf(raw[5] - mx), e1 = expf(raw[6] - mx);
      float e2 = expf(raw[7] - mx), e3 = expf(raw[8] - mx);
      float inv = 1.f / (e0 + e1 + e2 + e3);
      op[5] = e0 * inv; op[6] = e1 * inv; op[7] = e2 * inv; op[8] = e3 * inv;
    }
  }
}

// ---------------------------------------------------------------- attn (MFMA)
// One block per (b,h,window-block): 4 waves x 32 queries. KV chunks of 64 keys,
// double-buffered with async-split staging; one barrier per chunk.
__global__ __launch_bounds__(256) void attn_kernel(
    const __hip_bfloat16* __restrict__ qkv, const float2* __restrict__ tab,
    __hip_bfloat16* __restrict__ o_out) {
  __shared__ __align__(16) short Kc[2][64 * 72];   // [key 64][dim 64 pad 72]
  __shared__ __align__(16) short Vt[2][64 * 72];   // [dim 64][key 64 pad 72]
  __shared__ __align__(16) float rbuf[4][32];
  const int blk = blockIdx.x;
  const int nbIdx = blk & 63;
  const int h = (blk >> 6) & 7;
  const int b = blk >> 9;
  const int tid = threadIdx.x;
  const int w = tid >> 6;
  const int lane = tid & 63;
  const int lq = lane & 31;
  const int hi = lane >> 5;
  const size_t seqBase = (size_t)b * LSEQ;
  const int qi = w * 32 + lq;
  const int qtok = nbIdx * 128 + qi;

  const ushort* qkvu = (const ushort*)qkv;

  // ---- load Q fragments (B-operand), rope + 1/8 scale folded in
  bf16x8 qf[4];
  {
    const ushort* Qrow = qkvu + (seqBase + qtok) * 1536 + h * 64;
#pragma unroll
    for (int s = 0; s < 4; ++s) {
      int dim0 = 16 * s + 8 * hi;
      bf16x8 qv = *(const bf16x8*)(Qrow + dim0);
      const float4* tp = (const float4*)(tab + qtok * 32 + dim0 / 2);
      float4 t01 = tp[0], t23 = tp[1];
      float cs[4] = {t01.x, t01.z, t23.x, t23.z};
      float sn[4] = {t01.y, t01.w, t23.y, t23.w};
      union { uint u[4]; bf16x8 v; } pk;
#pragma unroll
      for (int j = 0; j < 4; ++j) {
        float x1 = bf2f((ushort)qv[2 * j]);
        float x2 = bf2f((ushort)qv[2 * j + 1]);
        float r0 = (x1 * cs[j] - x2 * sn[j]) * 0.125f;
        float r1 = (x1 * sn[j] + x2 * cs[j]) * 0.125f;
        pk.u[j] = cvtpk_bf16(r0, r1);
      }
      qf[s] = pk.v;
    }
  }

  const f32x16 Z16 = {0.f};
  f32x16 oa0 = Z16, oa1 = Z16;
  float m0 = -3.0e38f, l = 0.f;

  const int cstart = (nbIdx == 0) ? 2 : 0;
  const int cw0 = (w >= 2) ? 1 : 0;
  const int cw1 = (w >= 2) ? 3 : 2;

  const int skk = tid >> 2;         // key row this thread stages
  const int sd0 = (tid & 3) * 16;   // dim group [sd0, sd0+16)

  bf16x8 kreg0, kreg1, vreg0, vreg1;  // in-flight staging registers

  auto issue = [&](int c) {
    int ktok = (nbIdx - 1) * 128 + c * 64 + skk;
    const ushort* base = qkvu + (seqBase + ktok) * 1536 + h * 64 + sd0;
    kreg0 = *(const bf16x8*)(base + 512);
    kreg1 = *(const bf16x8*)(base + 512 + 8);
    vreg0 = *(const bf16x8*)(base + 1024);
    vreg1 = *(const bf16x8*)(base + 1024 + 8);
  };

  auto write_chunk = [&](int c) {
    short* Kb = Kc[c & 1];
    short* Vb = Vt[c & 1];
    int ktok = (nbIdx - 1) * 128 + c * 64 + skk;
    const float4* tp = (const float4*)(tab + ktok * 32 + (sd0 >> 1));
    float4 t0 = tp[0], t1 = tp[1], t2 = tp[2], t3 = tp[3];
    const int swk = ((skk >> 3) & 3) << 5;
    {
      float cs[4] = {t0.x, t0.z, t1.x, t1.z};
      float sn[4] = {t0.y, t0.w, t1.y, t1.w};
      union { uint u[4]; bf16x8 v; } pk;
#pragma unroll
      for (int j = 0; j < 4; ++j) {
        float x1 = bf2f((ushort)kreg0[2 * j]);
        float x2 = bf2f((ushort)kreg0[2 * j + 1]);
        pk.u[j] = cvtpk_bf16(x1 * cs[j] - x2 * sn[j], x1 * sn[j] + x2 * cs[j]);
      }
      *(bf16x8*)((char*)Kb + skk * 144 + ((sd0 * 2) ^ swk)) = pk.v;
    }
    {
      float cs[4] = {t2.x, t2.z, t3.x, t3.z};
      float sn[4] = {t2.y, t2.w, t3.y, t3.w};
      union { uint u[4]; bf16x8 v; } pk;
#pragma unroll
      for (int j = 0; j < 4; ++j) {
        float x1 = bf2f((ushort)kreg1[2 * j]);
        float x2 = bf2f((ushort)kreg1[2 * j + 1]);
        pk.u[j] = cvtpk_bf16(x1 * cs[j] - x2 * sn[j], x1 * sn[j] + x2 * cs[j]);
      }
      *(bf16x8*)((char*)Kb + skk * 144 + (((sd0 + 8) * 2) ^ swk)) = pk.v;
    }
#pragma unroll
    for (int j = 0; j < 8; ++j) {
      int d0 = sd0 + j;
      *(short*)((char*)Vb + d0 * 144 +
                ((skk * 2) ^ (((d0 >> 4) & 3) << 5))) = vreg0[j];
      int d1 = sd0 + 8 + j;
      *(short*)((char*)Vb + d1 * 144 +
                ((skk * 2) ^ (((d1 >> 4) & 3) << 5))) = vreg1[j];
    }
  };

  // prologue: stage chunk cstart
  issue(cstart);
  write_chunk(cstart);

  for (int c = cstart; c < 4; ++c) {
    if (c < 3) issue(c + 1);     // loads in flight during compute
    __syncthreads();             // buf[c&1] visible to all waves
    if (c >= cw0 && c <= cw1) {
      const char* Kb = (const char*)Kc[c & 1];
      const char* Vb = (const char*)Vt[c & 1];

      bf16x8 ka[2][4];
#pragma unroll
      for (int t2 = 0; t2 < 2; ++t2)
#pragma unroll
        for (int s = 0; s < 4; ++s) {
          int kk = 32 * t2 + lq;
          int byteoff =
              kk * 144 + ((32 * s + 16 * hi) ^ (((kk >> 3) & 3) << 5));
          ka[t2][s] = *(const bf16x8*)(Kb + byteoff);
        }
      f32x16 st0 = Z16, st1 = Z16;
#pragma unroll
      for (int s = 0; s < 4; ++s) {
        st0 = __builtin_amdgcn_mfma_f32_32x32x16_bf16(ka[0][s], qf[s], st0, 0, 0, 0);
        st1 = __builtin_amdgcn_mfma_f32_32x32x16_bf16(ka[1][s], qf[s], st1, 0, 0, 0);
      }

      float p2[2][16];
      float pmax = -3.0e38f;
#pragma unroll
      for (int t2 = 0; t2 < 2; ++t2)
#pragma unroll
        for (int r = 0; r < 16; ++r) {
          int key = c * 64 + 32 * t2 + (r & 3) + 8 * (r >> 2) + 4 * hi;
          float sv = (t2 ? st1[r] : st0[r]);
          bool act = (key >= qi) && (key <= qi + 128);
          sv = act ? sv : -1.0e30f;
          p2[t2][r] = sv;
          pmax = fmaxf(pmax, sv);
        }
      pmax = fmaxf(pmax, __shfl_xor(pmax, 32));
      if (__any(pmax > m0 + 8.f)) {
        float nm = fmaxf(m0, pmax);
        float rr2 = __expf(m0 - nm);
        l *= rr2;
        m0 = nm;
        rbuf[w][lq] = rr2;
        asm volatile("s_waitcnt lgkmcnt(0)" ::: "memory");
#pragma unroll
        for (int a = 0; a < 4; ++a) {
          f32x4 r4 = *(const f32x4*)&rbuf[w][8 * a + 4 * hi];
#pragma unroll
          for (int j = 0; j < 4; ++j) {
            oa0[4 * a + j] *= r4[j];
            oa1[4 * a + j] *= r4[j];
          }
        }
      }
      float lsum = 0.f;
#pragma unroll
      for (int t2 = 0; t2 < 2; ++t2)
#pragma unroll
        for (int r = 0; r < 16; ++r) {
          float p = __expf(p2[t2][r] - m0);
          p2[t2][r] = p;
          lsum += p;
        }
      l += lsum + __shfl_xor(lsum, 32);

      union { uint u[4]; bf16x8 v; } pa[4];
#pragma unroll
      for (int t2 = 0; t2 < 2; ++t2)
#pragma unroll
        for (int sl = 0; sl < 2; ++sl) {
          const float* pp = &p2[t2][8 * sl];
          uint a0 = cvtpk_bf16(pp[0], pp[1]);
          uint a1 = cvtpk_bf16(pp[2], pp[3]);
          uint b0 = cvtpk_bf16(pp[4], pp[5]);
          uint b1 = cvtpk_bf16(pp[6], pp[7]);
          perm32swap(a0, b0);
          perm32swap(a1, b1);
          int slot = 2 * t2 + sl;
          pa[slot].u[0] = a0; pa[slot].u[1] = a1;
          pa[slot].u[2] = b0; pa[slot].u[3] = b1;
        }

#pragma unroll
      for (int slot = 0; slot < 4; ++slot) {
        {
          int d = lq;
          int byteoff =
              d * 144 + ((32 * slot + 16 * hi) ^ (((d >> 4) & 3) << 5));
          bf16x8 vb = *(const bf16x8*)(Vb + byteoff);
          oa0 = __builtin_amdgcn_mfma_f32_32x32x16_bf16(pa[slot].v, vb, oa0, 0, 0, 0);
        }
        {
          int d = 32 + lq;
          int byteoff =
              d * 144 + ((32 * slot + 16 * hi) ^ (((d >> 4) & 3) << 5));
          bf16x8 vb = *(const bf16x8*)(Vb + byteoff);
          oa1 = __builtin_amdgcn_mfma_f32_32x32x16_bf16(pa[slot].v, vb, oa1, 0, 0, 0);
        }
      }
    }
    if (c < 3) write_chunk(c + 1);  // regs -> other buffer (post-compute)
  }

  rbuf[w][lq] = 1.f / l;
  asm volatile("s_waitcnt lgkmcnt(0)" ::: "memory");
  const int q0 = nbIdx * 128 + 32 * w;
#pragma unroll
  for (int a = 0; a < 4; ++a) {
    f32x4 r4 = *(const f32x4*)&rbuf[w][8 * a + 4 * hi];
#pragma unroll
    for (int j = 0; j < 4; ++j) {
      int tok = q0 + 8 * a + 4 * hi + j;
      __hip_bfloat16* orow = o_out + (seqBase + tok) * 512 + h * 64;
      orow[lq] = __float2bfloat16(oa0[4 * a + j] * r4[j]);
      orow[32 + lq] = __float2bfloat16(oa1[4 * a + j] * r4[j]);
    }
  }
}

// ---------------------------------------------------------------- launch
// Workspace layout (~133 MB peak):
//   w16: bf16 [inst | outp | qkv(permuted) | wcat] ; rope table (2MB)
//   R1 (96MB): {cat M*576 | Fb M*192} -> qkvb M*1536
//   R2 (32MB): hb bf16 -> att bf16
extern "C" void kernel_launch(void* const* d_in, const int* in_sizes, int n_in,
                              void* d_out, int out_size, void* d_ws,
                              size_t ws_size, hipStream_t stream) {
  const float* emb = (const float*)d_in[0];
  const float* reg_w = (const float*)d_in[1];
  const float* reg_b = (const float*)d_in[2];
  const float* br_w = (const float*)d_in[3];
  const float* br_b = (const float*)d_in[4];
  const float* mem_w = (const float*)d_in[5];
  const float* mem_b = (const float*)d_in[6];
  const float* inst_w = (const float*)d_in[7];
  const float* inst_b = (const float*)d_in[8];
  const float* ln1_g = (const float*)d_in[9];
  const float* ln1_b = (const float*)d_in[10];
  const float* qkv_w = (const float*)d_in[11];
  const float* outp_w = (const float*)d_in[12];
  const float* outp_b = (const float*)d_in[13];
  const float* ln2_g = (const float*)d_in[14];
  const float* ln2_b = (const float*)d_in[15];
  const float* head_w = (const float*)d_in[16];
  const float* head_b = (const float*)d_in[17];
  const int* x = (const int*)d_in[18];
  float* out = (float*)d_out;

  const int M = M_TOK;
  char* wsb = (char*)d_ws;
  __hip_bfloat16* w16 = (__hip_bfloat16*)wsb;
  __hip_bfloat16* w1 = w16;                        // inst
  __hip_bfloat16* w3 = w16 + NW1;                  // outp
  __hip_bfloat16* w2 = w16 + NW1 + NW3;            // qkv (permuted)
  __hip_bfloat16* wcat = w16 + NW1 + NW3 + NW2;    // feature proj
  size_t woff = ((size_t)(NW1 + NW2 + NW3 + NW4) * 2 + 255) & ~(size_t)255;
  float2* tab = (float2*)(wsb + woff);             // 2MB
  size_t toff = woff + (size_t)NTAB * 8;
  char* r1 = wsb + toff;                           // 96 MB region
  char* r2 = r1 + (size_t)M * 1536 * 2;            // 32 MB region
  __hip_bfloat16* cat = (__hip_bfloat16*)r1;       // M*576
  __hip_bfloat16* Fb = (__hip_bfloat16*)(r1 + (size_t)M * 576 * 2);  // M*192
  __hip_bfloat16* qkvb = (__hip_bfloat16*)r1;      // M*1536
  __hip_bfloat16* hb = (__hip_bfloat16*)r2;        // M*512
  __hip_bfloat16* att = (__hip_bfloat16*)r2;       // M*512

  // 0. all weight conversion + rope table (one kernel)
  const int setup_tot = NW1 + NW3 + NW2 + NW4 + NTAB;
  setup_kernel<<<(setup_tot + 255) / 256, 256, 0, stream>>>(
      inst_w, outp_w, qkv_w, reg_w, reg_b, br_w, br_b, mem_w, mem_b, w16, tab);
  // 1. prep: cat[:,0:192] = silu(emb[tid]) ; Fb = [1, feats, 0]
  prep_kernel<<<(M * 48) / 256, 256, 0, stream>>>(x, emb, cat, Fb);
  // 1b. feature proj: cat[:,192:576] = silu(Fb @ wcat^T)
  gemm_mfma<__hip_bfloat16, true><<<(M / 128) * 3, 256, 0, stream>>>(
      (const ushort*)Fb, (const ushort*)wcat, nullptr, cat + 192, M, 384, 192,
      576, 3);
  // 2. inst proj + LN1 + silu fused: hb = silu(LN(cat @ w1^T + b))
  gemm_ln_fused<false><<<M / 128, 512, 0, stream>>>(
      (const ushort*)cat, (const ushort*)w1, inst_b, ln1_g, ln1_b, nullptr,
      nullptr, hb, nullptr, 576);
  // 3. qkv proj (permuted cols): hb @ w2^T -> qkvb planes [Q|K|V]
  gemm_mfma<__hip_bfloat16><<<(M / 128) * 12, 256, 0, stream>>>(
      (const ushort*)hb, (const ushort*)w2, nullptr, qkvb, M, 1536, 512, 1536,
      12);
  // 4. attention (MFMA) -> att (bf16, [M][512] heads concatenated)
  attn_kernel<<<BATCH * 8 * 64, 256, 0, stream>>>(qkvb, tab, att);
  // 5. outp proj + LN2 + silu + head + activations fused -> out
  gemm_ln_fused<true><<<M / 128, 512, 0, stream>>>(
      (const ushort*)att, (const ushort*)w3, outp_b, ln2_g, ln2_b, head_w,
      head_b, nullptr, out, 512);
}